// Round 29
// baseline (378.855 us; speedup 1.0000x reference)
//
#include <hip/hip_runtime.h>
#include <hip/hip_bf16.h>
#include <cstddef>

#define L_SEQ   2048
#define NBATCH  2
#define NROWS   (NBATCH * L_SEQ)   /* 4096 */
#define NSTATE  16
#define CH      64
#define NCHUNK  (L_SEQ / CH)       /* 32 */

typedef __bf16 bf16x8 __attribute__((ext_vector_type(8)));
typedef float  f32x4  __attribute__((ext_vector_type(4)));
typedef unsigned short u16x4 __attribute__((ext_vector_type(4)));
typedef unsigned short u16x8 __attribute__((ext_vector_type(8)));

static __device__ __forceinline__ unsigned short f2bf(float f) {
  unsigned int x = __builtin_bit_cast(unsigned int, f);
  x += 0x7fffu + ((x >> 16) & 1u);          // RNE
  return (unsigned short)(x >> 16);
}
static __device__ __forceinline__ float bf2f(unsigned short u) {
  return __builtin_bit_cast(float, ((unsigned int)u) << 16);
}

// async global->LDS, 16B per lane; LDS dest = wave-uniform base + lane*16
#define GLDS(g, l) __builtin_amdgcn_global_load_lds( \
    (const __attribute__((address_space(1))) void*)(g), \
    (__attribute__((address_space(3))) void*)(l), 16, 0, 0)

#define DRAIN_VM() asm volatile("s_waitcnt vmcnt(0)" ::: "memory")

// ---------------------------------------------------------------- f32 -> bf16 (generic, for xdbl)
__global__ __launch_bounds__(256) void cvt_bf16_kernel(
    const float* __restrict__ in, unsigned short* __restrict__ out, int n4)
{
  const int i = blockIdx.x * 256 + threadIdx.x;
  if (i < n4) {
    const float4 v = reinterpret_cast<const float4*>(in)[i];
    u16x4 o;
    o[0] = f2bf(v.x); o[1] = f2bf(v.y); o[2] = f2bf(v.z); o[3] = f2bf(v.w);
    reinterpret_cast<u16x4*>(out)[i] = o;
  }
}

// ---------------------------------------------------------------- all weights -> bf16 + zero xdbl + step-1 LN
__global__ __launch_bounds__(256) void cvt_all_kernel(
    const float* __restrict__ ipw, const float* __restrict__ xpw,
    const float* __restrict__ dtw, const float* __restrict__ opw,
    const float* __restrict__ w1,  const float* __restrict__ w2,
    const float* __restrict__ few, float* __restrict__ zx,
    unsigned short* __restrict__ o_ipw, unsigned short* __restrict__ o_xpw,
    unsigned short* __restrict__ o_dtw, unsigned short* __restrict__ o_opw,
    unsigned short* __restrict__ o_w1,  unsigned short* __restrict__ o_w2,
    unsigned short* __restrict__ o_few,
    const float* __restrict__ lsrc, const float* __restrict__ lg,
    const float* __restrict__ lb, unsigned short* __restrict__ louth)
{
  __shared__ float sm[8];
  if (blockIdx.x >= 12832) {             // fused step-1 LayerNorm
    const int row = blockIdx.x - 12832;
    const int tid = threadIdx.x;
    const float4 v = reinterpret_cast<const float4*>(lsrc + (size_t)row * 1024)[tid];
    float s = v.x + v.y + v.z + v.w;
#pragma unroll
    for (int o = 32; o > 0; o >>= 1) s += __shfl_down(s, o, 64);
    if ((tid & 63) == 0) sm[tid >> 6] = s;
    __syncthreads();
    const float mean = (sm[0] + sm[1] + sm[2] + sm[3]) * (1.f / 1024.f);
    const float dx = v.x - mean, dy = v.y - mean, dz = v.z - mean, dw = v.w - mean;
    float q = dx * dx + dy * dy + dz * dz + dw * dw;
#pragma unroll
    for (int o = 32; o > 0; o >>= 1) q += __shfl_down(q, o, 64);
    __syncthreads();
    if ((tid & 63) == 0) sm[tid >> 6] = q;
    __syncthreads();
    const float var = (sm[0] + sm[1] + sm[2] + sm[3]) * (1.f / 1024.f);
    const float rstd = rsqrtf(var + 1e-5f);
    const float4 gv = reinterpret_cast<const float4*>(lg)[tid];
    const float4 bv = reinterpret_cast<const float4*>(lb)[tid];
    u16x4 ob;
    ob[0] = f2bf(dx * rstd * gv.x + bv.x);
    ob[1] = f2bf(dy * rstd * gv.y + bv.y);
    ob[2] = f2bf(dz * rstd * gv.z + bv.z);
    ob[3] = f2bf(dw * rstd * gv.w + bv.w);
    reinterpret_cast<u16x4*>(louth + (size_t)row * 1024)[tid] = ob;
    return;
  }
  int i = blockIdx.x * 256 + threadIdx.x;
  if (i < 98304) {                       // zero xdbl (393216 floats)
    reinterpret_cast<float4*>(zx)[i] = make_float4(0.f, 0.f, 0.f, 0.f);
    return;
  }
  i -= 98304;
  const float* src; unsigned short* dst;
  if (i < 524288)                 { src = ipw; dst = o_ipw; }
  else if ((i -= 524288) < 24576) { src = xpw; dst = o_xpw; }
  else if ((i -= 24576) < 16384)  { src = dtw; dst = o_dtw; }
  else if ((i -= 16384) < 262144) { src = opw; dst = o_opw; }
  else if ((i -= 262144) < 1048576){ src = w1; dst = o_w1; }
  else if ((i -= 1048576) < 1048576){ src = w2; dst = o_w2; }
  else if ((i -= 1048576) < 262144){ src = few; dst = o_few; }
  else return;
  const float4 v = reinterpret_cast<const float4*>(src)[i];
  u16x4 o;
  o[0] = f2bf(v.x); o[1] = f2bf(v.y); o[2] = f2bf(v.z); o[3] = f2bf(v.w);
  reinterpret_cast<u16x4*>(dst)[i] = o;
}

// ---------------------------------------------------------------- LayerNorm
__global__ __launch_bounds__(256) void ln_kernel(
    const float* __restrict__ in, const float* __restrict__ g,
    const float* __restrict__ bta, const float* __restrict__ res,
    float* __restrict__ out, unsigned short* __restrict__ outb)
{
  const int row = blockIdx.x;
  const int tid = threadIdx.x;
  __shared__ float sm[8];
  const float4 v = reinterpret_cast<const float4*>(in + (size_t)row * 1024)[tid];
  float s = v.x + v.y + v.z + v.w;
#pragma unroll
  for (int o = 32; o > 0; o >>= 1) s += __shfl_down(s, o, 64);
  if ((tid & 63) == 0) sm[tid >> 6] = s;
  __syncthreads();
  const float mean = (sm[0] + sm[1] + sm[2] + sm[3]) * (1.f / 1024.f);
  const float dx = v.x - mean, dy = v.y - mean, dz = v.z - mean, dw = v.w - mean;
  float q = dx * dx + dy * dy + dz * dz + dw * dw;
#pragma unroll
  for (int o = 32; o > 0; o >>= 1) q += __shfl_down(q, o, 64);
  __syncthreads();
  if ((tid & 63) == 0) sm[tid >> 6] = q;
  __syncthreads();
  const float var = (sm[0] + sm[1] + sm[2] + sm[3]) * (1.f / 1024.f);
  const float rstd = rsqrtf(var + 1e-5f);
  const float4 gv = reinterpret_cast<const float4*>(g)[tid];
  const float4 bv = reinterpret_cast<const float4*>(bta)[tid];
  float4 o4;
  o4.x = dx * rstd * gv.x + bv.x;
  o4.y = dy * rstd * gv.y + bv.y;
  o4.z = dz * rstd * gv.z + bv.z;
  o4.w = dw * rstd * gv.w + bv.w;
  if (outb) {
    u16x4 ob;
    ob[0] = f2bf(o4.x); ob[1] = f2bf(o4.y); ob[2] = f2bf(o4.z); ob[3] = f2bf(o4.w);
    reinterpret_cast<u16x4*>(outb + (size_t)row * 1024)[tid] = ob;
  } else {
    if (res) {
      const float4 rv = reinterpret_cast<const float4*>(res + (size_t)row * 1024)[tid];
      o4.x += rv.x; o4.y += rv.y; o4.z += rv.z; o4.w += rv.w;
    }
    reinterpret_cast<float4*>(out + (size_t)row * 1024)[tid] = o4;
  }
}

// ---------------------------------------------------------------- fused double-LayerNorm (steps 10+11)
__global__ __launch_bounds__(256) void ln2_kernel(
    const float* __restrict__ in, const float* __restrict__ g1,
    const float* __restrict__ b1, const float* __restrict__ res,
    const float* __restrict__ g2, const float* __restrict__ b2,
    float* __restrict__ out1, unsigned short* __restrict__ out2b)
{
  const int row = blockIdx.x;
  const int tid = threadIdx.x;
  __shared__ float sm[8];
  const float4 v = reinterpret_cast<const float4*>(in + (size_t)row * 1024)[tid];
  float s = v.x + v.y + v.z + v.w;
#pragma unroll
  for (int o = 32; o > 0; o >>= 1) s += __shfl_down(s, o, 64);
  if ((tid & 63) == 0) sm[tid >> 6] = s;
  __syncthreads();
  const float mean = (sm[0] + sm[1] + sm[2] + sm[3]) * (1.f / 1024.f);
  const float dx = v.x - mean, dy = v.y - mean, dz = v.z - mean, dw = v.w - mean;
  float q = dx * dx + dy * dy + dz * dz + dw * dw;
#pragma unroll
  for (int o = 32; o > 0; o >>= 1) q += __shfl_down(q, o, 64);
  __syncthreads();
  if ((tid & 63) == 0) sm[tid >> 6] = q;
  __syncthreads();
  const float var = (sm[0] + sm[1] + sm[2] + sm[3]) * (1.f / 1024.f);
  const float rstd = rsqrtf(var + 1e-5f);
  const float4 g1v = reinterpret_cast<const float4*>(g1)[tid];
  const float4 b1v = reinterpret_cast<const float4*>(b1)[tid];
  const float4 rv = reinterpret_cast<const float4*>(res + (size_t)row * 1024)[tid];
  float4 o4;
  o4.x = dx * rstd * g1v.x + b1v.x + rv.x;
  o4.y = dy * rstd * g1v.y + b1v.y + rv.y;
  o4.z = dz * rstd * g1v.z + b1v.z + rv.z;
  o4.w = dw * rstd * g1v.w + b1v.w + rv.w;
  reinterpret_cast<float4*>(out1 + (size_t)row * 1024)[tid] = o4;
  __syncthreads();
  float s2 = o4.x + o4.y + o4.z + o4.w;
#pragma unroll
  for (int o = 32; o > 0; o >>= 1) s2 += __shfl_down(s2, o, 64);
  if ((tid & 63) == 0) sm[tid >> 6] = s2;
  __syncthreads();
  const float mean2 = (sm[0] + sm[1] + sm[2] + sm[3]) * (1.f / 1024.f);
  const float ex = o4.x - mean2, ey = o4.y - mean2, ez = o4.z - mean2, ew = o4.w - mean2;
  float q2 = ex * ex + ey * ey + ez * ez + ew * ew;
#pragma unroll
  for (int o = 32; o > 0; o >>= 1) q2 += __shfl_down(q2, o, 64);
  __syncthreads();
  if ((tid & 63) == 0) sm[tid >> 6] = q2;
  __syncthreads();
  const float var2 = (sm[0] + sm[1] + sm[2] + sm[3]) * (1.f / 1024.f);
  const float rstd2 = rsqrtf(var2 + 1e-5f);
  const float4 g2v = reinterpret_cast<const float4*>(g2)[tid];
  const float4 b2v = reinterpret_cast<const float4*>(b2)[tid];
  u16x4 ob;
  ob[0] = f2bf(ex * rstd2 * g2v.x + b2v.x);
  ob[1] = f2bf(ey * rstd2 * g2v.y + b2v.y);
  ob[2] = f2bf(ez * rstd2 * g2v.z + b2v.z);
  ob[3] = f2bf(ew * rstd2 * g2v.w + b2v.w);
  reinterpret_cast<u16x4*>(out2b + (size_t)row * 1024)[tid] = ob;
}

// ---------------------------------------------------------------- bf16 GEMM, 256x256 tile, BK=32, 4-slot ring, depth-3 vmcnt (round-23 proven)
__global__ __launch_bounds__(512) void gemm256_kernel(
    const unsigned short* __restrict__ A, int lda,
    const unsigned short* __restrict__ B, int ldb,
    void* __restrict__ Cv, int ldc,
    const float* __restrict__ bias, const float* __restrict__ res,
    int K, int act, int outbf, int gy)
{
  __shared__ __align__(16) unsigned char smem[131072];
  const int t = threadIdx.x;
  const int w = t >> 6, l = t & 63;

  const int q = gridDim.x >> 3;
  const int nid = (blockIdx.x & 7) * q + (blockIdx.x >> 3);
  const int bm = (nid / gy) * 256;
  const int bn = (nid % gy) * 256;

  const int wr = (w >> 2) * 128;
  const int wc = (w & 3) * 64;
  f32x4 acc[8][4] = {};

  const int srow = t >> 2;          // 0..127
  const int sk = (t & 3) * 8;
  const unsigned short* gA = A + (size_t)(bm + srow) * lda + sk;
  const unsigned short* gB = B + (size_t)(bn + srow) * ldb + sk;

  const int fr = l & 15;
  const int kb = (l >> 4) * 8;

#define SA7(s) (smem + (s) * 16384)
#define SB7(s) (smem + 65536 + (s) * 16384)

#define STAGE7(s, k0) do { \
    GLDS(gA + (k0), SA7(s) + w * 1024); \
    GLDS(gA + (k0) + (size_t)128 * lda, SA7(s) + 8192 + w * 1024); \
    GLDS(gB + (k0), SB7(s) + w * 1024); \
    GLDS(gB + (k0) + (size_t)128 * ldb, SB7(s) + 8192 + w * 1024); \
  } while (0)

#define COMPUTE7(s) do { \
    bf16x8 af[8], bfr[4]; \
    _Pragma("unroll") \
    for (int j = 0; j < 4; ++j) \
      bfr[j] = *reinterpret_cast<const bf16x8*>((const unsigned short*)SB7(s) + (wc + j * 16 + fr) * 32 + kb); \
    _Pragma("unroll") \
    for (int i = 0; i < 8; ++i) \
      af[i] = *reinterpret_cast<const bf16x8*>((const unsigned short*)SA7(s) + (wr + i * 16 + fr) * 32 + kb); \
    _Pragma("unroll") \
    for (int i = 0; i < 8; ++i) \
      _Pragma("unroll") \
      for (int j = 0; j < 4; ++j) \
        acc[i][j] = __builtin_amdgcn_mfma_f32_16x16x32_bf16(af[i], bfr[j], acc[i][j], 0, 0, 0); \
  } while (0)

  const int nt = K >> 5;
  STAGE7(0, 0);
  if (nt > 1) STAGE7(1, 32);
  if (nt > 2) STAGE7(2, 64);
  if (nt > 2)      asm volatile("s_waitcnt vmcnt(8)" ::: "memory");
  else if (nt > 1) asm volatile("s_waitcnt vmcnt(4)" ::: "memory");
  else             asm volatile("s_waitcnt vmcnt(0)" ::: "memory");
  __builtin_amdgcn_s_barrier();
  for (int kt = 0; kt < nt; ++kt) {
    const int s = kt & 3;
    __builtin_amdgcn_sched_barrier(0);
    if (kt + 3 < nt) STAGE7((kt + 3) & 3, (kt + 3) * 32);
    __builtin_amdgcn_sched_barrier(0);
    COMPUTE7(s);
    __builtin_amdgcn_sched_barrier(0);
    if (kt + 3 < nt)      asm volatile("s_waitcnt vmcnt(8)" ::: "memory");
    else if (kt + 2 < nt) asm volatile("s_waitcnt vmcnt(4)" ::: "memory");
    else if (kt + 1 < nt) asm volatile("s_waitcnt vmcnt(0)" ::: "memory");
    __builtin_amdgcn_s_barrier();
  }
#undef STAGE7
#undef COMPUTE7
#undef SA7
#undef SB7

  const int crow = (l >> 4) * 4;
  const int ccol = l & 15;
  float* Cf = (float*)Cv;
  unsigned short* Cb = (unsigned short*)Cv;
#pragma unroll
  for (int i = 0; i < 8; ++i) {
#pragma unroll
    for (int j = 0; j < 4; ++j) {
      const int n = bn + wc + j * 16 + ccol;
      const float bv = bias ? bias[n] : 0.f;
#pragma unroll
      for (int r = 0; r < 4; ++r) {
        const int m = bm + wr + i * 16 + crow + r;
        float v = acc[i][j][r] + bv;
        if (act == 1) v = (v > 20.f) ? v : __logf(1.f + __expf(v));
        else if (act == 2) v = (v >= 0.f) ? v : 0.01f * v;
        if (res) v += res[(size_t)m * ldc + n];
        if (outbf) Cb[(size_t)m * ldc + n] = f2bf(v);
        else       Cf[(size_t)m * ldc + n] = v;
      }
    }
  }
}

// ---------------------------------------------------------------- bf16 GEMM, intra-block K-split, 2 groups, 2-phase (proven)
template<int BK>
__global__ __launch_bounds__(512) void gemm_ksplit_kernel(
    const unsigned short* __restrict__ A, int lda,
    const unsigned short* __restrict__ B, int ldb,
    void* __restrict__ Cv, int ldc,
    const float* __restrict__ bias, const float* __restrict__ res,
    int K, int act, int outbf, int gy)
{
  constexpr int ABYTES = 128 * BK * 2;
  constexpr int NISS = (BK == 32) ? 2 : 4;
  constexpr int RPI  = (BK == 32) ? 64 : 32;
  constexpr int NS   = BK / 32;
  __shared__ __align__(16) unsigned char smem[8 * ABYTES];
  const int tid = threadIdx.x;
  const int grp = tid >> 8;
  const int t = tid & 255;
  const int w = t >> 6, l = t & 63;

  const int q = gridDim.x >> 3;
  const int nid = (blockIdx.x & 7) * q + (blockIdx.x >> 3);
  const int bm = (nid / gy) * 128;
  const int bn = (nid % gy) * 128;

  const int K2 = K >> 1;
  const int koff = grp * K2;
  const int wr = (w >> 1) * 64, wc = (w & 1) * 64;
  f32x4 acc[4][4] = {};

  const int srow = (BK == 32) ? (t >> 2) : (t >> 3);
  const int sk   = (BK == 32) ? ((t & 3) * 8) : ((t & 7) * 8);
  const unsigned short* gA = A + (size_t)(bm + srow) * lda + koff + sk;
  const unsigned short* gB = B + (size_t)(bn + srow) * ldb + koff + sk;

  const int gbase = grp * 2 * ABYTES;
  const int fr = l & 15;
  const int kb = (l >> 4) * 8;

#define SAb(buf) (smem + gbase + (buf) * ABYTES)
#define SBb(buf) (smem + 4 * ABYTES + gbase + (buf) * ABYTES)

#define STAGEK(buf, k0) do { \
    _Pragma("unroll") \
    for (int ii = 0; ii < NISS; ++ii) { \
      GLDS(gA + (k0) + (size_t)ii * RPI * lda, SAb(buf) + ii * 4096 + w * 1024); \
      GLDS(gB + (k0) + (size_t)ii * RPI * ldb, SBb(buf) + ii * 4096 + w * 1024); \
    } \
  } while (0)

#define COMPUTEK(buf) do { \
    _Pragma("unroll") \
    for (int s = 0; s < NS; ++s) { \
      bf16x8 af[4], bfr[4]; \
      _Pragma("unroll") \
      for (int i = 0; i < 4; ++i) \
        af[i] = *reinterpret_cast<const bf16x8*>((const unsigned short*)SAb(buf) + (wr + i * 16 + fr) * BK + s * 32 + kb); \
      _Pragma("unroll") \
      for (int j = 0; j < 4; ++j) \
        bfr[j] = *reinterpret_cast<const bf16x8*>((const unsigned short*)SBb(buf) + (wc + j * 16 + fr) * BK + s * 32 + kb); \
      _Pragma("unroll") \
      for (int i = 0; i < 4; ++i) \
        _Pragma("unroll") \
        for (int j = 0; j < 4; ++j) \
          acc[i][j] = __builtin_amdgcn_mfma_f32_16x16x32_bf16(af[i], bfr[j], acc[i][j], 0, 0, 0); \
    } \
  } while (0)

  STAGEK(0, 0);
  DRAIN_VM();
  __syncthreads();
  int cur = 0;
  for (int k0 = BK; k0 < K2; k0 += BK) {
    __builtin_amdgcn_sched_barrier(0);
    STAGEK(cur ^ 1, k0);
    __builtin_amdgcn_sched_barrier(0);
    COMPUTEK(cur);
    DRAIN_VM();
    __syncthreads();
    cur ^= 1;
  }
  COMPUTEK(cur);
#undef STAGEK
#undef COMPUTEK
#undef SAb
#undef SBb

  __syncthreads();
  float* red = (float*)smem;
  if (grp) {
#pragma unroll
    for (int i = 0; i < 4; ++i)
#pragma unroll
      for (int j = 0; j < 4; ++j)
        *reinterpret_cast<f32x4*>(&red[(t << 6) + (i * 4 + j) * 4]) = acc[i][j];
  }
  __syncthreads();
  if (!grp) {
    const int crow = (l >> 4) * 4;
    const int ccol = l & 15;
    float* Cf = (float*)Cv;
    unsigned short* Cb = (unsigned short*)Cv;
#pragma unroll
    for (int i = 0; i < 4; ++i) {
#pragma unroll
      for (int j = 0; j < 4; ++j) {
        const f32x4 o = *reinterpret_cast<const f32x4*>(&red[(t << 6) + (i * 4 + j) * 4]);
        const int n = bn + wc + j * 16 + ccol;
        const float bv = bias ? bias[n] : 0.f;
#pragma unroll
        for (int r = 0; r < 4; ++r) {
          const int m = bm + wr + i * 16 + crow + r;
          float v = acc[i][j][r] + o[r] + bv;
          if (act == 1) v = (v > 20.f) ? v : __logf(1.f + __expf(v));
          else if (act == 2) v = (v >= 0.f) ? v : 0.01f * v;
          if (res) v += res[(size_t)m * ldc + n];
          if (outbf) Cb[(size_t)m * ldc + n] = f2bf(v);
          else       Cf[(size_t)m * ldc + n] = v;
        }
      }
    }
  }
}

// ---------------------------------------------------------------- bf16 GEMM, 128x64 tile, intra-block K-split, 2 groups, 2-phase
// Proven BETTER for short-K (K<=1024: out_proj, fe) and WORSE for long-K
// (ffn2 K=4096). Use only for K<=1024 sites.
__global__ __launch_bounds__(512) void gemm_ksplit_bn64_kernel(
    const unsigned short* __restrict__ A, int lda,
    const unsigned short* __restrict__ B, int ldb,
    void* __restrict__ Cv, int ldc,
    const float* __restrict__ bias, const float* __restrict__ res,
    int K, int act, int outbf, int gy)
{
  __shared__ __align__(16) unsigned char smem[49152];
  const int tid = threadIdx.x;
  const int grp = tid >> 8;
  const int t = tid & 255;
  const int w = t >> 6, l = t & 63;

  const int q = gridDim.x >> 3;
  const int nid = (blockIdx.x & 7) * q + (blockIdx.x >> 3);
  const int bm = (nid / gy) * 128;
  const int bn = (nid % gy) * 64;

  const int K2 = K >> 1;
  const int koff = grp * K2;
  const int wr = (w >> 1) * 64, wc = (w & 1) * 32;
  f32x4 acc[4][2] = {};

  const int srow = t >> 2;          // 0..63
  const int sk = (t & 3) * 8;
  const unsigned short* gA = A + (size_t)(bm + srow) * lda + koff + sk;
  const unsigned short* gB = B + (size_t)(bn + srow) * ldb + koff + sk;

  const int fr = l & 15;
  const int kb = (l >> 4) * 8;

#define SAn(buf) (smem + grp * 16384 + (buf) * 8192)
#define SBn(buf) (smem + 32768 + grp * 8192 + (buf) * 4096)

#define STAGEN(buf, k0) do { \
    GLDS(gA + (k0), SAn(buf) + w * 1024); \
    GLDS(gA + (k0) + (size_t)64 * lda, SAn(buf) + 4096 + w * 1024); \
    GLDS(gB + (k0), SBn(buf) + w * 1024); \
  } while (0)

#define COMPUTEN(buf) do { \
    bf16x8 af[4], bfr[2]; \
    _Pragma("unroll") \
    for (int i = 0; i < 4; ++i) \
      af[i] = *reinterpret_cast<const bf16x8*>((const unsigned short*)SAn(buf) + (wr + i * 16 + fr) * 32 + kb); \
    _Pragma("unroll") \
    for (int j = 0; j < 2; ++j) \
      bfr[j] = *reinterpret_cast<const bf16x8*>((const unsigned short*)SBn(buf) + (wc + j * 16 + fr) * 32 + kb); \
    _Pragma("unroll") \
    for (int i = 0; i < 4; ++i) \
      _Pragma("unroll") \
      for (int j = 0; j < 2; ++j) \
        acc[i][j] = __builtin_amdgcn_mfma_f32_16x16x32_bf16(af[i], bfr[j], acc[i][j], 0, 0, 0); \
  } while (0)

  STAGEN(0, 0);
  DRAIN_VM();
  __syncthreads();
  int cur = 0;
  for (int k0 = 32; k0 < K2; k0 += 32) {
    __builtin_amdgcn_sched_barrier(0);
    STAGEN(cur ^ 1, k0);
    __builtin_amdgcn_sched_barrier(0);
    COMPUTEN(cur);
    DRAIN_VM();
    __syncthreads();
    cur ^= 1;
  }
  COMPUTEN(cur);
#undef STAGEN
#undef COMPUTEN
#undef SAn
#undef SBn

  __syncthreads();
  float* red = (float*)smem;
  if (grp) {
#pragma unroll
    for (int i = 0; i < 4; ++i)
#pragma unroll
      for (int j = 0; j < 2; ++j)
        *reinterpret_cast<f32x4*>(&red[(t << 5) + (i * 2 + j) * 4]) = acc[i][j];
  }
  __syncthreads();
  if (!grp) {
    const int crow = (l >> 4) * 4;
    const int ccol = l & 15;
    float* Cf = (float*)Cv;
    unsigned short* Cb = (unsigned short*)Cv;
#pragma unroll
    for (int i = 0; i < 4; ++i) {
#pragma unroll
      for (int j = 0; j < 2; ++j) {
        const f32x4 o = *reinterpret_cast<const f32x4*>(&red[(t << 5) + (i * 2 + j) * 4]);
        const int n = bn + wc + j * 16 + ccol;
        const float bv = bias ? bias[n] : 0.f;
#pragma unroll
        for (int r = 0; r < 4; ++r) {
          const int m = bm + wr + i * 16 + crow + r;
          float v = acc[i][j][r] + o[r] + bv;
          if (act == 1) v = (v > 20.f) ? v : __logf(1.f + __expf(v));
          else if (act == 2) v = (v >= 0.f) ? v : 0.01f * v;
          if (res) v += res[(size_t)m * ldc + n];
          if (outbf) Cb[(size_t)m * ldc + n] = f2bf(v);
          else       Cf[(size_t)m * ldc + n] = v;
        }
      }
    }
  }
}

// ---------------------------------------------------------------- bf16 GEMM, intra-block K-split x4, 16 waves, 2-phase
// Occupancy lever WITHOUT intensity loss (round-27 lesson: bn64's BN=64 cost
// B-reuse; this keeps BN=128). 1024 threads = 4 K-groups x 4 waves;
// 4 waves/SIMD (vs ring's 2). LDS: A grp*16K+buf*8K in [0,64K); B at
// 65536 + same in [64K,128K). Reduction tree: grp1->grp0, grp3->grp2
// (disjoint 64KB halves), then grp2->grp0; grp0-only C-write (round-25
// write-amplification trap avoided).
__global__ __launch_bounds__(1024) void gemm_ksplit4_kernel(
    const unsigned short* __restrict__ A, int lda,
    const unsigned short* __restrict__ B, int ldb,
    void* __restrict__ Cv, int ldc,
    const float* __restrict__ bias, const float* __restrict__ res,
    int K, int act, int outbf, int gy)
{
  __shared__ __align__(16) unsigned char smem[131072];
  const int tid = threadIdx.x;
  const int grp = tid >> 8;         // 0..3
  const int t = tid & 255;
  const int w = t >> 6, l = t & 63;

  const int q = gridDim.x >> 3;
  const int nid = (blockIdx.x & 7) * q + (blockIdx.x >> 3);
  const int bm = (nid / gy) * 128;
  const int bn = (nid % gy) * 128;

  const int K4 = K >> 2;
  const int koff = grp * K4;
  const int wr = (w >> 1) * 64, wc = (w & 1) * 64;
  f32x4 acc[4][4] = {};

  const int srow = t >> 2;          // 0..63
  const int sk = (t & 3) * 8;
  const unsigned short* gA = A + (size_t)(bm + srow) * lda + koff + sk;
  const unsigned short* gB = B + (size_t)(bn + srow) * ldb + koff + sk;

  const int fr = l & 15;
  const int kb = (l >> 4) * 8;

#define SA4(buf) (smem + grp * 16384 + (buf) * 8192)
#define SB4(buf) (smem + 65536 + grp * 16384 + (buf) * 8192)

#define STAGE4(buf, k0) do { \
    GLDS(gA + (k0), SA4(buf) + w * 1024); \
    GLDS(gA + (k0) + (size_t)64 * lda, SA4(buf) + 4096 + w * 1024); \
    GLDS(gB + (k0), SB4(buf) + w * 1024); \
    GLDS(gB + (k0) + (size_t)64 * ldb, SB4(buf) + 4096 + w * 1024); \
  } while (0)

#define COMPUTE4(buf) do { \
    bf16x8 af[4], bfr[4]; \
    _Pragma("unroll") \
    for (int i = 0; i < 4; ++i) \
      af[i] = *reinterpret_cast<const bf16x8*>((const unsigned short*)SA4(buf) + (wr + i * 16 + fr) * 32 + kb); \
    _Pragma("unroll") \
    for (int j = 0; j < 4; ++j) \
      bfr[j] = *reinterpret_cast<const bf16x8*>((const unsigned short*)SB4(buf) + (wc + j * 16 + fr) * 32 + kb); \
    _Pragma("unroll") \
    for (int i = 0; i < 4; ++i) \
      _Pragma("unroll") \
      for (int j = 0; j < 4; ++j) \
        acc[i][j] = __builtin_amdgcn_mfma_f32_16x16x32_bf16(af[i], bfr[j], acc[i][j], 0, 0, 0); \
  } while (0)

  STAGE4(0, 0);
  DRAIN_VM();
  __syncthreads();
  int cur = 0;
  for (int k0 = 32; k0 < K4; k0 += 32) {
    __builtin_amdgcn_sched_barrier(0);
    STAGE4(cur ^ 1, k0);
    __builtin_amdgcn_sched_barrier(0);
    COMPUTE4(cur);
    DRAIN_VM();
    __syncthreads();
    cur ^= 1;
  }
  COMPUTE4(cur);
#undef STAGE4
#undef COMPUTE4
#undef SA4
#undef SB4

  // reduction tree: (grp1 -> grp0) and (grp3 -> grp2) in disjoint halves,
  // then grp2 -> grp0. Final C-write by grp0 only.
  __syncthreads();
  float* red1 = (float*)smem;                 // 64KB, written by grp1 / grp2
  float* red3 = (float*)(smem + 65536);       // 64KB, written by grp3
  if (grp == 1) {
#pragma unroll
    for (int i = 0; i < 4; ++i)
#pragma unroll
      for (int j = 0; j < 4; ++j)
        *reinterpret_cast<f32x4*>(&red1[(t << 6) + (i * 4 + j) * 4]) = acc[i][j];
  } else if (grp == 3) {
#pragma unroll
    for (int i = 0; i < 4; ++i)
#pragma unroll
      for (int j = 0; j < 4; ++j)
        *reinterpret_cast<f32x4*>(&red3[(t << 6) + (i * 4 + j) * 4]) = acc[i][j];
  }
  __syncthreads();
  if (grp == 0) {
#pragma unroll
    for (int i = 0; i < 4; ++i)
#pragma unroll
      for (int j = 0; j < 4; ++j)
        acc[i][j] += *reinterpret_cast<const f32x4*>(&red1[(t << 6) + (i * 4 + j) * 4]);
  } else if (grp == 2) {
#pragma unroll
    for (int i = 0; i < 4; ++i)
#pragma unroll
      for (int j = 0; j < 4; ++j)
        acc[i][j] += *reinterpret_cast<const f32x4*>(&red3[(t << 6) + (i * 4 + j) * 4]);
  }
  __syncthreads();
  if (grp == 2) {
#pragma unroll
    for (int i = 0; i < 4; ++i)
#pragma unroll
      for (int j = 0; j < 4; ++j)
        *reinterpret_cast<f32x4*>(&red1[(t << 6) + (i * 4 + j) * 4]) = acc[i][j];
  }
  __syncthreads();
  if (grp == 0) {
    const int crow = (l >> 4) * 4;
    const int ccol = l & 15;
    float* Cf = (float*)Cv;
    unsigned short* Cb = (unsigned short*)Cv;
#pragma unroll
    for (int i = 0; i < 4; ++i) {
#pragma unroll
      for (int j = 0; j < 4; ++j) {
        const f32x4 o = *reinterpret_cast<const f32x4*>(&red1[(t << 6) + (i * 4 + j) * 4]);
        const int n = bn + wc + j * 16 + ccol;
        const float bv = bias ? bias[n] : 0.f;
#pragma unroll
        for (int r = 0; r < 4; ++r) {
          const int m = bm + wr + i * 16 + crow + r;
          float v = acc[i][j][r] + o[r] + bv;
          if (act == 1) v = (v > 20.f) ? v : __logf(1.f + __expf(v));
          else if (act == 2) v = (v >= 0.f) ? v : 0.01f * v;
          if (res) v += res[(size_t)m * ldc + n];
          if (outbf) Cb[(size_t)m * ldc + n] = f2bf(v);
          else       Cf[(size_t)m * ldc + n] = v;
        }
      }
    }
  }
}

// ---------------------------------------------------------------- x_proj split-K (N=96), 2-phase (proven)
__global__ __launch_bounds__(256) void xproj_kernel(
    const unsigned short* __restrict__ A, int lda,
    const unsigned short* __restrict__ B, int ldb,
    float* __restrict__ C)
{
  __shared__ unsigned short As[2][128 * 32];
  __shared__ unsigned short Bs[2][96 * 32];
  const int t = threadIdx.x;
  const int w = t >> 6, l = t & 63;
  const int bm = blockIdx.x * 128;
  const int kbase = blockIdx.y * 128;

  f32x4 acc[2][6] = {};

  const int srow = t >> 2;
  const int sk = (t & 3) * 8;
  const unsigned short* gA0 = A + (size_t)(bm + srow) * lda + kbase + sk;
  const unsigned short* gA1 = gA0 + (size_t)64 * lda;
  const unsigned short* gB0 = B + (size_t)srow * ldb + kbase + sk;
  const unsigned short* gB1 = gB0 + (size_t)64 * ldb;

  const int fr = l & 15;
  const int kb = (l >> 4) * 8;

#define STAGEX(buf, k0) do { \
    GLDS(gA0 + (k0), &As[buf][w * 512]); \
    GLDS(gA1 + (k0), &As[buf][2048 + w * 512]); \
    GLDS(gB0 + (k0), &Bs[buf][w * 512]); \
    if (w < 2) GLDS(gB1 + (k0), &Bs[buf][2048 + w * 512]); \
  } while (0)

#define COMPUTEX(buf) do { \
    bf16x8 af[2], bfr[6]; \
    _Pragma("unroll") \
    for (int i = 0; i < 2; ++i) \
      af[i] = *reinterpret_cast<const bf16x8*>(&As[buf][(w * 32 + i * 16 + fr) * 32 + kb]); \
    _Pragma("unroll") \
    for (int j = 0; j < 6; ++j) \
      bfr[j] = *reinterpret_cast<const bf16x8*>(&Bs[buf][(j * 16 + fr) * 32 + kb]); \
    _Pragma("unroll") \
    for (int i = 0; i < 2; ++i) \
      _Pragma("unroll") \
      for (int j = 0; j < 6; ++j) \
        acc[i][j] = __builtin_amdgcn_mfma_f32_16x16x32_bf16(af[i], bfr[j], acc[i][j], 0, 0, 0); \
  } while (0)

  STAGEX(0, 0);
  DRAIN_VM();
  __syncthreads();
  int cur = 0;
  for (int s = 1; s < 4; ++s) {
    __builtin_amdgcn_sched_barrier(0);
    STAGEX(cur ^ 1, s * 32);
    __builtin_amdgcn_sched_barrier(0);
    COMPUTEX(cur);
    DRAIN_VM();
    __syncthreads();
    cur ^= 1;
  }
  COMPUTEX(cur);
#undef STAGEX
#undef COMPUTEX

  const int crow = (l >> 4) * 4;
  const int ccol = l & 15;
#pragma unroll
  for (int i = 0; i < 2; ++i)
#pragma unroll
    for (int j = 0; j < 6; ++j)
#pragma unroll
      for (int r = 0; r < 4; ++r) {
        const int m = bm + w * 32 + i * 16 + crow + r;
        const int n = j * 16 + ccol;
        atomicAdd(&C[(size_t)m * 96 + n], acc[i][j][r]);
      }
}

// ---------------------------------------------------------------- conv(k=2)+SiLU (bf16, x8 vectorized)
__global__ __launch_bounds__(256) void conv_silu_kernel(
    const unsigned short* __restrict__ xz, const float* __restrict__ cw,
    const float* __restrict__ cb, unsigned short* __restrict__ xcb)
{
  const int i = blockIdx.x * 256 + threadIdx.x;   // 524288 threads, 8 elems each
  const int row = i >> 7;
  const int dv = (i & 127) * 8;
  const int l = row & (L_SEQ - 1);
  const u16x8 cur = *reinterpret_cast<const u16x8*>(&xz[(size_t)row * 2048 + dv]);
  u16x8 prev = {};
  if (l != 0) prev = *reinterpret_cast<const u16x8*>(&xz[(size_t)(row - 1) * 2048 + dv]);
  float cwv[16], cbv[8];
#pragma unroll
  for (int qq = 0; qq < 4; ++qq)
    *reinterpret_cast<float4*>(&cwv[qq * 4]) = reinterpret_cast<const float4*>(cw + 2 * dv)[qq];
#pragma unroll
  for (int qq = 0; qq < 2; ++qq)
    *reinterpret_cast<float4*>(&cbv[qq * 4]) = reinterpret_cast<const float4*>(cb + dv)[qq];
  u16x8 o;
#pragma unroll
  for (int e = 0; e < 8; ++e) {
    const float v = bf2f(prev[e]) * cwv[2 * e] + bf2f(cur[e]) * cwv[2 * e + 1] + cbv[e];
    o[e] = f2bf(v / (1.f + __expf(-v)));
  }
  *reinterpret_cast<u16x8*>(&xcb[(size_t)row * 1024 + dv]) = o;
}

// ---------------------------------------------------------------- scan pass 1 (bf16 in, bf16 state out)
__global__ __launch_bounds__(256) void scan_pass1(
    const unsigned short* __restrict__ delta, const unsigned short* __restrict__ xc,
    const float* __restrict__ xdbl, const float* __restrict__ A_log,
    unsigned short* __restrict__ hfin, unsigned short* __restrict__ pcum)
{
  const int tid = threadIdx.x;
  const int db = blockIdx.x & 3;
  const int c = (blockIdx.x >> 2) & (NCHUNK - 1);
  const int b = blockIdx.x >> 7;
  const int d = db * 256 + tid;
  __shared__ float Bsh[CH][16];
  {
    const int lr = tid >> 2, q = tid & 3;
    const float* p = xdbl + ((size_t)(b * L_SEQ + c * CH + lr) * 96) + 64 + q * 4;
    *reinterpret_cast<float4*>(&Bsh[lr][q * 4]) = *reinterpret_cast<const float4*>(p);
  }
  float a[NSTATE];
#pragma unroll
  for (int n = 0; n < NSTATE; ++n) a[n] = -__expf(A_log[d * 16 + n]);
  __syncthreads();
  float h[NSTATE], P[NSTATE];
#pragma unroll
  for (int n = 0; n < NSTATE; ++n) { h[n] = 0.f; P[n] = 1.f; }
  const size_t rowbase = (size_t)(b * L_SEQ + c * CH);
  for (int s = 0; s < CH; ++s) {
    const size_t row = rowbase + s;
    const float dl = bf2f(delta[row * 1024 + d]);
    const float xcv = bf2f(xc[row * 1024 + d]);
#pragma unroll
    for (int n = 0; n < NSTATE; ++n) {
      const float dA = __expf(dl * a[n]);
      h[n] = h[n] * dA + (dl * Bsh[s][n]) * xcv;
      P[n] *= dA;
    }
  }
  const size_t base = ((size_t)((b * NCHUNK + c) * 1024 + d)) * 16;
  u16x8 h0, h1, p0, p1;
#pragma unroll
  for (int n = 0; n < 8; ++n) {
    h0[n] = f2bf(h[n]);     h1[n] = f2bf(h[n + 8]);
    p0[n] = f2bf(P[n]);     p1[n] = f2bf(P[n + 8]);
  }
  *reinterpret_cast<u16x8*>(hfin + base) = h0;
  *reinterpret_cast<u16x8*>(hfin + base + 8) = h1;
  *reinterpret_cast<u16x8*>(pcum + base) = p0;
  *reinterpret_cast<u16x8*>(pcum + base + 8) = p1;
}

// ---------------------------------------------------------------- scan pass 2 (bf16 state)
__global__ __launch_bounds__(256) void scan_pass2(
    const unsigned short* __restrict__ hfin, const unsigned short* __restrict__ pcum,
    unsigned short* __restrict__ hstart)
{
  const int t = blockIdx.x * 256 + threadIdx.x;
  const int b = t >> 14;
  const int dn = t & 16383;
  const size_t base = (size_t)b * NCHUNK * 16384 + dn;
  float h = 0.f;
  for (int c = 0; c < NCHUNK; ++c) {
    const size_t idx = base + (size_t)c * 16384;
    hstart[idx] = f2bf(h);
    h = bf2f(pcum[idx]) * h + bf2f(hfin[idx]);
  }
}

// ---------------------------------------------------------------- scan pass 3 (bf16 in, bf16 y out)
__global__ __launch_bounds__(256) void scan_pass3(
    const unsigned short* __restrict__ delta, const unsigned short* __restrict__ xc,
    const float* __restrict__ xdbl, const float* __restrict__ A_log,
    const unsigned short* __restrict__ hstart, const float* __restrict__ Dp,
    const unsigned short* __restrict__ xz, unsigned short* __restrict__ yout)
{
  const int tid = threadIdx.x;
  const int db = blockIdx.x & 3;
  const int c = (blockIdx.x >> 2) & (NCHUNK - 1);
  const int b = blockIdx.x >> 7;
  const int d = db * 256 + tid;
  __shared__ float Bsh[CH][16];
  __shared__ float Csh[CH][16];
  {
    const int lr = tid >> 2, q = tid & 3;
    const float* p = xdbl + ((size_t)(b * L_SEQ + c * CH + lr) * 96);
    *reinterpret_cast<float4*>(&Bsh[lr][q * 4]) = *reinterpret_cast<const float4*>(p + 64 + q * 4);
    *reinterpret_cast<float4*>(&Csh[lr][q * 4]) = *reinterpret_cast<const float4*>(p + 80 + q * 4);
  }
  float a[NSTATE];
#pragma unroll
  for (int n = 0; n < NSTATE; ++n) a[n] = -__expf(A_log[d * 16 + n]);
  float h[NSTATE];
  {
    const size_t base = ((size_t)((b * NCHUNK + c) * 1024 + d)) * 16;
    const u16x8 v0 = *reinterpret_cast<const u16x8*>(hstart + base);
    const u16x8 v1 = *reinterpret_cast<const u16x8*>(hstart + base + 8);
#pragma unroll
    for (int n = 0; n < 8; ++n) { h[n] = bf2f(v0[n]); h[n + 8] = bf2f(v1[n]); }
  }
  const float dpv = Dp[d];
  __syncthreads();
  const size_t rowbase = (size_t)(b * L_SEQ + c * CH);
  for (int s = 0; s < CH; ++s) {
    const size_t row = rowbase + s;
    const float dl = bf2f(delta[row * 1024 + d]);
    const float xcv = bf2f(xc[row * 1024 + d]);
    float y = 0.f;
#pragma unroll
    for (int n = 0; n < NSTATE; ++n) {
      const float dA = __expf(dl * a[n]);
      h[n] = h[n] * dA + (dl * Bsh[s][n]) * xcv;
      y += h[n] * Csh[s][n];
    }
    const float z = bf2f(xz[row * 2048 + 1024 + d]);
    const float sil = z / (1.f + __expf(-z));
    yout[row * 1024 + d] = f2bf((y + xcv * dpv) * sil);
  }
}

// ---------------------------------------------------------------- launch
extern "C" void kernel_launch(void* const* d_in, const int* in_sizes, int n_in,
                              void* d_out, int out_size, void* d_ws, size_t ws_size,
                              hipStream_t stream)
{
  (void)in_sizes; (void)n_in; (void)out_size; (void)ws_size;
  const float* src        = (const float*)d_in[0];
  const float* in_proj_w  = (const float*)d_in[1];
  const float* conv_w     = (const float*)d_in[2];
  const float* conv_b     = (const float*)d_in[3];
  const float* x_proj_w   = (const float*)d_in[4];
  const float* dt_proj_w  = (const float*)d_in[5];
  const float* dt_proj_b  = (const float*)d_in[6];
  const float* A_log      = (const float*)d_in[7];
  const float* Dp         = (const float*)d_in[8];
  const float* out_proj_w = (const float*)d_in[9];
  const float* mnorm_g    = (const float*)d_in[10];
  const float* mnorm_b    = (const float*)d_in[11];
  const float* n1_g       = (const float*)d_in[12];
  const float* n1_b       = (const float*)d_in[13];
  const float* n2_g       = (const float*)d_in[14];
  const float* n2_b       = (const float*)d_in[15];
  const float* n3_g       = (const float*)d_in[16];
  const float* n3_b       = (const float*)d_in[17];
  const float* ffn_w1     = (const float*)d_in[18];
  const float* ffn_w2     = (const float*)d_in[19];
  const float* fe_w       = (const float*)d_in[20];
  const float* fe_b       = (const float*)d_in[21];
  float* out = (float*)d_out;
  float* ws  = (float*)d_ws;

  // ---- workspace layout (float offsets; ranges disjoint) ----
  unsigned short* xzb   = (unsigned short*)ws;              // u16 8388608 = f[0 .. 4194304)
  unsigned short* xdblb = (unsigned short*)(ws + 4194304);  // u16 393216  = f[.. 4390912)
  unsigned short* dtwb  = (unsigned short*)(ws + 4390912);  // u16 65536   = f[.. 4423680)
  unsigned short* deltab= (unsigned short*)(ws + 4423680);  // u16 4194304 = f[.. 6520832)
  float* xdbl  = ws + 12582912;       // f[12582912 .. 12976128)
  float* s5    = ws + 17301504;       // f[17301504 .. 21495808)
  float* src1  = ws + 21495808;       // f[21495808 .. 25690112)
  unsigned short* hfin = (unsigned short*)(ws + 25690112);  // u16 1048576
  unsigned short* pcum = (unsigned short*)(ws + 26738688);  // u16 1048576
  unsigned short* hst  = (unsigned short*)(ws + 27787264);  // u16 1048576
  unsigned short* s1b  = (unsigned short*)(ws + 28835840);  // u16 4194304
  unsigned short* xcb  = (unsigned short*)(ws + 30932992);  // u16 4194304
  unsigned short* yb   = (unsigned short*)(ws + 33030144);  // u16 4194304
  unsigned short* f1b  = (unsigned short*)(ws + 35127296);  // u16 16777216
  unsigned short* ipwb = (unsigned short*)(ws + 43515904);  // u16 2097152
  unsigned short* xpwb = (unsigned short*)(ws + 44564480);  // u16 98304
  unsigned short* opwb = (unsigned short*)(ws + 44613632);  // u16 1048576
  unsigned short* w1b  = (unsigned short*)(ws + 45137920);  // u16 4194304
  unsigned short* w2b  = (unsigned short*)(ws + 47235072);  // u16 4194304
  unsigned short* fewb = (unsigned short*)(ws + 49332224);  // u16 1048576

  const dim3 blk(256);
  const dim3 blk512(512);
  const dim3 blk1024(1024);

  // 0+1. weights -> bf16, zero xdbl, step-1 LN (single launch; 12832 + 4096 blocks)
  cvt_all_kernel<<<16928, blk, 0, stream>>>(
      in_proj_w, x_proj_w, dt_proj_w, out_proj_w, ffn_w1, ffn_w2, fe_w, xdbl,
      ipwb, xpwb, dtwb, opwb, w1b, w2b, fewb,
      src, n1_g, n1_b, s1b);

  // 2. xz = x1 @ in_proj_w^T -> bf16  (ksplit2 BK=32, 2 blocks/CU)
  gemm_ksplit_kernel<32><<<512, blk512, 0, stream>>>(s1b, 1024, ipwb, 1024, xzb, 2048,
                                                     nullptr, nullptr, 1024, 0, 1, 16);
  // 3. x_c = silu(conv(x_in)) -> bf16 (x8 vectorized)
  conv_silu_kernel<<<2048, blk, 0, stream>>>(xzb, conv_w, conv_b, xcb);
  // 4. x_dbl = x_c @ x_proj_w^T  (split-K=8, atomic f32; xdbl pre-zeroed in cvt_all)
  xproj_kernel<<<dim3(32, 8), blk, 0, stream>>>(xcb, 1024, xpwb, 1024, xdbl);
  // 4b. xdbl -> bf16 for dt_proj
  cvt_bf16_kernel<<<384, blk, 0, stream>>>(xdbl, xdblb, 98304);
  // 5. delta = softplus(dt @ dt_proj_w^T + b) -> bf16  (ksplit2 BK=32, K=64)
  gemm_ksplit_kernel<32><<<256, blk512, 0, stream>>>(xdblb, 96, dtwb, 64, deltab, 1024,
                                                     dt_proj_b, nullptr, 64, 1, 1, 8);
  // 6-8. selective scan (bf16 datapath + bf16 inter-chunk state)
  scan_pass1<<<256, blk, 0, stream>>>(deltab, xcb, xdbl, A_log, hfin, pcum);
  scan_pass2<<<128, blk, 0, stream>>>(hfin, pcum, hst);
  scan_pass3<<<256, blk, 0, stream>>>(deltab, xcb, xdbl, A_log, hst, Dp, xzb, yb);
  // 9. mamba_out = y @ out_proj_w^T  (ksplit2 BN=64, 512 blocks = 2/CU; K=1024 short-K win)
  gemm_ksplit_bn64_kernel<<<512, blk512, 0, stream>>>(yb, 1024, opwb, 1024, s5, 1024,
                                                      nullptr, nullptr, 1024, 0, 0, 16);
  // 10+11. src1 = src + LN(s5; mnorm); x2 = LN(src1; n2) -> bf16  (fused)
  ln2_kernel<<<NROWS, blk, 0, stream>>>(s5, mnorm_g, mnorm_b, src,
                                        n2_g, n2_b, src1, s1b);
  // 12. f1 = leaky(x2 @ ffn_w1^T) -> bf16  (256² ring-4 depth-3 vmcnt)
  gemm256_kernel<<<256, blk512, 0, stream>>>(s1b, 1024, w1b, 1024, f1b, 4096,
                                             nullptr, nullptr, 1024, 2, 1, 16);
  // 13. src2 = src1 + f1 @ ffn_w2^T  (ksplit4: 16 waves, 4 waves/SIMD, BN=128)
  gemm_ksplit4_kernel<<<256, blk1024, 0, stream>>>(f1b, 4096, w2b, 4096, s5, 1024,
                                                   nullptr, src1, 4096, 0, 0, 8);
  // 14. x3 = LN(src2; n3) -> bf16
  ln_kernel<<<NROWS, blk, 0, stream>>>(s5, n3_g, n3_b, nullptr, nullptr, s1b);
  // 15. out = src2 + x3 @ fe_w^T + fe_b  (ksplit2 BN=64, 512 blocks = 2/CU; K=1024 short-K win)
  gemm_ksplit_bn64_kernel<<<512, blk512, 0, stream>>>(s1b, 1024, fewb, 1024, out, 1024,
                                                      fe_b, s5, 1024, 0, 0, 16);
}

// Round 30
// 367.155 us; speedup vs baseline: 1.0319x; 1.0319x over previous
//
#include <hip/hip_runtime.h>
#include <hip/hip_bf16.h>
#include <cstddef>

#define L_SEQ   2048
#define NBATCH  2
#define NROWS   (NBATCH * L_SEQ)   /* 4096 */
#define NSTATE  16
#define CH      64
#define NCHUNK  (L_SEQ / CH)       /* 32 */

typedef __bf16 bf16x8 __attribute__((ext_vector_type(8)));
typedef float  f32x4  __attribute__((ext_vector_type(4)));
typedef unsigned short u16x4 __attribute__((ext_vector_type(4)));
typedef unsigned short u16x8 __attribute__((ext_vector_type(8)));

static __device__ __forceinline__ unsigned short f2bf(float f) {
  unsigned int x = __builtin_bit_cast(unsigned int, f);
  x += 0x7fffu + ((x >> 16) & 1u);          // RNE
  return (unsigned short)(x >> 16);
}
static __device__ __forceinline__ float bf2f(unsigned short u) {
  return __builtin_bit_cast(float, ((unsigned int)u) << 16);
}

// async global->LDS, 16B per lane; LDS dest = wave-uniform base + lane*16
#define GLDS(g, l) __builtin_amdgcn_global_load_lds( \
    (const __attribute__((address_space(1))) void*)(g), \
    (__attribute__((address_space(3))) void*)(l), 16, 0, 0)

#define DRAIN_VM() asm volatile("s_waitcnt vmcnt(0)" ::: "memory")

// ---------------------------------------------------------------- f32 -> bf16 (generic, for xdbl)
__global__ __launch_bounds__(256) void cvt_bf16_kernel(
    const float* __restrict__ in, unsigned short* __restrict__ out, int n4)
{
  const int i = blockIdx.x * 256 + threadIdx.x;
  if (i < n4) {
    const float4 v = reinterpret_cast<const float4*>(in)[i];
    u16x4 o;
    o[0] = f2bf(v.x); o[1] = f2bf(v.y); o[2] = f2bf(v.z); o[3] = f2bf(v.w);
    reinterpret_cast<u16x4*>(out)[i] = o;
  }
}

// ---------------------------------------------------------------- all weights -> bf16 + zero xdbl + step-1 LN
__global__ __launch_bounds__(256) void cvt_all_kernel(
    const float* __restrict__ ipw, const float* __restrict__ xpw,
    const float* __restrict__ dtw, const float* __restrict__ opw,
    const float* __restrict__ w1,  const float* __restrict__ w2,
    const float* __restrict__ few, float* __restrict__ zx,
    unsigned short* __restrict__ o_ipw, unsigned short* __restrict__ o_xpw,
    unsigned short* __restrict__ o_dtw, unsigned short* __restrict__ o_opw,
    unsigned short* __restrict__ o_w1,  unsigned short* __restrict__ o_w2,
    unsigned short* __restrict__ o_few,
    const float* __restrict__ lsrc, const float* __restrict__ lg,
    const float* __restrict__ lb, unsigned short* __restrict__ louth)
{
  __shared__ float sm[8];
  if (blockIdx.x >= 12832) {             // fused step-1 LayerNorm
    const int row = blockIdx.x - 12832;
    const int tid = threadIdx.x;
    const float4 v = reinterpret_cast<const float4*>(lsrc + (size_t)row * 1024)[tid];
    float s = v.x + v.y + v.z + v.w;
#pragma unroll
    for (int o = 32; o > 0; o >>= 1) s += __shfl_down(s, o, 64);
    if ((tid & 63) == 0) sm[tid >> 6] = s;
    __syncthreads();
    const float mean = (sm[0] + sm[1] + sm[2] + sm[3]) * (1.f / 1024.f);
    const float dx = v.x - mean, dy = v.y - mean, dz = v.z - mean, dw = v.w - mean;
    float q = dx * dx + dy * dy + dz * dz + dw * dw;
#pragma unroll
    for (int o = 32; o > 0; o >>= 1) q += __shfl_down(q, o, 64);
    __syncthreads();
    if ((tid & 63) == 0) sm[tid >> 6] = q;
    __syncthreads();
    const float var = (sm[0] + sm[1] + sm[2] + sm[3]) * (1.f / 1024.f);
    const float rstd = rsqrtf(var + 1e-5f);
    const float4 gv = reinterpret_cast<const float4*>(lg)[tid];
    const float4 bv = reinterpret_cast<const float4*>(lb)[tid];
    u16x4 ob;
    ob[0] = f2bf(dx * rstd * gv.x + bv.x);
    ob[1] = f2bf(dy * rstd * gv.y + bv.y);
    ob[2] = f2bf(dz * rstd * gv.z + bv.z);
    ob[3] = f2bf(dw * rstd * gv.w + bv.w);
    reinterpret_cast<u16x4*>(louth + (size_t)row * 1024)[tid] = ob;
    return;
  }
  int i = blockIdx.x * 256 + threadIdx.x;
  if (i < 98304) {                       // zero xdbl (393216 floats)
    reinterpret_cast<float4*>(zx)[i] = make_float4(0.f, 0.f, 0.f, 0.f);
    return;
  }
  i -= 98304;
  const float* src; unsigned short* dst;
  if (i < 524288)                 { src = ipw; dst = o_ipw; }
  else if ((i -= 524288) < 24576) { src = xpw; dst = o_xpw; }
  else if ((i -= 24576) < 16384)  { src = dtw; dst = o_dtw; }
  else if ((i -= 16384) < 262144) { src = opw; dst = o_opw; }
  else if ((i -= 262144) < 1048576){ src = w1; dst = o_w1; }
  else if ((i -= 1048576) < 1048576){ src = w2; dst = o_w2; }
  else if ((i -= 1048576) < 262144){ src = few; dst = o_few; }
  else return;
  const float4 v = reinterpret_cast<const float4*>(src)[i];
  u16x4 o;
  o[0] = f2bf(v.x); o[1] = f2bf(v.y); o[2] = f2bf(v.z); o[3] = f2bf(v.w);
  reinterpret_cast<u16x4*>(dst)[i] = o;
}

// ---------------------------------------------------------------- LayerNorm
__global__ __launch_bounds__(256) void ln_kernel(
    const float* __restrict__ in, const float* __restrict__ g,
    const float* __restrict__ bta, const float* __restrict__ res,
    float* __restrict__ out, unsigned short* __restrict__ outb)
{
  const int row = blockIdx.x;
  const int tid = threadIdx.x;
  __shared__ float sm[8];
  const float4 v = reinterpret_cast<const float4*>(in + (size_t)row * 1024)[tid];
  float s = v.x + v.y + v.z + v.w;
#pragma unroll
  for (int o = 32; o > 0; o >>= 1) s += __shfl_down(s, o, 64);
  if ((tid & 63) == 0) sm[tid >> 6] = s;
  __syncthreads();
  const float mean = (sm[0] + sm[1] + sm[2] + sm[3]) * (1.f / 1024.f);
  const float dx = v.x - mean, dy = v.y - mean, dz = v.z - mean, dw = v.w - mean;
  float q = dx * dx + dy * dy + dz * dz + dw * dw;
#pragma unroll
  for (int o = 32; o > 0; o >>= 1) q += __shfl_down(q, o, 64);
  __syncthreads();
  if ((tid & 63) == 0) sm[tid >> 6] = q;
  __syncthreads();
  const float var = (sm[0] + sm[1] + sm[2] + sm[3]) * (1.f / 1024.f);
  const float rstd = rsqrtf(var + 1e-5f);
  const float4 gv = reinterpret_cast<const float4*>(g)[tid];
  const float4 bv = reinterpret_cast<const float4*>(bta)[tid];
  float4 o4;
  o4.x = dx * rstd * gv.x + bv.x;
  o4.y = dy * rstd * gv.y + bv.y;
  o4.z = dz * rstd * gv.z + bv.z;
  o4.w = dw * rstd * gv.w + bv.w;
  if (outb) {
    u16x4 ob;
    ob[0] = f2bf(o4.x); ob[1] = f2bf(o4.y); ob[2] = f2bf(o4.z); ob[3] = f2bf(o4.w);
    reinterpret_cast<u16x4*>(outb + (size_t)row * 1024)[tid] = ob;
  } else {
    if (res) {
      const float4 rv = reinterpret_cast<const float4*>(res + (size_t)row * 1024)[tid];
      o4.x += rv.x; o4.y += rv.y; o4.z += rv.z; o4.w += rv.w;
    }
    reinterpret_cast<float4*>(out + (size_t)row * 1024)[tid] = o4;
  }
}

// ---------------------------------------------------------------- fused double-LayerNorm (steps 10+11)
__global__ __launch_bounds__(256) void ln2_kernel(
    const float* __restrict__ in, const float* __restrict__ g1,
    const float* __restrict__ b1, const float* __restrict__ res,
    const float* __restrict__ g2, const float* __restrict__ b2,
    float* __restrict__ out1, unsigned short* __restrict__ out2b)
{
  const int row = blockIdx.x;
  const int tid = threadIdx.x;
  __shared__ float sm[8];
  const float4 v = reinterpret_cast<const float4*>(in + (size_t)row * 1024)[tid];
  float s = v.x + v.y + v.z + v.w;
#pragma unroll
  for (int o = 32; o > 0; o >>= 1) s += __shfl_down(s, o, 64);
  if ((tid & 63) == 0) sm[tid >> 6] = s;
  __syncthreads();
  const float mean = (sm[0] + sm[1] + sm[2] + sm[3]) * (1.f / 1024.f);
  const float dx = v.x - mean, dy = v.y - mean, dz = v.z - mean, dw = v.w - mean;
  float q = dx * dx + dy * dy + dz * dz + dw * dw;
#pragma unroll
  for (int o = 32; o > 0; o >>= 1) q += __shfl_down(q, o, 64);
  __syncthreads();
  if ((tid & 63) == 0) sm[tid >> 6] = q;
  __syncthreads();
  const float var = (sm[0] + sm[1] + sm[2] + sm[3]) * (1.f / 1024.f);
  const float rstd = rsqrtf(var + 1e-5f);
  const float4 g1v = reinterpret_cast<const float4*>(g1)[tid];
  const float4 b1v = reinterpret_cast<const float4*>(b1)[tid];
  const float4 rv = reinterpret_cast<const float4*>(res + (size_t)row * 1024)[tid];
  float4 o4;
  o4.x = dx * rstd * g1v.x + b1v.x + rv.x;
  o4.y = dy * rstd * g1v.y + b1v.y + rv.y;
  o4.z = dz * rstd * g1v.z + b1v.z + rv.z;
  o4.w = dw * rstd * g1v.w + b1v.w + rv.w;
  reinterpret_cast<float4*>(out1 + (size_t)row * 1024)[tid] = o4;
  __syncthreads();
  float s2 = o4.x + o4.y + o4.z + o4.w;
#pragma unroll
  for (int o = 32; o > 0; o >>= 1) s2 += __shfl_down(s2, o, 64);
  if ((tid & 63) == 0) sm[tid >> 6] = s2;
  __syncthreads();
  const float mean2 = (sm[0] + sm[1] + sm[2] + sm[3]) * (1.f / 1024.f);
  const float ex = o4.x - mean2, ey = o4.y - mean2, ez = o4.z - mean2, ew = o4.w - mean2;
  float q2 = ex * ex + ey * ey + ez * ez + ew * ew;
#pragma unroll
  for (int o = 32; o > 0; o >>= 1) q2 += __shfl_down(q2, o, 64);
  __syncthreads();
  if ((tid & 63) == 0) sm[tid >> 6] = q2;
  __syncthreads();
  const float var2 = (sm[0] + sm[1] + sm[2] + sm[3]) * (1.f / 1024.f);
  const float rstd2 = rsqrtf(var2 + 1e-5f);
  const float4 g2v = reinterpret_cast<const float4*>(g2)[tid];
  const float4 b2v = reinterpret_cast<const float4*>(b2)[tid];
  u16x4 ob;
  ob[0] = f2bf(ex * rstd2 * g2v.x + b2v.x);
  ob[1] = f2bf(ey * rstd2 * g2v.y + b2v.y);
  ob[2] = f2bf(ez * rstd2 * g2v.z + b2v.z);
  ob[3] = f2bf(ew * rstd2 * g2v.w + b2v.w);
  reinterpret_cast<u16x4*>(out2b + (size_t)row * 1024)[tid] = ob;
}

// ---------------------------------------------------------------- bf16 GEMM, 256x256 tile, BK=32, 4-slot ring, depth-3 vmcnt (round-23 proven)
__global__ __launch_bounds__(512) void gemm256_kernel(
    const unsigned short* __restrict__ A, int lda,
    const unsigned short* __restrict__ B, int ldb,
    void* __restrict__ Cv, int ldc,
    const float* __restrict__ bias, const float* __restrict__ res,
    int K, int act, int outbf, int gy)
{
  __shared__ __align__(16) unsigned char smem[131072];
  const int t = threadIdx.x;
  const int w = t >> 6, l = t & 63;

  const int q = gridDim.x >> 3;
  const int nid = (blockIdx.x & 7) * q + (blockIdx.x >> 3);
  const int bm = (nid / gy) * 256;
  const int bn = (nid % gy) * 256;

  const int wr = (w >> 2) * 128;
  const int wc = (w & 3) * 64;
  f32x4 acc[8][4] = {};

  const int srow = t >> 2;          // 0..127
  const int sk = (t & 3) * 8;
  const unsigned short* gA = A + (size_t)(bm + srow) * lda + sk;
  const unsigned short* gB = B + (size_t)(bn + srow) * ldb + sk;

  const int fr = l & 15;
  const int kb = (l >> 4) * 8;

#define SA7(s) (smem + (s) * 16384)
#define SB7(s) (smem + 65536 + (s) * 16384)

#define STAGE7(s, k0) do { \
    GLDS(gA + (k0), SA7(s) + w * 1024); \
    GLDS(gA + (k0) + (size_t)128 * lda, SA7(s) + 8192 + w * 1024); \
    GLDS(gB + (k0), SB7(s) + w * 1024); \
    GLDS(gB + (k0) + (size_t)128 * ldb, SB7(s) + 8192 + w * 1024); \
  } while (0)

#define COMPUTE7(s) do { \
    bf16x8 af[8], bfr[4]; \
    _Pragma("unroll") \
    for (int j = 0; j < 4; ++j) \
      bfr[j] = *reinterpret_cast<const bf16x8*>((const unsigned short*)SB7(s) + (wc + j * 16 + fr) * 32 + kb); \
    _Pragma("unroll") \
    for (int i = 0; i < 8; ++i) \
      af[i] = *reinterpret_cast<const bf16x8*>((const unsigned short*)SA7(s) + (wr + i * 16 + fr) * 32 + kb); \
    _Pragma("unroll") \
    for (int i = 0; i < 8; ++i) \
      _Pragma("unroll") \
      for (int j = 0; j < 4; ++j) \
        acc[i][j] = __builtin_amdgcn_mfma_f32_16x16x32_bf16(af[i], bfr[j], acc[i][j], 0, 0, 0); \
  } while (0)

  const int nt = K >> 5;
  STAGE7(0, 0);
  if (nt > 1) STAGE7(1, 32);
  if (nt > 2) STAGE7(2, 64);
  if (nt > 2)      asm volatile("s_waitcnt vmcnt(8)" ::: "memory");
  else if (nt > 1) asm volatile("s_waitcnt vmcnt(4)" ::: "memory");
  else             asm volatile("s_waitcnt vmcnt(0)" ::: "memory");
  __builtin_amdgcn_s_barrier();
  for (int kt = 0; kt < nt; ++kt) {
    const int s = kt & 3;
    __builtin_amdgcn_sched_barrier(0);
    if (kt + 3 < nt) STAGE7((kt + 3) & 3, (kt + 3) * 32);
    __builtin_amdgcn_sched_barrier(0);
    COMPUTE7(s);
    __builtin_amdgcn_sched_barrier(0);
    if (kt + 3 < nt)      asm volatile("s_waitcnt vmcnt(8)" ::: "memory");
    else if (kt + 2 < nt) asm volatile("s_waitcnt vmcnt(4)" ::: "memory");
    else if (kt + 1 < nt) asm volatile("s_waitcnt vmcnt(0)" ::: "memory");
    __builtin_amdgcn_s_barrier();
  }
#undef STAGE7
#undef COMPUTE7
#undef SA7
#undef SB7

  const int crow = (l >> 4) * 4;
  const int ccol = l & 15;
  float* Cf = (float*)Cv;
  unsigned short* Cb = (unsigned short*)Cv;
#pragma unroll
  for (int i = 0; i < 8; ++i) {
#pragma unroll
    for (int j = 0; j < 4; ++j) {
      const int n = bn + wc + j * 16 + ccol;
      const float bv = bias ? bias[n] : 0.f;
#pragma unroll
      for (int r = 0; r < 4; ++r) {
        const int m = bm + wr + i * 16 + crow + r;
        float v = acc[i][j][r] + bv;
        if (act == 1) v = (v > 20.f) ? v : __logf(1.f + __expf(v));
        else if (act == 2) v = (v >= 0.f) ? v : 0.01f * v;
        if (res) v += res[(size_t)m * ldc + n];
        if (outbf) Cb[(size_t)m * ldc + n] = f2bf(v);
        else       Cf[(size_t)m * ldc + n] = v;
      }
    }
  }
}

// ---------------------------------------------------------------- bf16 GEMM, intra-block K-split, 2 groups, 2-phase (proven)
template<int BK>
__global__ __launch_bounds__(512) void gemm_ksplit_kernel(
    const unsigned short* __restrict__ A, int lda,
    const unsigned short* __restrict__ B, int ldb,
    void* __restrict__ Cv, int ldc,
    const float* __restrict__ bias, const float* __restrict__ res,
    int K, int act, int outbf, int gy)
{
  constexpr int ABYTES = 128 * BK * 2;
  constexpr int NISS = (BK == 32) ? 2 : 4;
  constexpr int RPI  = (BK == 32) ? 64 : 32;
  constexpr int NS   = BK / 32;
  __shared__ __align__(16) unsigned char smem[8 * ABYTES];
  const int tid = threadIdx.x;
  const int grp = tid >> 8;
  const int t = tid & 255;
  const int w = t >> 6, l = t & 63;

  const int q = gridDim.x >> 3;
  const int nid = (blockIdx.x & 7) * q + (blockIdx.x >> 3);
  const int bm = (nid / gy) * 128;
  const int bn = (nid % gy) * 128;

  const int K2 = K >> 1;
  const int koff = grp * K2;
  const int wr = (w >> 1) * 64, wc = (w & 1) * 64;
  f32x4 acc[4][4] = {};

  const int srow = (BK == 32) ? (t >> 2) : (t >> 3);
  const int sk   = (BK == 32) ? ((t & 3) * 8) : ((t & 7) * 8);
  const unsigned short* gA = A + (size_t)(bm + srow) * lda + koff + sk;
  const unsigned short* gB = B + (size_t)(bn + srow) * ldb + koff + sk;

  const int gbase = grp * 2 * ABYTES;
  const int fr = l & 15;
  const int kb = (l >> 4) * 8;

#define SAb(buf) (smem + gbase + (buf) * ABYTES)
#define SBb(buf) (smem + 4 * ABYTES + gbase + (buf) * ABYTES)

#define STAGEK(buf, k0) do { \
    _Pragma("unroll") \
    for (int ii = 0; ii < NISS; ++ii) { \
      GLDS(gA + (k0) + (size_t)ii * RPI * lda, SAb(buf) + ii * 4096 + w * 1024); \
      GLDS(gB + (k0) + (size_t)ii * RPI * ldb, SBb(buf) + ii * 4096 + w * 1024); \
    } \
  } while (0)

#define COMPUTEK(buf) do { \
    _Pragma("unroll") \
    for (int s = 0; s < NS; ++s) { \
      bf16x8 af[4], bfr[4]; \
      _Pragma("unroll") \
      for (int i = 0; i < 4; ++i) \
        af[i] = *reinterpret_cast<const bf16x8*>((const unsigned short*)SAb(buf) + (wr + i * 16 + fr) * BK + s * 32 + kb); \
      _Pragma("unroll") \
      for (int j = 0; j < 4; ++j) \
        bfr[j] = *reinterpret_cast<const bf16x8*>((const unsigned short*)SBb(buf) + (wc + j * 16 + fr) * BK + s * 32 + kb); \
      _Pragma("unroll") \
      for (int i = 0; i < 4; ++i) \
        _Pragma("unroll") \
        for (int j = 0; j < 4; ++j) \
          acc[i][j] = __builtin_amdgcn_mfma_f32_16x16x32_bf16(af[i], bfr[j], acc[i][j], 0, 0, 0); \
    } \
  } while (0)

  STAGEK(0, 0);
  DRAIN_VM();
  __syncthreads();
  int cur = 0;
  for (int k0 = BK; k0 < K2; k0 += BK) {
    __builtin_amdgcn_sched_barrier(0);
    STAGEK(cur ^ 1, k0);
    __builtin_amdgcn_sched_barrier(0);
    COMPUTEK(cur);
    DRAIN_VM();
    __syncthreads();
    cur ^= 1;
  }
  COMPUTEK(cur);
#undef STAGEK
#undef COMPUTEK
#undef SAb
#undef SBb

  __syncthreads();
  float* red = (float*)smem;
  if (grp) {
#pragma unroll
    for (int i = 0; i < 4; ++i)
#pragma unroll
      for (int j = 0; j < 4; ++j)
        *reinterpret_cast<f32x4*>(&red[(t << 6) + (i * 4 + j) * 4]) = acc[i][j];
  }
  __syncthreads();
  if (!grp) {
    const int crow = (l >> 4) * 4;
    const int ccol = l & 15;
    float* Cf = (float*)Cv;
    unsigned short* Cb = (unsigned short*)Cv;
#pragma unroll
    for (int i = 0; i < 4; ++i) {
#pragma unroll
      for (int j = 0; j < 4; ++j) {
        const f32x4 o = *reinterpret_cast<const f32x4*>(&red[(t << 6) + (i * 4 + j) * 4]);
        const int n = bn + wc + j * 16 + ccol;
        const float bv = bias ? bias[n] : 0.f;
#pragma unroll
        for (int r = 0; r < 4; ++r) {
          const int m = bm + wr + i * 16 + crow + r;
          float v = acc[i][j][r] + o[r] + bv;
          if (act == 1) v = (v > 20.f) ? v : __logf(1.f + __expf(v));
          else if (act == 2) v = (v >= 0.f) ? v : 0.01f * v;
          if (res) v += res[(size_t)m * ldc + n];
          if (outbf) Cb[(size_t)m * ldc + n] = f2bf(v);
          else       Cf[(size_t)m * ldc + n] = v;
        }
      }
    }
  }
}

// ---------------------------------------------------------------- bf16 GEMM, 128x64 tile, intra-block K-split, 2 groups, 2-phase
// Proven BETTER for short-K (K<=1024: out_proj, fe) and WORSE for long-K
// (ffn2 K=4096). Use only for K<=1024 sites.
__global__ __launch_bounds__(512) void gemm_ksplit_bn64_kernel(
    const unsigned short* __restrict__ A, int lda,
    const unsigned short* __restrict__ B, int ldb,
    void* __restrict__ Cv, int ldc,
    const float* __restrict__ bias, const float* __restrict__ res,
    int K, int act, int outbf, int gy)
{
  __shared__ __align__(16) unsigned char smem[49152];
  const int tid = threadIdx.x;
  const int grp = tid >> 8;
  const int t = tid & 255;
  const int w = t >> 6, l = t & 63;

  const int q = gridDim.x >> 3;
  const int nid = (blockIdx.x & 7) * q + (blockIdx.x >> 3);
  const int bm = (nid / gy) * 128;
  const int bn = (nid % gy) * 64;

  const int K2 = K >> 1;
  const int koff = grp * K2;
  const int wr = (w >> 1) * 64, wc = (w & 1) * 32;
  f32x4 acc[4][2] = {};

  const int srow = t >> 2;          // 0..63
  const int sk = (t & 3) * 8;
  const unsigned short* gA = A + (size_t)(bm + srow) * lda + koff + sk;
  const unsigned short* gB = B + (size_t)(bn + srow) * ldb + koff + sk;

  const int fr = l & 15;
  const int kb = (l >> 4) * 8;

#define SAn(buf) (smem + grp * 16384 + (buf) * 8192)
#define SBn(buf) (smem + 32768 + grp * 8192 + (buf) * 4096)

#define STAGEN(buf, k0) do { \
    GLDS(gA + (k0), SAn(buf) + w * 1024); \
    GLDS(gA + (k0) + (size_t)64 * lda, SAn(buf) + 4096 + w * 1024); \
    GLDS(gB + (k0), SBn(buf) + w * 1024); \
  } while (0)

#define COMPUTEN(buf) do { \
    bf16x8 af[4], bfr[2]; \
    _Pragma("unroll") \
    for (int i = 0; i < 4; ++i) \
      af[i] = *reinterpret_cast<const bf16x8*>((const unsigned short*)SAn(buf) + (wr + i * 16 + fr) * 32 + kb); \
    _Pragma("unroll") \
    for (int j = 0; j < 2; ++j) \
      bfr[j] = *reinterpret_cast<const bf16x8*>((const unsigned short*)SBn(buf) + (wc + j * 16 + fr) * 32 + kb); \
    _Pragma("unroll") \
    for (int i = 0; i < 4; ++i) \
      _Pragma("unroll") \
      for (int j = 0; j < 2; ++j) \
        acc[i][j] = __builtin_amdgcn_mfma_f32_16x16x32_bf16(af[i], bfr[j], acc[i][j], 0, 0, 0); \
  } while (0)

  STAGEN(0, 0);
  DRAIN_VM();
  __syncthreads();
  int cur = 0;
  for (int k0 = 32; k0 < K2; k0 += 32) {
    __builtin_amdgcn_sched_barrier(0);
    STAGEN(cur ^ 1, k0);
    __builtin_amdgcn_sched_barrier(0);
    COMPUTEN(cur);
    DRAIN_VM();
    __syncthreads();
    cur ^= 1;
  }
  COMPUTEN(cur);
#undef STAGEN
#undef COMPUTEN
#undef SAn
#undef SBn

  __syncthreads();
  float* red = (float*)smem;
  if (grp) {
#pragma unroll
    for (int i = 0; i < 4; ++i)
#pragma unroll
      for (int j = 0; j < 2; ++j)
        *reinterpret_cast<f32x4*>(&red[(t << 5) + (i * 2 + j) * 4]) = acc[i][j];
  }
  __syncthreads();
  if (!grp) {
    const int crow = (l >> 4) * 4;
    const int ccol = l & 15;
    float* Cf = (float*)Cv;
    unsigned short* Cb = (unsigned short*)Cv;
#pragma unroll
    for (int i = 0; i < 4; ++i) {
#pragma unroll
      for (int j = 0; j < 2; ++j) {
        const f32x4 o = *reinterpret_cast<const f32x4*>(&red[(t << 5) + (i * 2 + j) * 4]);
        const int n = bn + wc + j * 16 + ccol;
        const float bv = bias ? bias[n] : 0.f;
#pragma unroll
        for (int r = 0; r < 4; ++r) {
          const int m = bm + wr + i * 16 + crow + r;
          float v = acc[i][j][r] + o[r] + bv;
          if (act == 1) v = (v > 20.f) ? v : __logf(1.f + __expf(v));
          else if (act == 2) v = (v >= 0.f) ? v : 0.01f * v;
          if (res) v += res[(size_t)m * ldc + n];
          if (outbf) Cb[(size_t)m * ldc + n] = f2bf(v);
          else       Cf[(size_t)m * ldc + n] = v;
        }
      }
    }
  }
}

// ---------------------------------------------------------------- bf16 GEMM, intra-block K-split, 2 groups, 4-slot ring depth-3
// (round-24 proven; best for long-K steady state: ffn2 K=4096 @ 67.2 µs.
// Round-29: ksplit4 (4 groups, 16 waves) regressed to 76.5 µs — occupancy
// axis dead in all forms; the per-K-step barrier is the binding constraint.)
__global__ __launch_bounds__(512) void gemm_ksplit_ring_kernel(
    const unsigned short* __restrict__ A, int lda,
    const unsigned short* __restrict__ B, int ldb,
    void* __restrict__ Cv, int ldc,
    const float* __restrict__ bias, const float* __restrict__ res,
    int K, int act, int outbf, int gy)
{
  __shared__ __align__(16) unsigned char smem[131072];
  const int tid = threadIdx.x;
  const int grp = tid >> 8;
  const int t = tid & 255;
  const int w = t >> 6, l = t & 63;

  const int q = gridDim.x >> 3;
  const int nid = (blockIdx.x & 7) * q + (blockIdx.x >> 3);
  const int bm = (nid / gy) * 128;
  const int bn = (nid % gy) * 128;

  const int K2 = K >> 1;
  const int koff = grp * K2;
  const int wr = (w >> 1) * 64, wc = (w & 1) * 64;
  f32x4 acc[4][4] = {};

  const int srow = t >> 2;          // 0..63
  const int sk = (t & 3) * 8;
  const unsigned short* gA = A + (size_t)(bm + srow) * lda + koff + sk;
  const unsigned short* gB = B + (size_t)(bn + srow) * ldb + koff + sk;

  const int fr = l & 15;
  const int kb = (l >> 4) * 8;

#define SAr(s) (smem + grp * 32768 + (s) * 8192)
#define SBr(s) (smem + 65536 + grp * 32768 + (s) * 8192)

#define STAGER(s, k0) do { \
    GLDS(gA + (k0), SAr(s) + w * 1024); \
    GLDS(gA + (k0) + (size_t)64 * lda, SAr(s) + 4096 + w * 1024); \
    GLDS(gB + (k0), SBr(s) + w * 1024); \
    GLDS(gB + (k0) + (size_t)64 * ldb, SBr(s) + 4096 + w * 1024); \
  } while (0)

#define COMPUTER(s) do { \
    bf16x8 af[4], bfr[4]; \
    _Pragma("unroll") \
    for (int i = 0; i < 4; ++i) \
      af[i] = *reinterpret_cast<const bf16x8*>((const unsigned short*)SAr(s) + (wr + i * 16 + fr) * 32 + kb); \
    _Pragma("unroll") \
    for (int j = 0; j < 4; ++j) \
      bfr[j] = *reinterpret_cast<const bf16x8*>((const unsigned short*)SBr(s) + (wc + j * 16 + fr) * 32 + kb); \
    _Pragma("unroll") \
    for (int i = 0; i < 4; ++i) \
      _Pragma("unroll") \
      for (int j = 0; j < 4; ++j) \
        acc[i][j] = __builtin_amdgcn_mfma_f32_16x16x32_bf16(af[i], bfr[j], acc[i][j], 0, 0, 0); \
  } while (0)

  const int nt = K2 >> 5;
  STAGER(0, 0);
  if (nt > 1) STAGER(1, 32);
  if (nt > 2) STAGER(2, 64);
  if (nt > 2)      asm volatile("s_waitcnt vmcnt(8)" ::: "memory");
  else if (nt > 1) asm volatile("s_waitcnt vmcnt(4)" ::: "memory");
  else             asm volatile("s_waitcnt vmcnt(0)" ::: "memory");
  __builtin_amdgcn_s_barrier();
  for (int kt = 0; kt < nt; ++kt) {
    const int s = kt & 3;
    __builtin_amdgcn_sched_barrier(0);
    if (kt + 3 < nt) STAGER((kt + 3) & 3, (kt + 3) * 32);
    __builtin_amdgcn_sched_barrier(0);
    COMPUTER(s);
    __builtin_amdgcn_sched_barrier(0);
    if (kt + 3 < nt)      asm volatile("s_waitcnt vmcnt(8)" ::: "memory");
    else if (kt + 2 < nt) asm volatile("s_waitcnt vmcnt(4)" ::: "memory");
    else if (kt + 1 < nt) asm volatile("s_waitcnt vmcnt(0)" ::: "memory");
    __builtin_amdgcn_s_barrier();
  }
#undef STAGER
#undef COMPUTER
#undef SAr
#undef SBr

  __syncthreads();
  float* red = (float*)smem;
  if (grp) {
#pragma unroll
    for (int i = 0; i < 4; ++i)
#pragma unroll
      for (int j = 0; j < 4; ++j)
        *reinterpret_cast<f32x4*>(&red[(t << 6) + (i * 4 + j) * 4]) = acc[i][j];
  }
  __syncthreads();
  if (!grp) {
    const int crow = (l >> 4) * 4;
    const int ccol = l & 15;
    float* Cf = (float*)Cv;
    unsigned short* Cb = (unsigned short*)Cv;
#pragma unroll
    for (int i = 0; i < 4; ++i) {
#pragma unroll
      for (int j = 0; j < 4; ++j) {
        const f32x4 o = *reinterpret_cast<const f32x4*>(&red[(t << 6) + (i * 4 + j) * 4]);
        const int n = bn + wc + j * 16 + ccol;
        const float bv = bias ? bias[n] : 0.f;
#pragma unroll
        for (int r = 0; r < 4; ++r) {
          const int m = bm + wr + i * 16 + crow + r;
          float v = acc[i][j][r] + o[r] + bv;
          if (act == 1) v = (v > 20.f) ? v : __logf(1.f + __expf(v));
          else if (act == 2) v = (v >= 0.f) ? v : 0.01f * v;
          if (res) v += res[(size_t)m * ldc + n];
          if (outbf) Cb[(size_t)m * ldc + n] = f2bf(v);
          else       Cf[(size_t)m * ldc + n] = v;
        }
      }
    }
  }
}

// ---------------------------------------------------------------- x_proj split-K (N=96), 2-phase (proven)
__global__ __launch_bounds__(256) void xproj_kernel(
    const unsigned short* __restrict__ A, int lda,
    const unsigned short* __restrict__ B, int ldb,
    float* __restrict__ C)
{
  __shared__ unsigned short As[2][128 * 32];
  __shared__ unsigned short Bs[2][96 * 32];
  const int t = threadIdx.x;
  const int w = t >> 6, l = t & 63;
  const int bm = blockIdx.x * 128;
  const int kbase = blockIdx.y * 128;

  f32x4 acc[2][6] = {};

  const int srow = t >> 2;
  const int sk = (t & 3) * 8;
  const unsigned short* gA0 = A + (size_t)(bm + srow) * lda + kbase + sk;
  const unsigned short* gA1 = gA0 + (size_t)64 * lda;
  const unsigned short* gB0 = B + (size_t)srow * ldb + kbase + sk;
  const unsigned short* gB1 = gB0 + (size_t)64 * ldb;

  const int fr = l & 15;
  const int kb = (l >> 4) * 8;

#define STAGEX(buf, k0) do { \
    GLDS(gA0 + (k0), &As[buf][w * 512]); \
    GLDS(gA1 + (k0), &As[buf][2048 + w * 512]); \
    GLDS(gB0 + (k0), &Bs[buf][w * 512]); \
    if (w < 2) GLDS(gB1 + (k0), &Bs[buf][2048 + w * 512]); \
  } while (0)

#define COMPUTEX(buf) do { \
    bf16x8 af[2], bfr[6]; \
    _Pragma("unroll") \
    for (int i = 0; i < 2; ++i) \
      af[i] = *reinterpret_cast<const bf16x8*>(&As[buf][(w * 32 + i * 16 + fr) * 32 + kb]); \
    _Pragma("unroll") \
    for (int j = 0; j < 6; ++j) \
      bfr[j] = *reinterpret_cast<const bf16x8*>(&Bs[buf][(j * 16 + fr) * 32 + kb]); \
    _Pragma("unroll") \
    for (int i = 0; i < 2; ++i) \
      _Pragma("unroll") \
      for (int j = 0; j < 6; ++j) \
        acc[i][j] = __builtin_amdgcn_mfma_f32_16x16x32_bf16(af[i], bfr[j], acc[i][j], 0, 0, 0); \
  } while (0)

  STAGEX(0, 0);
  DRAIN_VM();
  __syncthreads();
  int cur = 0;
  for (int s = 1; s < 4; ++s) {
    __builtin_amdgcn_sched_barrier(0);
    STAGEX(cur ^ 1, s * 32);
    __builtin_amdgcn_sched_barrier(0);
    COMPUTEX(cur);
    DRAIN_VM();
    __syncthreads();
    cur ^= 1;
  }
  COMPUTEX(cur);
#undef STAGEX
#undef COMPUTEX

  const int crow = (l >> 4) * 4;
  const int ccol = l & 15;
#pragma unroll
  for (int i = 0; i < 2; ++i)
#pragma unroll
    for (int j = 0; j < 6; ++j)
#pragma unroll
      for (int r = 0; r < 4; ++r) {
        const int m = bm + w * 32 + i * 16 + crow + r;
        const int n = j * 16 + ccol;
        atomicAdd(&C[(size_t)m * 96 + n], acc[i][j][r]);
      }
}

// ---------------------------------------------------------------- conv(k=2)+SiLU (bf16, x8 vectorized)
__global__ __launch_bounds__(256) void conv_silu_kernel(
    const unsigned short* __restrict__ xz, const float* __restrict__ cw,
    const float* __restrict__ cb, unsigned short* __restrict__ xcb)
{
  const int i = blockIdx.x * 256 + threadIdx.x;   // 524288 threads, 8 elems each
  const int row = i >> 7;
  const int dv = (i & 127) * 8;
  const int l = row & (L_SEQ - 1);
  const u16x8 cur = *reinterpret_cast<const u16x8*>(&xz[(size_t)row * 2048 + dv]);
  u16x8 prev = {};
  if (l != 0) prev = *reinterpret_cast<const u16x8*>(&xz[(size_t)(row - 1) * 2048 + dv]);
  float cwv[16], cbv[8];
#pragma unroll
  for (int qq = 0; qq < 4; ++qq)
    *reinterpret_cast<float4*>(&cwv[qq * 4]) = reinterpret_cast<const float4*>(cw + 2 * dv)[qq];
#pragma unroll
  for (int qq = 0; qq < 2; ++qq)
    *reinterpret_cast<float4*>(&cbv[qq * 4]) = reinterpret_cast<const float4*>(cb + dv)[qq];
  u16x8 o;
#pragma unroll
  for (int e = 0; e < 8; ++e) {
    const float v = bf2f(prev[e]) * cwv[2 * e] + bf2f(cur[e]) * cwv[2 * e + 1] + cbv[e];
    o[e] = f2bf(v / (1.f + __expf(-v)));
  }
  *reinterpret_cast<u16x8*>(&xcb[(size_t)row * 1024 + dv]) = o;
}

// ---------------------------------------------------------------- scan pass 1 (bf16 in, bf16 state out)
__global__ __launch_bounds__(256) void scan_pass1(
    const unsigned short* __restrict__ delta, const unsigned short* __restrict__ xc,
    const float* __restrict__ xdbl, const float* __restrict__ A_log,
    unsigned short* __restrict__ hfin, unsigned short* __restrict__ pcum)
{
  const int tid = threadIdx.x;
  const int db = blockIdx.x & 3;
  const int c = (blockIdx.x >> 2) & (NCHUNK - 1);
  const int b = blockIdx.x >> 7;
  const int d = db * 256 + tid;
  __shared__ float Bsh[CH][16];
  {
    const int lr = tid >> 2, q = tid & 3;
    const float* p = xdbl + ((size_t)(b * L_SEQ + c * CH + lr) * 96) + 64 + q * 4;
    *reinterpret_cast<float4*>(&Bsh[lr][q * 4]) = *reinterpret_cast<const float4*>(p);
  }
  float a[NSTATE];
#pragma unroll
  for (int n = 0; n < NSTATE; ++n) a[n] = -__expf(A_log[d * 16 + n]);
  __syncthreads();
  float h[NSTATE], P[NSTATE];
#pragma unroll
  for (int n = 0; n < NSTATE; ++n) { h[n] = 0.f; P[n] = 1.f; }
  const size_t rowbase = (size_t)(b * L_SEQ + c * CH);
  for (int s = 0; s < CH; ++s) {
    const size_t row = rowbase + s;
    const float dl = bf2f(delta[row * 1024 + d]);
    const float xcv = bf2f(xc[row * 1024 + d]);
#pragma unroll
    for (int n = 0; n < NSTATE; ++n) {
      const float dA = __expf(dl * a[n]);
      h[n] = h[n] * dA + (dl * Bsh[s][n]) * xcv;
      P[n] *= dA;
    }
  }
  const size_t base = ((size_t)((b * NCHUNK + c) * 1024 + d)) * 16;
  u16x8 h0, h1, p0, p1;
#pragma unroll
  for (int n = 0; n < 8; ++n) {
    h0[n] = f2bf(h[n]);     h1[n] = f2bf(h[n + 8]);
    p0[n] = f2bf(P[n]);     p1[n] = f2bf(P[n + 8]);
  }
  *reinterpret_cast<u16x8*>(hfin + base) = h0;
  *reinterpret_cast<u16x8*>(hfin + base + 8) = h1;
  *reinterpret_cast<u16x8*>(pcum + base) = p0;
  *reinterpret_cast<u16x8*>(pcum + base + 8) = p1;
}

// ---------------------------------------------------------------- scan pass 2 (bf16 state)
__global__ __launch_bounds__(256) void scan_pass2(
    const unsigned short* __restrict__ hfin, const unsigned short* __restrict__ pcum,
    unsigned short* __restrict__ hstart)
{
  const int t = blockIdx.x * 256 + threadIdx.x;
  const int b = t >> 14;
  const int dn = t & 16383;
  const size_t base = (size_t)b * NCHUNK * 16384 + dn;
  float h = 0.f;
  for (int c = 0; c < NCHUNK; ++c) {
    const size_t idx = base + (size_t)c * 16384;
    hstart[idx] = f2bf(h);
    h = bf2f(pcum[idx]) * h + bf2f(hfin[idx]);
  }
}

// ---------------------------------------------------------------- scan pass 3 (bf16 in, bf16 y out)
__global__ __launch_bounds__(256) void scan_pass3(
    const unsigned short* __restrict__ delta, const unsigned short* __restrict__ xc,
    const float* __restrict__ xdbl, const float* __restrict__ A_log,
    const unsigned short* __restrict__ hstart, const float* __restrict__ Dp,
    const unsigned short* __restrict__ xz, unsigned short* __restrict__ yout)
{
  const int tid = threadIdx.x;
  const int db = blockIdx.x & 3;
  const int c = (blockIdx.x >> 2) & (NCHUNK - 1);
  const int b = blockIdx.x >> 7;
  const int d = db * 256 + tid;
  __shared__ float Bsh[CH][16];
  __shared__ float Csh[CH][16];
  {
    const int lr = tid >> 2, q = tid & 3;
    const float* p = xdbl + ((size_t)(b * L_SEQ + c * CH + lr) * 96);
    *reinterpret_cast<float4*>(&Bsh[lr][q * 4]) = *reinterpret_cast<const float4*>(p + 64 + q * 4);
    *reinterpret_cast<float4*>(&Csh[lr][q * 4]) = *reinterpret_cast<const float4*>(p + 80 + q * 4);
  }
  float a[NSTATE];
#pragma unroll
  for (int n = 0; n < NSTATE; ++n) a[n] = -__expf(A_log[d * 16 + n]);
  float h[NSTATE];
  {
    const size_t base = ((size_t)((b * NCHUNK + c) * 1024 + d)) * 16;
    const u16x8 v0 = *reinterpret_cast<const u16x8*>(hstart + base);
    const u16x8 v1 = *reinterpret_cast<const u16x8*>(hstart + base + 8);
#pragma unroll
    for (int n = 0; n < 8; ++n) { h[n] = bf2f(v0[n]); h[n + 8] = bf2f(v1[n]); }
  }
  const float dpv = Dp[d];
  __syncthreads();
  const size_t rowbase = (size_t)(b * L_SEQ + c * CH);
  for (int s = 0; s < CH; ++s) {
    const size_t row = rowbase + s;
    const float dl = bf2f(delta[row * 1024 + d]);
    const float xcv = bf2f(xc[row * 1024 + d]);
    float y = 0.f;
#pragma unroll
    for (int n = 0; n < NSTATE; ++n) {
      const float dA = __expf(dl * a[n]);
      h[n] = h[n] * dA + (dl * Bsh[s][n]) * xcv;
      y += h[n] * Csh[s][n];
    }
    const float z = bf2f(xz[row * 2048 + 1024 + d]);
    const float sil = z / (1.f + __expf(-z));
    yout[row * 1024 + d] = f2bf((y + xcv * dpv) * sil);
  }
}

// ---------------------------------------------------------------- launch
extern "C" void kernel_launch(void* const* d_in, const int* in_sizes, int n_in,
                              void* d_out, int out_size, void* d_ws, size_t ws_size,
                              hipStream_t stream)
{
  (void)in_sizes; (void)n_in; (void)out_size; (void)ws_size;
  const float* src        = (const float*)d_in[0];
  const float* in_proj_w  = (const float*)d_in[1];
  const float* conv_w     = (const float*)d_in[2];
  const float* conv_b     = (const float*)d_in[3];
  const float* x_proj_w   = (const float*)d_in[4];
  const float* dt_proj_w  = (const float*)d_in[5];
  const float* dt_proj_b  = (const float*)d_in[6];
  const float* A_log      = (const float*)d_in[7];
  const float* Dp         = (const float*)d_in[8];
  const float* out_proj_w = (const float*)d_in[9];
  const float* mnorm_g    = (const float*)d_in[10];
  const float* mnorm_b    = (const float*)d_in[11];
  const float* n1_g       = (const float*)d_in[12];
  const float* n1_b       = (const float*)d_in[13];
  const float* n2_g       = (const float*)d_in[14];
  const float* n2_b       = (const float*)d_in[15];
  const float* n3_g       = (const float*)d_in[16];
  const float* n3_b       = (const float*)d_in[17];
  const float* ffn_w1     = (const float*)d_in[18];
  const float* ffn_w2     = (const float*)d_in[19];
  const float* fe_w       = (const float*)d_in[20];
  const float* fe_b       = (const float*)d_in[21];
  float* out = (float*)d_out;
  float* ws  = (float*)d_ws;

  // ---- workspace layout (float offsets; ranges disjoint) ----
  unsigned short* xzb   = (unsigned short*)ws;              // u16 8388608 = f[0 .. 4194304)
  unsigned short* xdblb = (unsigned short*)(ws + 4194304);  // u16 393216  = f[.. 4390912)
  unsigned short* dtwb  = (unsigned short*)(ws + 4390912);  // u16 65536   = f[.. 4423680)
  unsigned short* deltab= (unsigned short*)(ws + 4423680);  // u16 4194304 = f[.. 6520832)
  float* xdbl  = ws + 12582912;       // f[12582912 .. 12976128)
  float* s5    = ws + 17301504;       // f[17301504 .. 21495808)
  float* src1  = ws + 21495808;       // f[21495808 .. 25690112)
  unsigned short* hfin = (unsigned short*)(ws + 25690112);  // u16 1048576
  unsigned short* pcum = (unsigned short*)(ws + 26738688);  // u16 1048576
  unsigned short* hst  = (unsigned short*)(ws + 27787264);  // u16 1048576
  unsigned short* s1b  = (unsigned short*)(ws + 28835840);  // u16 4194304
  unsigned short* xcb  = (unsigned short*)(ws + 30932992);  // u16 4194304
  unsigned short* yb   = (unsigned short*)(ws + 33030144);  // u16 4194304
  unsigned short* f1b  = (unsigned short*)(ws + 35127296);  // u16 16777216
  unsigned short* ipwb = (unsigned short*)(ws + 43515904);  // u16 2097152
  unsigned short* xpwb = (unsigned short*)(ws + 44564480);  // u16 98304
  unsigned short* opwb = (unsigned short*)(ws + 44613632);  // u16 1048576
  unsigned short* w1b  = (unsigned short*)(ws + 45137920);  // u16 4194304
  unsigned short* w2b  = (unsigned short*)(ws + 47235072);  // u16 4194304
  unsigned short* fewb = (unsigned short*)(ws + 49332224);  // u16 1048576

  const dim3 blk(256);
  const dim3 blk512(512);

  // 0+1. weights -> bf16, zero xdbl, step-1 LN (single launch; 12832 + 4096 blocks)
  cvt_all_kernel<<<16928, blk, 0, stream>>>(
      in_proj_w, x_proj_w, dt_proj_w, out_proj_w, ffn_w1, ffn_w2, fe_w, xdbl,
      ipwb, xpwb, dtwb, opwb, w1b, w2b, fewb,
      src, n1_g, n1_b, s1b);

  // 2. xz = x1 @ in_proj_w^T -> bf16  (ksplit2 BK=32, 2 blocks/CU)
  gemm_ksplit_kernel<32><<<512, blk512, 0, stream>>>(s1b, 1024, ipwb, 1024, xzb, 2048,
                                                     nullptr, nullptr, 1024, 0, 1, 16);
  // 3. x_c = silu(conv(x_in)) -> bf16 (x8 vectorized)
  conv_silu_kernel<<<2048, blk, 0, stream>>>(xzb, conv_w, conv_b, xcb);
  // 4. x_dbl = x_c @ x_proj_w^T  (split-K=8, atomic f32; xdbl pre-zeroed in cvt_all)
  xproj_kernel<<<dim3(32, 8), blk, 0, stream>>>(xcb, 1024, xpwb, 1024, xdbl);
  // 4b. xdbl -> bf16 for dt_proj
  cvt_bf16_kernel<<<384, blk, 0, stream>>>(xdbl, xdblb, 98304);
  // 5. delta = softplus(dt @ dt_proj_w^T + b) -> bf16  (ksplit2 BK=32, K=64)
  gemm_ksplit_kernel<32><<<256, blk512, 0, stream>>>(xdblb, 96, dtwb, 64, deltab, 1024,
                                                     dt_proj_b, nullptr, 64, 1, 1, 8);
  // 6-8. selective scan (bf16 datapath + bf16 inter-chunk state)
  scan_pass1<<<256, blk, 0, stream>>>(deltab, xcb, xdbl, A_log, hfin, pcum);
  scan_pass2<<<128, blk, 0, stream>>>(hfin, pcum, hst);
  scan_pass3<<<256, blk, 0, stream>>>(deltab, xcb, xdbl, A_log, hst, Dp, xzb, yb);
  // 9. mamba_out = y @ out_proj_w^T  (ksplit2 BN=64, 512 blocks = 2/CU; K=1024 short-K win)
  gemm_ksplit_bn64_kernel<<<512, blk512, 0, stream>>>(yb, 1024, opwb, 1024, s5, 1024,
                                                      nullptr, nullptr, 1024, 0, 0, 16);
  // 10+11. src1 = src + LN(s5; mnorm); x2 = LN(src1; n2) -> bf16  (fused)
  ln2_kernel<<<NROWS, blk, 0, stream>>>(s5, mnorm_g, mnorm_b, src,
                                        n2_g, n2_b, src1, s1b);
  // 12. f1 = leaky(x2 @ ffn_w1^T) -> bf16  (256² ring-4 depth-3 vmcnt)
  gemm256_kernel<<<256, blk512, 0, stream>>>(s1b, 1024, w1b, 1024, f1b, 4096,
                                             nullptr, nullptr, 1024, 2, 1, 16);
  // 13. src2 = src1 + f1 @ ffn_w2^T  (ksplit2 ring-4 depth-3; K=4096 long-K — ring wins)
  gemm_ksplit_ring_kernel<<<256, blk512, 0, stream>>>(f1b, 4096, w2b, 4096, s5, 1024,
                                                      nullptr, src1, 4096, 0, 0, 8);
  // 14. x3 = LN(src2; n3) -> bf16
  ln_kernel<<<NROWS, blk, 0, stream>>>(s5, n3_g, n3_b, nullptr, nullptr, s1b);
  // 15. out = src2 + x3 @ fe_w^T + fe_b  (ksplit2 BN=64, 512 blocks = 2/CU; K=1024 short-K win)
  gemm_ksplit_bn64_kernel<<<512, blk512, 0, stream>>>(s1b, 1024, fewb, 1024, out, 1024,
                                                      fe_b, s5, 1024, 0, 0, 16);
}

// Round 31
// 366.414 us; speedup vs baseline: 1.0340x; 1.0020x over previous
//
#include <hip/hip_runtime.h>
#include <hip/hip_bf16.h>
#include <cstddef>

#define L_SEQ   2048
#define NBATCH  2
#define NROWS   (NBATCH * L_SEQ)   /* 4096 */
#define NSTATE  16
#define CH      64
#define NCHUNK  (L_SEQ / CH)       /* 32 */

typedef __bf16 bf16x8 __attribute__((ext_vector_type(8)));
typedef float  f32x4  __attribute__((ext_vector_type(4)));
typedef unsigned short u16x4 __attribute__((ext_vector_type(4)));
typedef unsigned short u16x8 __attribute__((ext_vector_type(8)));

static __device__ __forceinline__ unsigned short f2bf(float f) {
  unsigned int x = __builtin_bit_cast(unsigned int, f);
  x += 0x7fffu + ((x >> 16) & 1u);          // RNE
  return (unsigned short)(x >> 16);
}
static __device__ __forceinline__ float bf2f(unsigned short u) {
  return __builtin_bit_cast(float, ((unsigned int)u) << 16);
}

// async global->LDS, 16B per lane; LDS dest = wave-uniform base + lane*16
#define GLDS(g, l) __builtin_amdgcn_global_load_lds( \
    (const __attribute__((address_space(1))) void*)(g), \
    (__attribute__((address_space(3))) void*)(l), 16, 0, 0)

#define DRAIN_VM() asm volatile("s_waitcnt vmcnt(0)" ::: "memory")

// ---------------------------------------------------------------- f32 -> bf16 (generic, for xdbl)
__global__ __launch_bounds__(256) void cvt_bf16_kernel(
    const float* __restrict__ in, unsigned short* __restrict__ out, int n4)
{
  const int i = blockIdx.x * 256 + threadIdx.x;
  if (i < n4) {
    const float4 v = reinterpret_cast<const float4*>(in)[i];
    u16x4 o;
    o[0] = f2bf(v.x); o[1] = f2bf(v.y); o[2] = f2bf(v.z); o[3] = f2bf(v.w);
    reinterpret_cast<u16x4*>(out)[i] = o;
  }
}

// ---------------------------------------------------------------- all weights -> bf16 + zero xdbl + step-1 LN
__global__ __launch_bounds__(256) void cvt_all_kernel(
    const float* __restrict__ ipw, const float* __restrict__ xpw,
    const float* __restrict__ dtw, const float* __restrict__ opw,
    const float* __restrict__ w1,  const float* __restrict__ w2,
    const float* __restrict__ few, float* __restrict__ zx,
    unsigned short* __restrict__ o_ipw, unsigned short* __restrict__ o_xpw,
    unsigned short* __restrict__ o_dtw, unsigned short* __restrict__ o_opw,
    unsigned short* __restrict__ o_w1,  unsigned short* __restrict__ o_w2,
    unsigned short* __restrict__ o_few,
    const float* __restrict__ lsrc, const float* __restrict__ lg,
    const float* __restrict__ lb, unsigned short* __restrict__ louth)
{
  __shared__ float sm[8];
  if (blockIdx.x >= 12832) {             // fused step-1 LayerNorm
    const int row = blockIdx.x - 12832;
    const int tid = threadIdx.x;
    const float4 v = reinterpret_cast<const float4*>(lsrc + (size_t)row * 1024)[tid];
    float s = v.x + v.y + v.z + v.w;
#pragma unroll
    for (int o = 32; o > 0; o >>= 1) s += __shfl_down(s, o, 64);
    if ((tid & 63) == 0) sm[tid >> 6] = s;
    __syncthreads();
    const float mean = (sm[0] + sm[1] + sm[2] + sm[3]) * (1.f / 1024.f);
    const float dx = v.x - mean, dy = v.y - mean, dz = v.z - mean, dw = v.w - mean;
    float q = dx * dx + dy * dy + dz * dz + dw * dw;
#pragma unroll
    for (int o = 32; o > 0; o >>= 1) q += __shfl_down(q, o, 64);
    __syncthreads();
    if ((tid & 63) == 0) sm[tid >> 6] = q;
    __syncthreads();
    const float var = (sm[0] + sm[1] + sm[2] + sm[3]) * (1.f / 1024.f);
    const float rstd = rsqrtf(var + 1e-5f);
    const float4 gv = reinterpret_cast<const float4*>(lg)[tid];
    const float4 bv = reinterpret_cast<const float4*>(lb)[tid];
    u16x4 ob;
    ob[0] = f2bf(dx * rstd * gv.x + bv.x);
    ob[1] = f2bf(dy * rstd * gv.y + bv.y);
    ob[2] = f2bf(dz * rstd * gv.z + bv.z);
    ob[3] = f2bf(dw * rstd * gv.w + bv.w);
    reinterpret_cast<u16x4*>(louth + (size_t)row * 1024)[tid] = ob;
    return;
  }
  int i = blockIdx.x * 256 + threadIdx.x;
  if (i < 98304) {                       // zero xdbl (393216 floats)
    reinterpret_cast<float4*>(zx)[i] = make_float4(0.f, 0.f, 0.f, 0.f);
    return;
  }
  i -= 98304;
  const float* src; unsigned short* dst;
  if (i < 524288)                 { src = ipw; dst = o_ipw; }
  else if ((i -= 524288) < 24576) { src = xpw; dst = o_xpw; }
  else if ((i -= 24576) < 16384)  { src = dtw; dst = o_dtw; }
  else if ((i -= 16384) < 262144) { src = opw; dst = o_opw; }
  else if ((i -= 262144) < 1048576){ src = w1; dst = o_w1; }
  else if ((i -= 1048576) < 1048576){ src = w2; dst = o_w2; }
  else if ((i -= 1048576) < 262144){ src = few; dst = o_few; }
  else return;
  const float4 v = reinterpret_cast<const float4*>(src)[i];
  u16x4 o;
  o[0] = f2bf(v.x); o[1] = f2bf(v.y); o[2] = f2bf(v.z); o[3] = f2bf(v.w);
  reinterpret_cast<u16x4*>(dst)[i] = o;
}

// ---------------------------------------------------------------- LayerNorm
__global__ __launch_bounds__(256) void ln_kernel(
    const float* __restrict__ in, const float* __restrict__ g,
    const float* __restrict__ bta, const float* __restrict__ res,
    float* __restrict__ out, unsigned short* __restrict__ outb)
{
  const int row = blockIdx.x;
  const int tid = threadIdx.x;
  __shared__ float sm[8];
  const float4 v = reinterpret_cast<const float4*>(in + (size_t)row * 1024)[tid];
  float s = v.x + v.y + v.z + v.w;
#pragma unroll
  for (int o = 32; o > 0; o >>= 1) s += __shfl_down(s, o, 64);
  if ((tid & 63) == 0) sm[tid >> 6] = s;
  __syncthreads();
  const float mean = (sm[0] + sm[1] + sm[2] + sm[3]) * (1.f / 1024.f);
  const float dx = v.x - mean, dy = v.y - mean, dz = v.z - mean, dw = v.w - mean;
  float q = dx * dx + dy * dy + dz * dz + dw * dw;
#pragma unroll
  for (int o = 32; o > 0; o >>= 1) q += __shfl_down(q, o, 64);
  __syncthreads();
  if ((tid & 63) == 0) sm[tid >> 6] = q;
  __syncthreads();
  const float var = (sm[0] + sm[1] + sm[2] + sm[3]) * (1.f / 1024.f);
  const float rstd = rsqrtf(var + 1e-5f);
  const float4 gv = reinterpret_cast<const float4*>(g)[tid];
  const float4 bv = reinterpret_cast<const float4*>(bta)[tid];
  float4 o4;
  o4.x = dx * rstd * gv.x + bv.x;
  o4.y = dy * rstd * gv.y + bv.y;
  o4.z = dz * rstd * gv.z + bv.z;
  o4.w = dw * rstd * gv.w + bv.w;
  if (outb) {
    u16x4 ob;
    ob[0] = f2bf(o4.x); ob[1] = f2bf(o4.y); ob[2] = f2bf(o4.z); ob[3] = f2bf(o4.w);
    reinterpret_cast<u16x4*>(outb + (size_t)row * 1024)[tid] = ob;
  } else {
    if (res) {
      const float4 rv = reinterpret_cast<const float4*>(res + (size_t)row * 1024)[tid];
      o4.x += rv.x; o4.y += rv.y; o4.z += rv.z; o4.w += rv.w;
    }
    reinterpret_cast<float4*>(out + (size_t)row * 1024)[tid] = o4;
  }
}

// ---------------------------------------------------------------- fused double-LayerNorm (steps 10+11)
__global__ __launch_bounds__(256) void ln2_kernel(
    const float* __restrict__ in, const float* __restrict__ g1,
    const float* __restrict__ b1, const float* __restrict__ res,
    const float* __restrict__ g2, const float* __restrict__ b2,
    float* __restrict__ out1, unsigned short* __restrict__ out2b)
{
  const int row = blockIdx.x;
  const int tid = threadIdx.x;
  __shared__ float sm[8];
  const float4 v = reinterpret_cast<const float4*>(in + (size_t)row * 1024)[tid];
  float s = v.x + v.y + v.z + v.w;
#pragma unroll
  for (int o = 32; o > 0; o >>= 1) s += __shfl_down(s, o, 64);
  if ((tid & 63) == 0) sm[tid >> 6] = s;
  __syncthreads();
  const float mean = (sm[0] + sm[1] + sm[2] + sm[3]) * (1.f / 1024.f);
  const float dx = v.x - mean, dy = v.y - mean, dz = v.z - mean, dw = v.w - mean;
  float q = dx * dx + dy * dy + dz * dz + dw * dw;
#pragma unroll
  for (int o = 32; o > 0; o >>= 1) q += __shfl_down(q, o, 64);
  __syncthreads();
  if ((tid & 63) == 0) sm[tid >> 6] = q;
  __syncthreads();
  const float var = (sm[0] + sm[1] + sm[2] + sm[3]) * (1.f / 1024.f);
  const float rstd = rsqrtf(var + 1e-5f);
  const float4 g1v = reinterpret_cast<const float4*>(g1)[tid];
  const float4 b1v = reinterpret_cast<const float4*>(b1)[tid];
  const float4 rv = reinterpret_cast<const float4*>(res + (size_t)row * 1024)[tid];
  float4 o4;
  o4.x = dx * rstd * g1v.x + b1v.x + rv.x;
  o4.y = dy * rstd * g1v.y + b1v.y + rv.y;
  o4.z = dz * rstd * g1v.z + b1v.z + rv.z;
  o4.w = dw * rstd * g1v.w + b1v.w + rv.w;
  reinterpret_cast<float4*>(out1 + (size_t)row * 1024)[tid] = o4;
  __syncthreads();
  float s2 = o4.x + o4.y + o4.z + o4.w;
#pragma unroll
  for (int o = 32; o > 0; o >>= 1) s2 += __shfl_down(s2, o, 64);
  if ((tid & 63) == 0) sm[tid >> 6] = s2;
  __syncthreads();
  const float mean2 = (sm[0] + sm[1] + sm[2] + sm[3]) * (1.f / 1024.f);
  const float ex = o4.x - mean2, ey = o4.y - mean2, ez = o4.z - mean2, ew = o4.w - mean2;
  float q2 = ex * ex + ey * ey + ez * ez + ew * ew;
#pragma unroll
  for (int o = 32; o > 0; o >>= 1) q2 += __shfl_down(q2, o, 64);
  __syncthreads();
  if ((tid & 63) == 0) sm[tid >> 6] = q2;
  __syncthreads();
  const float var2 = (sm[0] + sm[1] + sm[2] + sm[3]) * (1.f / 1024.f);
  const float rstd2 = rsqrtf(var2 + 1e-5f);
  const float4 g2v = reinterpret_cast<const float4*>(g2)[tid];
  const float4 b2v = reinterpret_cast<const float4*>(b2)[tid];
  u16x4 ob;
  ob[0] = f2bf(ex * rstd2 * g2v.x + b2v.x);
  ob[1] = f2bf(ey * rstd2 * g2v.y + b2v.y);
  ob[2] = f2bf(ez * rstd2 * g2v.z + b2v.z);
  ob[3] = f2bf(ew * rstd2 * g2v.w + b2v.w);
  reinterpret_cast<u16x4*>(out2b + (size_t)row * 1024)[tid] = ob;
}

// ---------------------------------------------------------------- bf16 GEMM, 256x256 tile, BK=32, 4-slot ring, depth-3 vmcnt (round-23 proven)
__global__ __launch_bounds__(512) void gemm256_kernel(
    const unsigned short* __restrict__ A, int lda,
    const unsigned short* __restrict__ B, int ldb,
    void* __restrict__ Cv, int ldc,
    const float* __restrict__ bias, const float* __restrict__ res,
    int K, int act, int outbf, int gy)
{
  __shared__ __align__(16) unsigned char smem[131072];
  const int t = threadIdx.x;
  const int w = t >> 6, l = t & 63;

  const int q = gridDim.x >> 3;
  const int nid = (blockIdx.x & 7) * q + (blockIdx.x >> 3);
  const int bm = (nid / gy) * 256;
  const int bn = (nid % gy) * 256;

  const int wr = (w >> 2) * 128;
  const int wc = (w & 3) * 64;
  f32x4 acc[8][4] = {};

  const int srow = t >> 2;          // 0..127
  const int sk = (t & 3) * 8;
  const unsigned short* gA = A + (size_t)(bm + srow) * lda + sk;
  const unsigned short* gB = B + (size_t)(bn + srow) * ldb + sk;

  const int fr = l & 15;
  const int kb = (l >> 4) * 8;

#define SA7(s) (smem + (s) * 16384)
#define SB7(s) (smem + 65536 + (s) * 16384)

#define STAGE7(s, k0) do { \
    GLDS(gA + (k0), SA7(s) + w * 1024); \
    GLDS(gA + (k0) + (size_t)128 * lda, SA7(s) + 8192 + w * 1024); \
    GLDS(gB + (k0), SB7(s) + w * 1024); \
    GLDS(gB + (k0) + (size_t)128 * ldb, SB7(s) + 8192 + w * 1024); \
  } while (0)

#define COMPUTE7(s) do { \
    bf16x8 af[8], bfr[4]; \
    _Pragma("unroll") \
    for (int j = 0; j < 4; ++j) \
      bfr[j] = *reinterpret_cast<const bf16x8*>((const unsigned short*)SB7(s) + (wc + j * 16 + fr) * 32 + kb); \
    _Pragma("unroll") \
    for (int i = 0; i < 8; ++i) \
      af[i] = *reinterpret_cast<const bf16x8*>((const unsigned short*)SA7(s) + (wr + i * 16 + fr) * 32 + kb); \
    _Pragma("unroll") \
    for (int i = 0; i < 8; ++i) \
      _Pragma("unroll") \
      for (int j = 0; j < 4; ++j) \
        acc[i][j] = __builtin_amdgcn_mfma_f32_16x16x32_bf16(af[i], bfr[j], acc[i][j], 0, 0, 0); \
  } while (0)

  const int nt = K >> 5;
  STAGE7(0, 0);
  if (nt > 1) STAGE7(1, 32);
  if (nt > 2) STAGE7(2, 64);
  if (nt > 2)      asm volatile("s_waitcnt vmcnt(8)" ::: "memory");
  else if (nt > 1) asm volatile("s_waitcnt vmcnt(4)" ::: "memory");
  else             asm volatile("s_waitcnt vmcnt(0)" ::: "memory");
  __builtin_amdgcn_s_barrier();
  for (int kt = 0; kt < nt; ++kt) {
    const int s = kt & 3;
    __builtin_amdgcn_sched_barrier(0);
    if (kt + 3 < nt) STAGE7((kt + 3) & 3, (kt + 3) * 32);
    __builtin_amdgcn_sched_barrier(0);
    COMPUTE7(s);
    __builtin_amdgcn_sched_barrier(0);
    if (kt + 3 < nt)      asm volatile("s_waitcnt vmcnt(8)" ::: "memory");
    else if (kt + 2 < nt) asm volatile("s_waitcnt vmcnt(4)" ::: "memory");
    else if (kt + 1 < nt) asm volatile("s_waitcnt vmcnt(0)" ::: "memory");
    __builtin_amdgcn_s_barrier();
  }
#undef STAGE7
#undef COMPUTE7
#undef SA7
#undef SB7

  const int crow = (l >> 4) * 4;
  const int ccol = l & 15;
  float* Cf = (float*)Cv;
  unsigned short* Cb = (unsigned short*)Cv;
#pragma unroll
  for (int i = 0; i < 8; ++i) {
#pragma unroll
    for (int j = 0; j < 4; ++j) {
      const int n = bn + wc + j * 16 + ccol;
      const float bv = bias ? bias[n] : 0.f;
#pragma unroll
      for (int r = 0; r < 4; ++r) {
        const int m = bm + wr + i * 16 + crow + r;
        float v = acc[i][j][r] + bv;
        if (act == 1) v = (v > 20.f) ? v : __logf(1.f + __expf(v));
        else if (act == 2) v = (v >= 0.f) ? v : 0.01f * v;
        if (res) v += res[(size_t)m * ldc + n];
        if (outbf) Cb[(size_t)m * ldc + n] = f2bf(v);
        else       Cf[(size_t)m * ldc + n] = v;
      }
    }
  }
}

// ---------------------------------------------------------------- bf16 GEMM, intra-block K-split, 2 groups, 2-phase (proven)
template<int BK>
__global__ __launch_bounds__(512) void gemm_ksplit_kernel(
    const unsigned short* __restrict__ A, int lda,
    const unsigned short* __restrict__ B, int ldb,
    void* __restrict__ Cv, int ldc,
    const float* __restrict__ bias, const float* __restrict__ res,
    int K, int act, int outbf, int gy)
{
  constexpr int ABYTES = 128 * BK * 2;
  constexpr int NISS = (BK == 32) ? 2 : 4;
  constexpr int RPI  = (BK == 32) ? 64 : 32;
  constexpr int NS   = BK / 32;
  __shared__ __align__(16) unsigned char smem[8 * ABYTES];
  const int tid = threadIdx.x;
  const int grp = tid >> 8;
  const int t = tid & 255;
  const int w = t >> 6, l = t & 63;

  const int q = gridDim.x >> 3;
  const int nid = (blockIdx.x & 7) * q + (blockIdx.x >> 3);
  const int bm = (nid / gy) * 128;
  const int bn = (nid % gy) * 128;

  const int K2 = K >> 1;
  const int koff = grp * K2;
  const int wr = (w >> 1) * 64, wc = (w & 1) * 64;
  f32x4 acc[4][4] = {};

  const int srow = (BK == 32) ? (t >> 2) : (t >> 3);
  const int sk   = (BK == 32) ? ((t & 3) * 8) : ((t & 7) * 8);
  const unsigned short* gA = A + (size_t)(bm + srow) * lda + koff + sk;
  const unsigned short* gB = B + (size_t)(bn + srow) * ldb + koff + sk;

  const int gbase = grp * 2 * ABYTES;
  const int fr = l & 15;
  const int kb = (l >> 4) * 8;

#define SAb(buf) (smem + gbase + (buf) * ABYTES)
#define SBb(buf) (smem + 4 * ABYTES + gbase + (buf) * ABYTES)

#define STAGEK(buf, k0) do { \
    _Pragma("unroll") \
    for (int ii = 0; ii < NISS; ++ii) { \
      GLDS(gA + (k0) + (size_t)ii * RPI * lda, SAb(buf) + ii * 4096 + w * 1024); \
      GLDS(gB + (k0) + (size_t)ii * RPI * ldb, SBb(buf) + ii * 4096 + w * 1024); \
    } \
  } while (0)

#define COMPUTEK(buf) do { \
    _Pragma("unroll") \
    for (int s = 0; s < NS; ++s) { \
      bf16x8 af[4], bfr[4]; \
      _Pragma("unroll") \
      for (int i = 0; i < 4; ++i) \
        af[i] = *reinterpret_cast<const bf16x8*>((const unsigned short*)SAb(buf) + (wr + i * 16 + fr) * BK + s * 32 + kb); \
      _Pragma("unroll") \
      for (int j = 0; j < 4; ++j) \
        bfr[j] = *reinterpret_cast<const bf16x8*>((const unsigned short*)SBb(buf) + (wc + j * 16 + fr) * BK + s * 32 + kb); \
      _Pragma("unroll") \
      for (int i = 0; i < 4; ++i) \
        _Pragma("unroll") \
        for (int j = 0; j < 4; ++j) \
          acc[i][j] = __builtin_amdgcn_mfma_f32_16x16x32_bf16(af[i], bfr[j], acc[i][j], 0, 0, 0); \
    } \
  } while (0)

  STAGEK(0, 0);
  DRAIN_VM();
  __syncthreads();
  int cur = 0;
  for (int k0 = BK; k0 < K2; k0 += BK) {
    __builtin_amdgcn_sched_barrier(0);
    STAGEK(cur ^ 1, k0);
    __builtin_amdgcn_sched_barrier(0);
    COMPUTEK(cur);
    DRAIN_VM();
    __syncthreads();
    cur ^= 1;
  }
  COMPUTEK(cur);
#undef STAGEK
#undef COMPUTEK
#undef SAb
#undef SBb

  __syncthreads();
  float* red = (float*)smem;
  if (grp) {
#pragma unroll
    for (int i = 0; i < 4; ++i)
#pragma unroll
      for (int j = 0; j < 4; ++j)
        *reinterpret_cast<f32x4*>(&red[(t << 6) + (i * 4 + j) * 4]) = acc[i][j];
  }
  __syncthreads();
  if (!grp) {
    const int crow = (l >> 4) * 4;
    const int ccol = l & 15;
    float* Cf = (float*)Cv;
    unsigned short* Cb = (unsigned short*)Cv;
#pragma unroll
    for (int i = 0; i < 4; ++i) {
#pragma unroll
      for (int j = 0; j < 4; ++j) {
        const f32x4 o = *reinterpret_cast<const f32x4*>(&red[(t << 6) + (i * 4 + j) * 4]);
        const int n = bn + wc + j * 16 + ccol;
        const float bv = bias ? bias[n] : 0.f;
#pragma unroll
        for (int r = 0; r < 4; ++r) {
          const int m = bm + wr + i * 16 + crow + r;
          float v = acc[i][j][r] + o[r] + bv;
          if (act == 1) v = (v > 20.f) ? v : __logf(1.f + __expf(v));
          else if (act == 2) v = (v >= 0.f) ? v : 0.01f * v;
          if (res) v += res[(size_t)m * ldc + n];
          if (outbf) Cb[(size_t)m * ldc + n] = f2bf(v);
          else       Cf[(size_t)m * ldc + n] = v;
        }
      }
    }
  }
}

// ---------------------------------------------------------------- bf16 GEMM, 128x64 tile, intra-block K-split, 2 groups, 2-phase
// Proven BETTER for short-K (K<=1024: out_proj, fe) and WORSE for long-K
// (ffn2 K=4096). Use only for K<=1024 sites.
__global__ __launch_bounds__(512) void gemm_ksplit_bn64_kernel(
    const unsigned short* __restrict__ A, int lda,
    const unsigned short* __restrict__ B, int ldb,
    void* __restrict__ Cv, int ldc,
    const float* __restrict__ bias, const float* __restrict__ res,
    int K, int act, int outbf, int gy)
{
  __shared__ __align__(16) unsigned char smem[49152];
  const int tid = threadIdx.x;
  const int grp = tid >> 8;
  const int t = tid & 255;
  const int w = t >> 6, l = t & 63;

  const int q = gridDim.x >> 3;
  const int nid = (blockIdx.x & 7) * q + (blockIdx.x >> 3);
  const int bm = (nid / gy) * 128;
  const int bn = (nid % gy) * 64;

  const int K2 = K >> 1;
  const int koff = grp * K2;
  const int wr = (w >> 1) * 64, wc = (w & 1) * 32;
  f32x4 acc[4][2] = {};

  const int srow = t >> 2;          // 0..63
  const int sk = (t & 3) * 8;
  const unsigned short* gA = A + (size_t)(bm + srow) * lda + koff + sk;
  const unsigned short* gB = B + (size_t)(bn + srow) * ldb + koff + sk;

  const int fr = l & 15;
  const int kb = (l >> 4) * 8;

#define SAn(buf) (smem + grp * 16384 + (buf) * 8192)
#define SBn(buf) (smem + 32768 + grp * 8192 + (buf) * 4096)

#define STAGEN(buf, k0) do { \
    GLDS(gA + (k0), SAn(buf) + w * 1024); \
    GLDS(gA + (k0) + (size_t)64 * lda, SAn(buf) + 4096 + w * 1024); \
    GLDS(gB + (k0), SBn(buf) + w * 1024); \
  } while (0)

#define COMPUTEN(buf) do { \
    bf16x8 af[4], bfr[2]; \
    _Pragma("unroll") \
    for (int i = 0; i < 4; ++i) \
      af[i] = *reinterpret_cast<const bf16x8*>((const unsigned short*)SAn(buf) + (wr + i * 16 + fr) * 32 + kb); \
    _Pragma("unroll") \
    for (int j = 0; j < 2; ++j) \
      bfr[j] = *reinterpret_cast<const bf16x8*>((const unsigned short*)SBn(buf) + (wc + j * 16 + fr) * 32 + kb); \
    _Pragma("unroll") \
    for (int i = 0; i < 4; ++i) \
      _Pragma("unroll") \
      for (int j = 0; j < 2; ++j) \
        acc[i][j] = __builtin_amdgcn_mfma_f32_16x16x32_bf16(af[i], bfr[j], acc[i][j], 0, 0, 0); \
  } while (0)

  STAGEN(0, 0);
  DRAIN_VM();
  __syncthreads();
  int cur = 0;
  for (int k0 = 32; k0 < K2; k0 += 32) {
    __builtin_amdgcn_sched_barrier(0);
    STAGEN(cur ^ 1, k0);
    __builtin_amdgcn_sched_barrier(0);
    COMPUTEN(cur);
    DRAIN_VM();
    __syncthreads();
    cur ^= 1;
  }
  COMPUTEN(cur);
#undef STAGEN
#undef COMPUTEN
#undef SAn
#undef SBn

  __syncthreads();
  float* red = (float*)smem;
  if (grp) {
#pragma unroll
    for (int i = 0; i < 4; ++i)
#pragma unroll
      for (int j = 0; j < 2; ++j)
        *reinterpret_cast<f32x4*>(&red[(t << 5) + (i * 2 + j) * 4]) = acc[i][j];
  }
  __syncthreads();
  if (!grp) {
    const int crow = (l >> 4) * 4;
    const int ccol = l & 15;
    float* Cf = (float*)Cv;
    unsigned short* Cb = (unsigned short*)Cv;
#pragma unroll
    for (int i = 0; i < 4; ++i) {
#pragma unroll
      for (int j = 0; j < 2; ++j) {
        const f32x4 o = *reinterpret_cast<const f32x4*>(&red[(t << 5) + (i * 2 + j) * 4]);
        const int n = bn + wc + j * 16 + ccol;
        const float bv = bias ? bias[n] : 0.f;
#pragma unroll
        for (int r = 0; r < 4; ++r) {
          const int m = bm + wr + i * 16 + crow + r;
          float v = acc[i][j][r] + o[r] + bv;
          if (act == 1) v = (v > 20.f) ? v : __logf(1.f + __expf(v));
          else if (act == 2) v = (v >= 0.f) ? v : 0.01f * v;
          if (res) v += res[(size_t)m * ldc + n];
          if (outbf) Cb[(size_t)m * ldc + n] = f2bf(v);
          else       Cf[(size_t)m * ldc + n] = v;
        }
      }
    }
  }
}

// ---------------------------------------------------------------- bf16 GEMM, intra-block K-split, 2 groups, 4-slot ring depth-3
// + T2 both-sides XOR swizzle (rule #21: linear LDS dest, inverse-swizzled
// GLOBAL source via sk, matching involution on ds_read via kb).
// Row r, 16B-chunk c stored at chunk c ^ ((r>>1)&3): spreads each 16-lane
// ds_read_b128 group across all 32 banks (was 8 banks -> 8-way serialize;
// SQ_LDS_BANK_CONFLICT 6.1M/dispatch on ffn2).
__global__ __launch_bounds__(512) void gemm_ksplit_ring_kernel(
    const unsigned short* __restrict__ A, int lda,
    const unsigned short* __restrict__ B, int ldb,
    void* __restrict__ Cv, int ldc,
    const float* __restrict__ bias, const float* __restrict__ res,
    int K, int act, int outbf, int gy)
{
  __shared__ __align__(16) unsigned char smem[131072];
  const int tid = threadIdx.x;
  const int grp = tid >> 8;
  const int t = tid & 255;
  const int w = t >> 6, l = t & 63;

  const int q = gridDim.x >> 3;
  const int nid = (blockIdx.x & 7) * q + (blockIdx.x >> 3);
  const int bm = (nid / gy) * 128;
  const int bn = (nid % gy) * 128;

  const int K2 = K >> 1;
  const int koff = grp * K2;
  const int wr = (w >> 1) * 64, wc = (w & 1) * 64;
  f32x4 acc[4][4] = {};

  const int srow = t >> 2;          // 0..63 (LDS row = srow; +64 for 2nd half)
  // T2 source-side swizzle: lane stages global k-chunk (t&3)^((t>>3)&3)
  // into linear LDS chunk (t&3). (row>>1)&3 == (t>>3)&3 for both halves.
  const int sk = ((t & 3) ^ ((t >> 3) & 3)) * 8;
  const unsigned short* gA = A + (size_t)(bm + srow) * lda + koff + sk;
  const unsigned short* gB = B + (size_t)(bn + srow) * ldb + koff + sk;

  const int fr = l & 15;
  // matching read involution: logical chunk (l>>4) lives at (l>>4)^((row>>1)&3),
  // (row>>1)&3 == (fr>>1)&3 == (l>>1)&3 (wr/wc/i*16/j*16 contribute 0 mod 4)
  const int kb = ((l >> 4) ^ ((l >> 1) & 3)) * 8;

#define SAr(s) (smem + grp * 32768 + (s) * 8192)
#define SBr(s) (smem + 65536 + grp * 32768 + (s) * 8192)

#define STAGER(s, k0) do { \
    GLDS(gA + (k0), SAr(s) + w * 1024); \
    GLDS(gA + (k0) + (size_t)64 * lda, SAr(s) + 4096 + w * 1024); \
    GLDS(gB + (k0), SBr(s) + w * 1024); \
    GLDS(gB + (k0) + (size_t)64 * ldb, SBr(s) + 4096 + w * 1024); \
  } while (0)

#define COMPUTER(s) do { \
    bf16x8 af[4], bfr[4]; \
    _Pragma("unroll") \
    for (int i = 0; i < 4; ++i) \
      af[i] = *reinterpret_cast<const bf16x8*>((const unsigned short*)SAr(s) + (wr + i * 16 + fr) * 32 + kb); \
    _Pragma("unroll") \
    for (int j = 0; j < 4; ++j) \
      bfr[j] = *reinterpret_cast<const bf16x8*>((const unsigned short*)SBr(s) + (wc + j * 16 + fr) * 32 + kb); \
    _Pragma("unroll") \
    for (int i = 0; i < 4; ++i) \
      _Pragma("unroll") \
      for (int j = 0; j < 4; ++j) \
        acc[i][j] = __builtin_amdgcn_mfma_f32_16x16x32_bf16(af[i], bfr[j], acc[i][j], 0, 0, 0); \
  } while (0)

  const int nt = K2 >> 5;
  STAGER(0, 0);
  if (nt > 1) STAGER(1, 32);
  if (nt > 2) STAGER(2, 64);
  if (nt > 2)      asm volatile("s_waitcnt vmcnt(8)" ::: "memory");
  else if (nt > 1) asm volatile("s_waitcnt vmcnt(4)" ::: "memory");
  else             asm volatile("s_waitcnt vmcnt(0)" ::: "memory");
  __builtin_amdgcn_s_barrier();
  for (int kt = 0; kt < nt; ++kt) {
    const int s = kt & 3;
    __builtin_amdgcn_sched_barrier(0);
    if (kt + 3 < nt) STAGER((kt + 3) & 3, (kt + 3) * 32);
    __builtin_amdgcn_sched_barrier(0);
    COMPUTER(s);
    __builtin_amdgcn_sched_barrier(0);
    if (kt + 3 < nt)      asm volatile("s_waitcnt vmcnt(8)" ::: "memory");
    else if (kt + 2 < nt) asm volatile("s_waitcnt vmcnt(4)" ::: "memory");
    else if (kt + 1 < nt) asm volatile("s_waitcnt vmcnt(0)" ::: "memory");
    __builtin_amdgcn_s_barrier();
  }
#undef STAGER
#undef COMPUTER
#undef SAr
#undef SBr

  __syncthreads();
  float* red = (float*)smem;
  if (grp) {
#pragma unroll
    for (int i = 0; i < 4; ++i)
#pragma unroll
      for (int j = 0; j < 4; ++j)
        *reinterpret_cast<f32x4*>(&red[(t << 6) + (i * 4 + j) * 4]) = acc[i][j];
  }
  __syncthreads();
  if (!grp) {
    const int crow = (l >> 4) * 4;
    const int ccol = l & 15;
    float* Cf = (float*)Cv;
    unsigned short* Cb = (unsigned short*)Cv;
#pragma unroll
    for (int i = 0; i < 4; ++i) {
#pragma unroll
      for (int j = 0; j < 4; ++j) {
        const f32x4 o = *reinterpret_cast<const f32x4*>(&red[(t << 6) + (i * 4 + j) * 4]);
        const int n = bn + wc + j * 16 + ccol;
        const float bv = bias ? bias[n] : 0.f;
#pragma unroll
        for (int r = 0; r < 4; ++r) {
          const int m = bm + wr + i * 16 + crow + r;
          float v = acc[i][j][r] + o[r] + bv;
          if (act == 1) v = (v > 20.f) ? v : __logf(1.f + __expf(v));
          else if (act == 2) v = (v >= 0.f) ? v : 0.01f * v;
          if (res) v += res[(size_t)m * ldc + n];
          if (outbf) Cb[(size_t)m * ldc + n] = f2bf(v);
          else       Cf[(size_t)m * ldc + n] = v;
        }
      }
    }
  }
}

// ---------------------------------------------------------------- x_proj split-K (N=96), 2-phase (proven)
__global__ __launch_bounds__(256) void xproj_kernel(
    const unsigned short* __restrict__ A, int lda,
    const unsigned short* __restrict__ B, int ldb,
    float* __restrict__ C)
{
  __shared__ unsigned short As[2][128 * 32];
  __shared__ unsigned short Bs[2][96 * 32];
  const int t = threadIdx.x;
  const int w = t >> 6, l = t & 63;
  const int bm = blockIdx.x * 128;
  const int kbase = blockIdx.y * 128;

  f32x4 acc[2][6] = {};

  const int srow = t >> 2;
  const int sk = (t & 3) * 8;
  const unsigned short* gA0 = A + (size_t)(bm + srow) * lda + kbase + sk;
  const unsigned short* gA1 = gA0 + (size_t)64 * lda;
  const unsigned short* gB0 = B + (size_t)srow * ldb + kbase + sk;
  const unsigned short* gB1 = gB0 + (size_t)64 * ldb;

  const int fr = l & 15;
  const int kb = (l >> 4) * 8;

#define STAGEX(buf, k0) do { \
    GLDS(gA0 + (k0), &As[buf][w * 512]); \
    GLDS(gA1 + (k0), &As[buf][2048 + w * 512]); \
    GLDS(gB0 + (k0), &Bs[buf][w * 512]); \
    if (w < 2) GLDS(gB1 + (k0), &Bs[buf][2048 + w * 512]); \
  } while (0)

#define COMPUTEX(buf) do { \
    bf16x8 af[2], bfr[6]; \
    _Pragma("unroll") \
    for (int i = 0; i < 2; ++i) \
      af[i] = *reinterpret_cast<const bf16x8*>(&As[buf][(w * 32 + i * 16 + fr) * 32 + kb]); \
    _Pragma("unroll") \
    for (int j = 0; j < 6; ++j) \
      bfr[j] = *reinterpret_cast<const bf16x8*>(&Bs[buf][(j * 16 + fr) * 32 + kb]); \
    _Pragma("unroll") \
    for (int i = 0; i < 2; ++i) \
      _Pragma("unroll") \
      for (int j = 0; j < 6; ++j) \
        acc[i][j] = __builtin_amdgcn_mfma_f32_16x16x32_bf16(af[i], bfr[j], acc[i][j], 0, 0, 0); \
  } while (0)

  STAGEX(0, 0);
  DRAIN_VM();
  __syncthreads();
  int cur = 0;
  for (int s = 1; s < 4; ++s) {
    __builtin_amdgcn_sched_barrier(0);
    STAGEX(cur ^ 1, s * 32);
    __builtin_amdgcn_sched_barrier(0);
    COMPUTEX(cur);
    DRAIN_VM();
    __syncthreads();
    cur ^= 1;
  }
  COMPUTEX(cur);
#undef STAGEX
#undef COMPUTEX

  const int crow = (l >> 4) * 4;
  const int ccol = l & 15;
#pragma unroll
  for (int i = 0; i < 2; ++i)
#pragma unroll
    for (int j = 0; j < 6; ++j)
#pragma unroll
      for (int r = 0; r < 4; ++r) {
        const int m = bm + w * 32 + i * 16 + crow + r;
        const int n = j * 16 + ccol;
        atomicAdd(&C[(size_t)m * 96 + n], acc[i][j][r]);
      }
}

// ---------------------------------------------------------------- conv(k=2)+SiLU (bf16, x8 vectorized)
__global__ __launch_bounds__(256) void conv_silu_kernel(
    const unsigned short* __restrict__ xz, const float* __restrict__ cw,
    const float* __restrict__ cb, unsigned short* __restrict__ xcb)
{
  const int i = blockIdx.x * 256 + threadIdx.x;   // 524288 threads, 8 elems each
  const int row = i >> 7;
  const int dv = (i & 127) * 8;
  const int l = row & (L_SEQ - 1);
  const u16x8 cur = *reinterpret_cast<const u16x8*>(&xz[(size_t)row * 2048 + dv]);
  u16x8 prev = {};
  if (l != 0) prev = *reinterpret_cast<const u16x8*>(&xz[(size_t)(row - 1) * 2048 + dv]);
  float cwv[16], cbv[8];
#pragma unroll
  for (int qq = 0; qq < 4; ++qq)
    *reinterpret_cast<float4*>(&cwv[qq * 4]) = reinterpret_cast<const float4*>(cw + 2 * dv)[qq];
#pragma unroll
  for (int qq = 0; qq < 2; ++qq)
    *reinterpret_cast<float4*>(&cbv[qq * 4]) = reinterpret_cast<const float4*>(cb + dv)[qq];
  u16x8 o;
#pragma unroll
  for (int e = 0; e < 8; ++e) {
    const float v = bf2f(prev[e]) * cwv[2 * e] + bf2f(cur[e]) * cwv[2 * e + 1] + cbv[e];
    o[e] = f2bf(v / (1.f + __expf(-v)));
  }
  *reinterpret_cast<u16x8*>(&xcb[(size_t)row * 1024 + dv]) = o;
}

// ---------------------------------------------------------------- scan pass 1 (bf16 in, bf16 state out)
__global__ __launch_bounds__(256) void scan_pass1(
    const unsigned short* __restrict__ delta, const unsigned short* __restrict__ xc,
    const float* __restrict__ xdbl, const float* __restrict__ A_log,
    unsigned short* __restrict__ hfin, unsigned short* __restrict__ pcum)
{
  const int tid = threadIdx.x;
  const int db = blockIdx.x & 3;
  const int c = (blockIdx.x >> 2) & (NCHUNK - 1);
  const int b = blockIdx.x >> 7;
  const int d = db * 256 + tid;
  __shared__ float Bsh[CH][16];
  {
    const int lr = tid >> 2, q = tid & 3;
    const float* p = xdbl + ((size_t)(b * L_SEQ + c * CH + lr) * 96) + 64 + q * 4;
    *reinterpret_cast<float4*>(&Bsh[lr][q * 4]) = *reinterpret_cast<const float4*>(p);
  }
  float a[NSTATE];
#pragma unroll
  for (int n = 0; n < NSTATE; ++n) a[n] = -__expf(A_log[d * 16 + n]);
  __syncthreads();
  float h[NSTATE], P[NSTATE];
#pragma unroll
  for (int n = 0; n < NSTATE; ++n) { h[n] = 0.f; P[n] = 1.f; }
  const size_t rowbase = (size_t)(b * L_SEQ + c * CH);
  for (int s = 0; s < CH; ++s) {
    const size_t row = rowbase + s;
    const float dl = bf2f(delta[row * 1024 + d]);
    const float xcv = bf2f(xc[row * 1024 + d]);
#pragma unroll
    for (int n = 0; n < NSTATE; ++n) {
      const float dA = __expf(dl * a[n]);
      h[n] = h[n] * dA + (dl * Bsh[s][n]) * xcv;
      P[n] *= dA;
    }
  }
  const size_t base = ((size_t)((b * NCHUNK + c) * 1024 + d)) * 16;
  u16x8 h0, h1, p0, p1;
#pragma unroll
  for (int n = 0; n < 8; ++n) {
    h0[n] = f2bf(h[n]);     h1[n] = f2bf(h[n + 8]);
    p0[n] = f2bf(P[n]);     p1[n] = f2bf(P[n + 8]);
  }
  *reinterpret_cast<u16x8*>(hfin + base) = h0;
  *reinterpret_cast<u16x8*>(hfin + base + 8) = h1;
  *reinterpret_cast<u16x8*>(pcum + base) = p0;
  *reinterpret_cast<u16x8*>(pcum + base + 8) = p1;
}

// ---------------------------------------------------------------- scan pass 2 (bf16 state)
__global__ __launch_bounds__(256) void scan_pass2(
    const unsigned short* __restrict__ hfin, const unsigned short* __restrict__ pcum,
    unsigned short* __restrict__ hstart)
{
  const int t = blockIdx.x * 256 + threadIdx.x;
  const int b = t >> 14;
  const int dn = t & 16383;
  const size_t base = (size_t)b * NCHUNK * 16384 + dn;
  float h = 0.f;
  for (int c = 0; c < NCHUNK; ++c) {
    const size_t idx = base + (size_t)c * 16384;
    hstart[idx] = f2bf(h);
    h = bf2f(pcum[idx]) * h + bf2f(hfin[idx]);
  }
}

// ---------------------------------------------------------------- scan pass 3 (bf16 in, bf16 y out)
__global__ __launch_bounds__(256) void scan_pass3(
    const unsigned short* __restrict__ delta, const unsigned short* __restrict__ xc,
    const float* __restrict__ xdbl, const float* __restrict__ A_log,
    const unsigned short* __restrict__ hstart, const float* __restrict__ Dp,
    const unsigned short* __restrict__ xz, unsigned short* __restrict__ yout)
{
  const int tid = threadIdx.x;
  const int db = blockIdx.x & 3;
  const int c = (blockIdx.x >> 2) & (NCHUNK - 1);
  const int b = blockIdx.x >> 7;
  const int d = db * 256 + tid;
  __shared__ float Bsh[CH][16];
  __shared__ float Csh[CH][16];
  {
    const int lr = tid >> 2, q = tid & 3;
    const float* p = xdbl + ((size_t)(b * L_SEQ + c * CH + lr) * 96);
    *reinterpret_cast<float4*>(&Bsh[lr][q * 4]) = *reinterpret_cast<const float4*>(p + 64 + q * 4);
    *reinterpret_cast<float4*>(&Csh[lr][q * 4]) = *reinterpret_cast<const float4*>(p + 80 + q * 4);
  }
  float a[NSTATE];
#pragma unroll
  for (int n = 0; n < NSTATE; ++n) a[n] = -__expf(A_log[d * 16 + n]);
  float h[NSTATE];
  {
    const size_t base = ((size_t)((b * NCHUNK + c) * 1024 + d)) * 16;
    const u16x8 v0 = *reinterpret_cast<const u16x8*>(hstart + base);
    const u16x8 v1 = *reinterpret_cast<const u16x8*>(hstart + base + 8);
#pragma unroll
    for (int n = 0; n < 8; ++n) { h[n] = bf2f(v0[n]); h[n + 8] = bf2f(v1[n]); }
  }
  const float dpv = Dp[d];
  __syncthreads();
  const size_t rowbase = (size_t)(b * L_SEQ + c * CH);
  for (int s = 0; s < CH; ++s) {
    const size_t row = rowbase + s;
    const float dl = bf2f(delta[row * 1024 + d]);
    const float xcv = bf2f(xc[row * 1024 + d]);
    float y = 0.f;
#pragma unroll
    for (int n = 0; n < NSTATE; ++n) {
      const float dA = __expf(dl * a[n]);
      h[n] = h[n] * dA + (dl * Bsh[s][n]) * xcv;
      y += h[n] * Csh[s][n];
    }
    const float z = bf2f(xz[row * 2048 + 1024 + d]);
    const float sil = z / (1.f + __expf(-z));
    yout[row * 1024 + d] = f2bf((y + xcv * dpv) * sil);
  }
}

// ---------------------------------------------------------------- launch
extern "C" void kernel_launch(void* const* d_in, const int* in_sizes, int n_in,
                              void* d_out, int out_size, void* d_ws, size_t ws_size,
                              hipStream_t stream)
{
  (void)in_sizes; (void)n_in; (void)out_size; (void)ws_size;
  const float* src        = (const float*)d_in[0];
  const float* in_proj_w  = (const float*)d_in[1];
  const float* conv_w     = (const float*)d_in[2];
  const float* conv_b     = (const float*)d_in[3];
  const float* x_proj_w   = (const float*)d_in[4];
  const float* dt_proj_w  = (const float*)d_in[5];
  const float* dt_proj_b  = (const float*)d_in[6];
  const float* A_log      = (const float*)d_in[7];
  const float* Dp         = (const float*)d_in[8];
  const float* out_proj_w = (const float*)d_in[9];
  const float* mnorm_g    = (const float*)d_in[10];
  const float* mnorm_b    = (const float*)d_in[11];
  const float* n1_g       = (const float*)d_in[12];
  const float* n1_b       = (const float*)d_in[13];
  const float* n2_g       = (const float*)d_in[14];
  const float* n2_b       = (const float*)d_in[15];
  const float* n3_g       = (const float*)d_in[16];
  const float* n3_b       = (const float*)d_in[17];
  const float* ffn_w1     = (const float*)d_in[18];
  const float* ffn_w2     = (const float*)d_in[19];
  const float* fe_w       = (const float*)d_in[20];
  const float* fe_b       = (const float*)d_in[21];
  float* out = (float*)d_out;
  float* ws  = (float*)d_ws;

  // ---- workspace layout (float offsets; ranges disjoint) ----
  unsigned short* xzb   = (unsigned short*)ws;              // u16 8388608 = f[0 .. 4194304)
  unsigned short* xdblb = (unsigned short*)(ws + 4194304);  // u16 393216  = f[.. 4390912)
  unsigned short* dtwb  = (unsigned short*)(ws + 4390912);  // u16 65536   = f[.. 4423680)
  unsigned short* deltab= (unsigned short*)(ws + 4423680);  // u16 4194304 = f[.. 6520832)
  float* xdbl  = ws + 12582912;       // f[12582912 .. 12976128)
  float* s5    = ws + 17301504;       // f[17301504 .. 21495808)
  float* src1  = ws + 21495808;       // f[21495808 .. 25690112)
  unsigned short* hfin = (unsigned short*)(ws + 25690112);  // u16 1048576
  unsigned short* pcum = (unsigned short*)(ws + 26738688);  // u16 1048576
  unsigned short* hst  = (unsigned short*)(ws + 27787264);  // u16 1048576
  unsigned short* s1b  = (unsigned short*)(ws + 28835840);  // u16 4194304
  unsigned short* xcb  = (unsigned short*)(ws + 30932992);  // u16 4194304
  unsigned short* yb   = (unsigned short*)(ws + 33030144);  // u16 4194304
  unsigned short* f1b  = (unsigned short*)(ws + 35127296);  // u16 16777216
  unsigned short* ipwb = (unsigned short*)(ws + 43515904);  // u16 2097152
  unsigned short* xpwb = (unsigned short*)(ws + 44564480);  // u16 98304
  unsigned short* opwb = (unsigned short*)(ws + 44613632);  // u16 1048576
  unsigned short* w1b  = (unsigned short*)(ws + 45137920);  // u16 4194304
  unsigned short* w2b  = (unsigned short*)(ws + 47235072);  // u16 4194304
  unsigned short* fewb = (unsigned short*)(ws + 49332224);  // u16 1048576

  const dim3 blk(256);
  const dim3 blk512(512);

  // 0+1. weights -> bf16, zero xdbl, step-1 LN (single launch; 12832 + 4096 blocks)
  cvt_all_kernel<<<16928, blk, 0, stream>>>(
      in_proj_w, x_proj_w, dt_proj_w, out_proj_w, ffn_w1, ffn_w2, fe_w, xdbl,
      ipwb, xpwb, dtwb, opwb, w1b, w2b, fewb,
      src, n1_g, n1_b, s1b);

  // 2. xz = x1 @ in_proj_w^T -> bf16  (ksplit2 BK=32, 2 blocks/CU)
  gemm_ksplit_kernel<32><<<512, blk512, 0, stream>>>(s1b, 1024, ipwb, 1024, xzb, 2048,
                                                     nullptr, nullptr, 1024, 0, 1, 16);
  // 3. x_c = silu(conv(x_in)) -> bf16 (x8 vectorized)
  conv_silu_kernel<<<2048, blk, 0, stream>>>(xzb, conv_w, conv_b, xcb);
  // 4. x_dbl = x_c @ x_proj_w^T  (split-K=8, atomic f32; xdbl pre-zeroed in cvt_all)
  xproj_kernel<<<dim3(32, 8), blk, 0, stream>>>(xcb, 1024, xpwb, 1024, xdbl);
  // 4b. xdbl -> bf16 for dt_proj
  cvt_bf16_kernel<<<384, blk, 0, stream>>>(xdbl, xdblb, 98304);
  // 5. delta = softplus(dt @ dt_proj_w^T + b) -> bf16  (ksplit2 BK=32, K=64)
  gemm_ksplit_kernel<32><<<256, blk512, 0, stream>>>(xdblb, 96, dtwb, 64, deltab, 1024,
                                                     dt_proj_b, nullptr, 64, 1, 1, 8);
  // 6-8. selective scan (bf16 datapath + bf16 inter-chunk state)
  scan_pass1<<<256, blk, 0, stream>>>(deltab, xcb, xdbl, A_log, hfin, pcum);
  scan_pass2<<<128, blk, 0, stream>>>(hfin, pcum, hst);
  scan_pass3<<<256, blk, 0, stream>>>(deltab, xcb, xdbl, A_log, hst, Dp, xzb, yb);
  // 9. mamba_out = y @ out_proj_w^T  (ksplit2 BN=64, 512 blocks = 2/CU; K=1024 short-K win)
  gemm_ksplit_bn64_kernel<<<512, blk512, 0, stream>>>(yb, 1024, opwb, 1024, s5, 1024,
                                                      nullptr, nullptr, 1024, 0, 0, 16);
  // 10+11. src1 = src + LN(s5; mnorm); x2 = LN(src1; n2) -> bf16  (fused)
  ln2_kernel<<<NROWS, blk, 0, stream>>>(s5, mnorm_g, mnorm_b, src,
                                        n2_g, n2_b, src1, s1b);
  // 12. f1 = leaky(x2 @ ffn_w1^T) -> bf16  (256² ring-4 depth-3 vmcnt)
  gemm256_kernel<<<256, blk512, 0, stream>>>(s1b, 1024, w1b, 1024, f1b, 4096,
                                             nullptr, nullptr, 1024, 2, 1, 16);
  // 13. src2 = src1 + f1 @ ffn_w2^T  (ksplit2 ring-4 depth-3 + T2 swizzle)
  gemm_ksplit_ring_kernel<<<256, blk512, 0, stream>>>(f1b, 4096, w2b, 4096, s5, 1024,
                                                      nullptr, src1, 4096, 0, 0, 8);
  // 14. x3 = LN(src2; n3) -> bf16
  ln_kernel<<<NROWS, blk, 0, stream>>>(s5, n3_g, n3_b, nullptr, nullptr, s1b);
  // 15. out = src2 + x3 @ fe_w^T + fe_b  (ksplit2 BN=64, 512 blocks = 2/CU; K=1024 short-K win)
  gemm_ksplit_bn64_kernel<<<512, blk512, 0, stream>>>(s1b, 1024, fewb, 1024, out, 1024,
                                                      fe_b, s5, 1024, 0, 0, 16);
}

// Round 32
// 361.897 us; speedup vs baseline: 1.0469x; 1.0125x over previous
//
#include <hip/hip_runtime.h>
#include <hip/hip_bf16.h>
#include <cstddef>

#define L_SEQ   2048
#define NBATCH  2
#define NROWS   (NBATCH * L_SEQ)   /* 4096 */
#define NSTATE  16
#define CH      64
#define NCHUNK  (L_SEQ / CH)       /* 32 */

typedef __bf16 bf16x8 __attribute__((ext_vector_type(8)));
typedef float  f32x4  __attribute__((ext_vector_type(4)));
typedef unsigned short u16x4 __attribute__((ext_vector_type(4)));
typedef unsigned short u16x8 __attribute__((ext_vector_type(8)));

static __device__ __forceinline__ unsigned short f2bf(float f) {
  unsigned int x = __builtin_bit_cast(unsigned int, f);
  x += 0x7fffu + ((x >> 16) & 1u);          // RNE
  return (unsigned short)(x >> 16);
}
static __device__ __forceinline__ float bf2f(unsigned short u) {
  return __builtin_bit_cast(float, ((unsigned int)u) << 16);
}

// async global->LDS, 16B per lane; LDS dest = wave-uniform base + lane*16
#define GLDS(g, l) __builtin_amdgcn_global_load_lds( \
    (const __attribute__((address_space(1))) void*)(g), \
    (__attribute__((address_space(3))) void*)(l), 16, 0, 0)

#define DRAIN_VM() asm volatile("s_waitcnt vmcnt(0)" ::: "memory")

// T2 both-sides XOR swizzle (proven round-31 on ring: conflicts 6.1M->1.9M,
// 67.7->64.7 us): global source k-chunk (t&3)^((t>>3)&3) staged into linear
// LDS chunk (t&3); read back with kb = ((l>>4)^((l>>1)&3))*8. Valid whenever
// LDS rows are 32 bf16 wide, staging srow = t>>2 (+64/128 offsets preserve
// (row>>1)&3 == (t>>3)&3), and read row offsets (wr/wc/i*16/j*16) are
// multiples of 4 so (row>>1)&3 == (fr>>1)&3 == (l>>1)&3.
#define SWZ_SK(t)  ((((t) & 3) ^ (((t) >> 3) & 3)) * 8)
#define SWZ_KB(l)  (((((l) >> 4) ^ (((l) >> 1) & 3))) * 8)

// ---------------------------------------------------------------- f32 -> bf16 (generic, for xdbl)
__global__ __launch_bounds__(256) void cvt_bf16_kernel(
    const float* __restrict__ in, unsigned short* __restrict__ out, int n4)
{
  const int i = blockIdx.x * 256 + threadIdx.x;
  if (i < n4) {
    const float4 v = reinterpret_cast<const float4*>(in)[i];
    u16x4 o;
    o[0] = f2bf(v.x); o[1] = f2bf(v.y); o[2] = f2bf(v.z); o[3] = f2bf(v.w);
    reinterpret_cast<u16x4*>(out)[i] = o;
  }
}

// ---------------------------------------------------------------- all weights -> bf16 + zero xdbl + step-1 LN
__global__ __launch_bounds__(256) void cvt_all_kernel(
    const float* __restrict__ ipw, const float* __restrict__ xpw,
    const float* __restrict__ dtw, const float* __restrict__ opw,
    const float* __restrict__ w1,  const float* __restrict__ w2,
    const float* __restrict__ few, float* __restrict__ zx,
    unsigned short* __restrict__ o_ipw, unsigned short* __restrict__ o_xpw,
    unsigned short* __restrict__ o_dtw, unsigned short* __restrict__ o_opw,
    unsigned short* __restrict__ o_w1,  unsigned short* __restrict__ o_w2,
    unsigned short* __restrict__ o_few,
    const float* __restrict__ lsrc, const float* __restrict__ lg,
    const float* __restrict__ lb, unsigned short* __restrict__ louth)
{
  __shared__ float sm[8];
  if (blockIdx.x >= 12832) {             // fused step-1 LayerNorm
    const int row = blockIdx.x - 12832;
    const int tid = threadIdx.x;
    const float4 v = reinterpret_cast<const float4*>(lsrc + (size_t)row * 1024)[tid];
    float s = v.x + v.y + v.z + v.w;
#pragma unroll
    for (int o = 32; o > 0; o >>= 1) s += __shfl_down(s, o, 64);
    if ((tid & 63) == 0) sm[tid >> 6] = s;
    __syncthreads();
    const float mean = (sm[0] + sm[1] + sm[2] + sm[3]) * (1.f / 1024.f);
    const float dx = v.x - mean, dy = v.y - mean, dz = v.z - mean, dw = v.w - mean;
    float q = dx * dx + dy * dy + dz * dz + dw * dw;
#pragma unroll
    for (int o = 32; o > 0; o >>= 1) q += __shfl_down(q, o, 64);
    __syncthreads();
    if ((tid & 63) == 0) sm[tid >> 6] = q;
    __syncthreads();
    const float var = (sm[0] + sm[1] + sm[2] + sm[3]) * (1.f / 1024.f);
    const float rstd = rsqrtf(var + 1e-5f);
    const float4 gv = reinterpret_cast<const float4*>(lg)[tid];
    const float4 bv = reinterpret_cast<const float4*>(lb)[tid];
    u16x4 ob;
    ob[0] = f2bf(dx * rstd * gv.x + bv.x);
    ob[1] = f2bf(dy * rstd * gv.y + bv.y);
    ob[2] = f2bf(dz * rstd * gv.z + bv.z);
    ob[3] = f2bf(dw * rstd * gv.w + bv.w);
    reinterpret_cast<u16x4*>(louth + (size_t)row * 1024)[tid] = ob;
    return;
  }
  int i = blockIdx.x * 256 + threadIdx.x;
  if (i < 98304) {                       // zero xdbl (393216 floats)
    reinterpret_cast<float4*>(zx)[i] = make_float4(0.f, 0.f, 0.f, 0.f);
    return;
  }
  i -= 98304;
  const float* src; unsigned short* dst;
  if (i < 524288)                 { src = ipw; dst = o_ipw; }
  else if ((i -= 524288) < 24576) { src = xpw; dst = o_xpw; }
  else if ((i -= 24576) < 16384)  { src = dtw; dst = o_dtw; }
  else if ((i -= 16384) < 262144) { src = opw; dst = o_opw; }
  else if ((i -= 262144) < 1048576){ src = w1; dst = o_w1; }
  else if ((i -= 1048576) < 1048576){ src = w2; dst = o_w2; }
  else if ((i -= 1048576) < 262144){ src = few; dst = o_few; }
  else return;
  const float4 v = reinterpret_cast<const float4*>(src)[i];
  u16x4 o;
  o[0] = f2bf(v.x); o[1] = f2bf(v.y); o[2] = f2bf(v.z); o[3] = f2bf(v.w);
  reinterpret_cast<u16x4*>(dst)[i] = o;
}

// ---------------------------------------------------------------- LayerNorm
__global__ __launch_bounds__(256) void ln_kernel(
    const float* __restrict__ in, const float* __restrict__ g,
    const float* __restrict__ bta, const float* __restrict__ res,
    float* __restrict__ out, unsigned short* __restrict__ outb)
{
  const int row = blockIdx.x;
  const int tid = threadIdx.x;
  __shared__ float sm[8];
  const float4 v = reinterpret_cast<const float4*>(in + (size_t)row * 1024)[tid];
  float s = v.x + v.y + v.z + v.w;
#pragma unroll
  for (int o = 32; o > 0; o >>= 1) s += __shfl_down(s, o, 64);
  if ((tid & 63) == 0) sm[tid >> 6] = s;
  __syncthreads();
  const float mean = (sm[0] + sm[1] + sm[2] + sm[3]) * (1.f / 1024.f);
  const float dx = v.x - mean, dy = v.y - mean, dz = v.z - mean, dw = v.w - mean;
  float q = dx * dx + dy * dy + dz * dz + dw * dw;
#pragma unroll
  for (int o = 32; o > 0; o >>= 1) q += __shfl_down(q, o, 64);
  __syncthreads();
  if ((tid & 63) == 0) sm[tid >> 6] = q;
  __syncthreads();
  const float var = (sm[0] + sm[1] + sm[2] + sm[3]) * (1.f / 1024.f);
  const float rstd = rsqrtf(var + 1e-5f);
  const float4 gv = reinterpret_cast<const float4*>(g)[tid];
  const float4 bv = reinterpret_cast<const float4*>(bta)[tid];
  float4 o4;
  o4.x = dx * rstd * gv.x + bv.x;
  o4.y = dy * rstd * gv.y + bv.y;
  o4.z = dz * rstd * gv.z + bv.z;
  o4.w = dw * rstd * gv.w + bv.w;
  if (outb) {
    u16x4 ob;
    ob[0] = f2bf(o4.x); ob[1] = f2bf(o4.y); ob[2] = f2bf(o4.z); ob[3] = f2bf(o4.w);
    reinterpret_cast<u16x4*>(outb + (size_t)row * 1024)[tid] = ob;
  } else {
    if (res) {
      const float4 rv = reinterpret_cast<const float4*>(res + (size_t)row * 1024)[tid];
      o4.x += rv.x; o4.y += rv.y; o4.z += rv.z; o4.w += rv.w;
    }
    reinterpret_cast<float4*>(out + (size_t)row * 1024)[tid] = o4;
  }
}

// ---------------------------------------------------------------- fused double-LayerNorm (steps 10+11)
__global__ __launch_bounds__(256) void ln2_kernel(
    const float* __restrict__ in, const float* __restrict__ g1,
    const float* __restrict__ b1, const float* __restrict__ res,
    const float* __restrict__ g2, const float* __restrict__ b2,
    float* __restrict__ out1, unsigned short* __restrict__ out2b)
{
  const int row = blockIdx.x;
  const int tid = threadIdx.x;
  __shared__ float sm[8];
  const float4 v = reinterpret_cast<const float4*>(in + (size_t)row * 1024)[tid];
  float s = v.x + v.y + v.z + v.w;
#pragma unroll
  for (int o = 32; o > 0; o >>= 1) s += __shfl_down(s, o, 64);
  if ((tid & 63) == 0) sm[tid >> 6] = s;
  __syncthreads();
  const float mean = (sm[0] + sm[1] + sm[2] + sm[3]) * (1.f / 1024.f);
  const float dx = v.x - mean, dy = v.y - mean, dz = v.z - mean, dw = v.w - mean;
  float q = dx * dx + dy * dy + dz * dz + dw * dw;
#pragma unroll
  for (int o = 32; o > 0; o >>= 1) q += __shfl_down(q, o, 64);
  __syncthreads();
  if ((tid & 63) == 0) sm[tid >> 6] = q;
  __syncthreads();
  const float var = (sm[0] + sm[1] + sm[2] + sm[3]) * (1.f / 1024.f);
  const float rstd = rsqrtf(var + 1e-5f);
  const float4 g1v = reinterpret_cast<const float4*>(g1)[tid];
  const float4 b1v = reinterpret_cast<const float4*>(b1)[tid];
  const float4 rv = reinterpret_cast<const float4*>(res + (size_t)row * 1024)[tid];
  float4 o4;
  o4.x = dx * rstd * g1v.x + b1v.x + rv.x;
  o4.y = dy * rstd * g1v.y + b1v.y + rv.y;
  o4.z = dz * rstd * g1v.z + b1v.z + rv.z;
  o4.w = dw * rstd * g1v.w + b1v.w + rv.w;
  reinterpret_cast<float4*>(out1 + (size_t)row * 1024)[tid] = o4;
  __syncthreads();
  float s2 = o4.x + o4.y + o4.z + o4.w;
#pragma unroll
  for (int o = 32; o > 0; o >>= 1) s2 += __shfl_down(s2, o, 64);
  if ((tid & 63) == 0) sm[tid >> 6] = s2;
  __syncthreads();
  const float mean2 = (sm[0] + sm[1] + sm[2] + sm[3]) * (1.f / 1024.f);
  const float ex = o4.x - mean2, ey = o4.y - mean2, ez = o4.z - mean2, ew = o4.w - mean2;
  float q2 = ex * ex + ey * ey + ez * ez + ew * ew;
#pragma unroll
  for (int o = 32; o > 0; o >>= 1) q2 += __shfl_down(q2, o, 64);
  __syncthreads();
  if ((tid & 63) == 0) sm[tid >> 6] = q2;
  __syncthreads();
  const float var2 = (sm[0] + sm[1] + sm[2] + sm[3]) * (1.f / 1024.f);
  const float rstd2 = rsqrtf(var2 + 1e-5f);
  const float4 g2v = reinterpret_cast<const float4*>(g2)[tid];
  const float4 b2v = reinterpret_cast<const float4*>(b2)[tid];
  u16x4 ob;
  ob[0] = f2bf(ex * rstd2 * g2v.x + b2v.x);
  ob[1] = f2bf(ey * rstd2 * g2v.y + b2v.y);
  ob[2] = f2bf(ez * rstd2 * g2v.z + b2v.z);
  ob[3] = f2bf(ew * rstd2 * g2v.w + b2v.w);
  reinterpret_cast<u16x4*>(out2b + (size_t)row * 1024)[tid] = ob;
}

// ---------------------------------------------------------------- bf16 GEMM, 256x256 tile, BK=32, 4-slot ring, depth-3 vmcnt + T2 swizzle
__global__ __launch_bounds__(512) void gemm256_kernel(
    const unsigned short* __restrict__ A, int lda,
    const unsigned short* __restrict__ B, int ldb,
    void* __restrict__ Cv, int ldc,
    const float* __restrict__ bias, const float* __restrict__ res,
    int K, int act, int outbf, int gy)
{
  __shared__ __align__(16) unsigned char smem[131072];
  const int t = threadIdx.x;
  const int w = t >> 6, l = t & 63;

  const int q = gridDim.x >> 3;
  const int nid = (blockIdx.x & 7) * q + (blockIdx.x >> 3);
  const int bm = (nid / gy) * 256;
  const int bn = (nid % gy) * 256;

  const int wr = (w >> 2) * 128;
  const int wc = (w & 3) * 64;
  f32x4 acc[8][4] = {};

  const int srow = t >> 2;          // 0..127 (+128 second half: (row>>1)&3 invariant)
  const int sk = SWZ_SK(t);
  const unsigned short* gA = A + (size_t)(bm + srow) * lda + sk;
  const unsigned short* gB = B + (size_t)(bn + srow) * ldb + sk;

  const int fr = l & 15;
  const int kb = SWZ_KB(l);

#define SA7(s) (smem + (s) * 16384)
#define SB7(s) (smem + 65536 + (s) * 16384)

#define STAGE7(s, k0) do { \
    GLDS(gA + (k0), SA7(s) + w * 1024); \
    GLDS(gA + (k0) + (size_t)128 * lda, SA7(s) + 8192 + w * 1024); \
    GLDS(gB + (k0), SB7(s) + w * 1024); \
    GLDS(gB + (k0) + (size_t)128 * ldb, SB7(s) + 8192 + w * 1024); \
  } while (0)

#define COMPUTE7(s) do { \
    bf16x8 af[8], bfr[4]; \
    _Pragma("unroll") \
    for (int j = 0; j < 4; ++j) \
      bfr[j] = *reinterpret_cast<const bf16x8*>((const unsigned short*)SB7(s) + (wc + j * 16 + fr) * 32 + kb); \
    _Pragma("unroll") \
    for (int i = 0; i < 8; ++i) \
      af[i] = *reinterpret_cast<const bf16x8*>((const unsigned short*)SA7(s) + (wr + i * 16 + fr) * 32 + kb); \
    _Pragma("unroll") \
    for (int i = 0; i < 8; ++i) \
      _Pragma("unroll") \
      for (int j = 0; j < 4; ++j) \
        acc[i][j] = __builtin_amdgcn_mfma_f32_16x16x32_bf16(af[i], bfr[j], acc[i][j], 0, 0, 0); \
  } while (0)

  const int nt = K >> 5;
  STAGE7(0, 0);
  if (nt > 1) STAGE7(1, 32);
  if (nt > 2) STAGE7(2, 64);
  if (nt > 2)      asm volatile("s_waitcnt vmcnt(8)" ::: "memory");
  else if (nt > 1) asm volatile("s_waitcnt vmcnt(4)" ::: "memory");
  else             asm volatile("s_waitcnt vmcnt(0)" ::: "memory");
  __builtin_amdgcn_s_barrier();
  for (int kt = 0; kt < nt; ++kt) {
    const int s = kt & 3;
    __builtin_amdgcn_sched_barrier(0);
    if (kt + 3 < nt) STAGE7((kt + 3) & 3, (kt + 3) * 32);
    __builtin_amdgcn_sched_barrier(0);
    COMPUTE7(s);
    __builtin_amdgcn_sched_barrier(0);
    if (kt + 3 < nt)      asm volatile("s_waitcnt vmcnt(8)" ::: "memory");
    else if (kt + 2 < nt) asm volatile("s_waitcnt vmcnt(4)" ::: "memory");
    else if (kt + 1 < nt) asm volatile("s_waitcnt vmcnt(0)" ::: "memory");
    __builtin_amdgcn_s_barrier();
  }
#undef STAGE7
#undef COMPUTE7
#undef SA7
#undef SB7

  const int crow = (l >> 4) * 4;
  const int ccol = l & 15;
  float* Cf = (float*)Cv;
  unsigned short* Cb = (unsigned short*)Cv;
#pragma unroll
  for (int i = 0; i < 8; ++i) {
#pragma unroll
    for (int j = 0; j < 4; ++j) {
      const int n = bn + wc + j * 16 + ccol;
      const float bv = bias ? bias[n] : 0.f;
#pragma unroll
      for (int r = 0; r < 4; ++r) {
        const int m = bm + wr + i * 16 + crow + r;
        float v = acc[i][j][r] + bv;
        if (act == 1) v = (v > 20.f) ? v : __logf(1.f + __expf(v));
        else if (act == 2) v = (v >= 0.f) ? v : 0.01f * v;
        if (res) v += res[(size_t)m * ldc + n];
        if (outbf) Cb[(size_t)m * ldc + n] = f2bf(v);
        else       Cf[(size_t)m * ldc + n] = v;
      }
    }
  }
}

// ---------------------------------------------------------------- bf16 GEMM, intra-block K-split, 2 groups, 2-phase + T2 swizzle (BK=32)
template<int BK>
__global__ __launch_bounds__(512) void gemm_ksplit_kernel(
    const unsigned short* __restrict__ A, int lda,
    const unsigned short* __restrict__ B, int ldb,
    void* __restrict__ Cv, int ldc,
    const float* __restrict__ bias, const float* __restrict__ res,
    int K, int act, int outbf, int gy)
{
  constexpr int ABYTES = 128 * BK * 2;
  constexpr int NISS = (BK == 32) ? 2 : 4;
  constexpr int RPI  = (BK == 32) ? 64 : 32;
  constexpr int NS   = BK / 32;
  __shared__ __align__(16) unsigned char smem[8 * ABYTES];
  const int tid = threadIdx.x;
  const int grp = tid >> 8;
  const int t = tid & 255;
  const int w = t >> 6, l = t & 63;

  const int q = gridDim.x >> 3;
  const int nid = (blockIdx.x & 7) * q + (blockIdx.x >> 3);
  const int bm = (nid / gy) * 128;
  const int bn = (nid % gy) * 128;

  const int K2 = K >> 1;
  const int koff = grp * K2;
  const int wr = (w >> 1) * 64, wc = (w & 1) * 64;
  f32x4 acc[4][4] = {};

  const int srow = (BK == 32) ? (t >> 2) : (t >> 3);
  const int sk   = (BK == 32) ? SWZ_SK(t) : ((t & 7) * 8);
  const unsigned short* gA = A + (size_t)(bm + srow) * lda + koff + sk;
  const unsigned short* gB = B + (size_t)(bn + srow) * ldb + koff + sk;

  const int gbase = grp * 2 * ABYTES;
  const int fr = l & 15;
  const int kb = (BK == 32) ? SWZ_KB(l) : ((l >> 4) * 8);

#define SAb(buf) (smem + gbase + (buf) * ABYTES)
#define SBb(buf) (smem + 4 * ABYTES + gbase + (buf) * ABYTES)

#define STAGEK(buf, k0) do { \
    _Pragma("unroll") \
    for (int ii = 0; ii < NISS; ++ii) { \
      GLDS(gA + (k0) + (size_t)ii * RPI * lda, SAb(buf) + ii * 4096 + w * 1024); \
      GLDS(gB + (k0) + (size_t)ii * RPI * ldb, SBb(buf) + ii * 4096 + w * 1024); \
    } \
  } while (0)

#define COMPUTEK(buf) do { \
    _Pragma("unroll") \
    for (int s = 0; s < NS; ++s) { \
      bf16x8 af[4], bfr[4]; \
      _Pragma("unroll") \
      for (int i = 0; i < 4; ++i) \
        af[i] = *reinterpret_cast<const bf16x8*>((const unsigned short*)SAb(buf) + (wr + i * 16 + fr) * BK + s * 32 + kb); \
      _Pragma("unroll") \
      for (int j = 0; j < 4; ++j) \
        bfr[j] = *reinterpret_cast<const bf16x8*>((const unsigned short*)SBb(buf) + (wc + j * 16 + fr) * BK + s * 32 + kb); \
      _Pragma("unroll") \
      for (int i = 0; i < 4; ++i) \
        _Pragma("unroll") \
        for (int j = 0; j < 4; ++j) \
          acc[i][j] = __builtin_amdgcn_mfma_f32_16x16x32_bf16(af[i], bfr[j], acc[i][j], 0, 0, 0); \
    } \
  } while (0)

  STAGEK(0, 0);
  DRAIN_VM();
  __syncthreads();
  int cur = 0;
  for (int k0 = BK; k0 < K2; k0 += BK) {
    __builtin_amdgcn_sched_barrier(0);
    STAGEK(cur ^ 1, k0);
    __builtin_amdgcn_sched_barrier(0);
    COMPUTEK(cur);
    DRAIN_VM();
    __syncthreads();
    cur ^= 1;
  }
  COMPUTEK(cur);
#undef STAGEK
#undef COMPUTEK
#undef SAb
#undef SBb

  __syncthreads();
  float* red = (float*)smem;
  if (grp) {
#pragma unroll
    for (int i = 0; i < 4; ++i)
#pragma unroll
      for (int j = 0; j < 4; ++j)
        *reinterpret_cast<f32x4*>(&red[(t << 6) + (i * 4 + j) * 4]) = acc[i][j];
  }
  __syncthreads();
  if (!grp) {
    const int crow = (l >> 4) * 4;
    const int ccol = l & 15;
    float* Cf = (float*)Cv;
    unsigned short* Cb = (unsigned short*)Cv;
#pragma unroll
    for (int i = 0; i < 4; ++i) {
#pragma unroll
      for (int j = 0; j < 4; ++j) {
        const f32x4 o = *reinterpret_cast<const f32x4*>(&red[(t << 6) + (i * 4 + j) * 4]);
        const int n = bn + wc + j * 16 + ccol;
        const float bv = bias ? bias[n] : 0.f;
#pragma unroll
        for (int r = 0; r < 4; ++r) {
          const int m = bm + wr + i * 16 + crow + r;
          float v = acc[i][j][r] + o[r] + bv;
          if (act == 1) v = (v > 20.f) ? v : __logf(1.f + __expf(v));
          else if (act == 2) v = (v >= 0.f) ? v : 0.01f * v;
          if (res) v += res[(size_t)m * ldc + n];
          if (outbf) Cb[(size_t)m * ldc + n] = f2bf(v);
          else       Cf[(size_t)m * ldc + n] = v;
        }
      }
    }
  }
}

// ---------------------------------------------------------------- bf16 GEMM, 128x64 tile, intra-block K-split, 2 groups, 2-phase + T2 swizzle
// Short-K sites only (out_proj, fe). Padded reduction (stride 36 floats).
__global__ __launch_bounds__(512) void gemm_ksplit_bn64_kernel(
    const unsigned short* __restrict__ A, int lda,
    const unsigned short* __restrict__ B, int ldb,
    void* __restrict__ Cv, int ldc,
    const float* __restrict__ bias, const float* __restrict__ res,
    int K, int act, int outbf, int gy)
{
  __shared__ __align__(16) unsigned char smem[49152];
  const int tid = threadIdx.x;
  const int grp = tid >> 8;
  const int t = tid & 255;
  const int w = t >> 6, l = t & 63;

  const int q = gridDim.x >> 3;
  const int nid = (blockIdx.x & 7) * q + (blockIdx.x >> 3);
  const int bm = (nid / gy) * 128;
  const int bn = (nid % gy) * 64;

  const int K2 = K >> 1;
  const int koff = grp * K2;
  const int wr = (w >> 1) * 64, wc = (w & 1) * 32;
  f32x4 acc[4][2] = {};

  const int srow = t >> 2;          // 0..63
  const int sk = SWZ_SK(t);
  const unsigned short* gA = A + (size_t)(bm + srow) * lda + koff + sk;
  const unsigned short* gB = B + (size_t)(bn + srow) * ldb + koff + sk;

  const int fr = l & 15;
  const int kb = SWZ_KB(l);

#define SAn(buf) (smem + grp * 16384 + (buf) * 8192)
#define SBn(buf) (smem + 32768 + grp * 8192 + (buf) * 4096)

#define STAGEN(buf, k0) do { \
    GLDS(gA + (k0), SAn(buf) + w * 1024); \
    GLDS(gA + (k0) + (size_t)64 * lda, SAn(buf) + 4096 + w * 1024); \
    GLDS(gB + (k0), SBn(buf) + w * 1024); \
  } while (0)

#define COMPUTEN(buf) do { \
    bf16x8 af[4], bfr[2]; \
    _Pragma("unroll") \
    for (int i = 0; i < 4; ++i) \
      af[i] = *reinterpret_cast<const bf16x8*>((const unsigned short*)SAn(buf) + (wr + i * 16 + fr) * 32 + kb); \
    _Pragma("unroll") \
    for (int j = 0; j < 2; ++j) \
      bfr[j] = *reinterpret_cast<const bf16x8*>((const unsigned short*)SBn(buf) + (wc + j * 16 + fr) * 32 + kb); \
    _Pragma("unroll") \
    for (int i = 0; i < 4; ++i) \
      _Pragma("unroll") \
      for (int j = 0; j < 2; ++j) \
        acc[i][j] = __builtin_amdgcn_mfma_f32_16x16x32_bf16(af[i], bfr[j], acc[i][j], 0, 0, 0); \
  } while (0)

  STAGEN(0, 0);
  DRAIN_VM();
  __syncthreads();
  int cur = 0;
  for (int k0 = 32; k0 < K2; k0 += 32) {
    __builtin_amdgcn_sched_barrier(0);
    STAGEN(cur ^ 1, k0);
    __builtin_amdgcn_sched_barrier(0);
    COMPUTEN(cur);
    DRAIN_VM();
    __syncthreads();
    cur ^= 1;
  }
  COMPUTEN(cur);
#undef STAGEN
#undef COMPUTEN
#undef SAn
#undef SBn

  // reduction: grp1 dumps acc, grp0 adds + writes (stride 36 = bank-spread pad)
  __syncthreads();
  float* red = (float*)smem;
  if (grp) {
#pragma unroll
    for (int i = 0; i < 4; ++i)
#pragma unroll
      for (int j = 0; j < 2; ++j)
        *reinterpret_cast<f32x4*>(&red[t * 36 + (i * 2 + j) * 4]) = acc[i][j];
  }
  __syncthreads();
  if (!grp) {
    const int crow = (l >> 4) * 4;
    const int ccol = l & 15;
    float* Cf = (float*)Cv;
    unsigned short* Cb = (unsigned short*)Cv;
#pragma unroll
    for (int i = 0; i < 4; ++i) {
#pragma unroll
      for (int j = 0; j < 2; ++j) {
        const f32x4 o = *reinterpret_cast<const f32x4*>(&red[t * 36 + (i * 2 + j) * 4]);
        const int n = bn + wc + j * 16 + ccol;
        const float bv = bias ? bias[n] : 0.f;
#pragma unroll
        for (int r = 0; r < 4; ++r) {
          const int m = bm + wr + i * 16 + crow + r;
          float v = acc[i][j][r] + o[r] + bv;
          if (act == 1) v = (v > 20.f) ? v : __logf(1.f + __expf(v));
          else if (act == 2) v = (v >= 0.f) ? v : 0.01f * v;
          if (res) v += res[(size_t)m * ldc + n];
          if (outbf) Cb[(size_t)m * ldc + n] = f2bf(v);
          else       Cf[(size_t)m * ldc + n] = v;
        }
      }
    }
  }
}

// ---------------------------------------------------------------- bf16 GEMM, intra-block K-split, 2 groups, 4-slot ring depth-3
// + T2 swizzle (round-31 proven: conflicts 6.1M->1.9M, 67.7->64.7 us)
// + padded reduction (stride 68 floats) for the residual epilogue banking.
__global__ __launch_bounds__(512) void gemm_ksplit_ring_kernel(
    const unsigned short* __restrict__ A, int lda,
    const unsigned short* __restrict__ B, int ldb,
    void* __restrict__ Cv, int ldc,
    const float* __restrict__ bias, const float* __restrict__ res,
    int K, int act, int outbf, int gy)
{
  __shared__ __align__(16) unsigned char smem[131072];
  const int tid = threadIdx.x;
  const int grp = tid >> 8;
  const int t = tid & 255;
  const int w = t >> 6, l = t & 63;

  const int q = gridDim.x >> 3;
  const int nid = (blockIdx.x & 7) * q + (blockIdx.x >> 3);
  const int bm = (nid / gy) * 128;
  const int bn = (nid % gy) * 128;

  const int K2 = K >> 1;
  const int koff = grp * K2;
  const int wr = (w >> 1) * 64, wc = (w & 1) * 64;
  f32x4 acc[4][4] = {};

  const int srow = t >> 2;          // 0..63
  const int sk = SWZ_SK(t);
  const unsigned short* gA = A + (size_t)(bm + srow) * lda + koff + sk;
  const unsigned short* gB = B + (size_t)(bn + srow) * ldb + koff + sk;

  const int fr = l & 15;
  const int kb = SWZ_KB(l);

#define SAr(s) (smem + grp * 32768 + (s) * 8192)
#define SBr(s) (smem + 65536 + grp * 32768 + (s) * 8192)

#define STAGER(s, k0) do { \
    GLDS(gA + (k0), SAr(s) + w * 1024); \
    GLDS(gA + (k0) + (size_t)64 * lda, SAr(s) + 4096 + w * 1024); \
    GLDS(gB + (k0), SBr(s) + w * 1024); \
    GLDS(gB + (k0) + (size_t)64 * ldb, SBr(s) + 4096 + w * 1024); \
  } while (0)

#define COMPUTER(s) do { \
    bf16x8 af[4], bfr[4]; \
    _Pragma("unroll") \
    for (int i = 0; i < 4; ++i) \
      af[i] = *reinterpret_cast<const bf16x8*>((const unsigned short*)SAr(s) + (wr + i * 16 + fr) * 32 + kb); \
    _Pragma("unroll") \
    for (int j = 0; j < 4; ++j) \
      bfr[j] = *reinterpret_cast<const bf16x8*>((const unsigned short*)SBr(s) + (wc + j * 16 + fr) * 32 + kb); \
    _Pragma("unroll") \
    for (int i = 0; i < 4; ++i) \
      _Pragma("unroll") \
      for (int j = 0; j < 4; ++j) \
        acc[i][j] = __builtin_amdgcn_mfma_f32_16x16x32_bf16(af[i], bfr[j], acc[i][j], 0, 0, 0); \
  } while (0)

  const int nt = K2 >> 5;
  STAGER(0, 0);
  if (nt > 1) STAGER(1, 32);
  if (nt > 2) STAGER(2, 64);
  if (nt > 2)      asm volatile("s_waitcnt vmcnt(8)" ::: "memory");
  else if (nt > 1) asm volatile("s_waitcnt vmcnt(4)" ::: "memory");
  else             asm volatile("s_waitcnt vmcnt(0)" ::: "memory");
  __builtin_amdgcn_s_barrier();
  for (int kt = 0; kt < nt; ++kt) {
    const int s = kt & 3;
    __builtin_amdgcn_sched_barrier(0);
    if (kt + 3 < nt) STAGER((kt + 3) & 3, (kt + 3) * 32);
    __builtin_amdgcn_sched_barrier(0);
    COMPUTER(s);
    __builtin_amdgcn_sched_barrier(0);
    if (kt + 3 < nt)      asm volatile("s_waitcnt vmcnt(8)" ::: "memory");
    else if (kt + 2 < nt) asm volatile("s_waitcnt vmcnt(4)" ::: "memory");
    else if (kt + 1 < nt) asm volatile("s_waitcnt vmcnt(0)" ::: "memory");
    __builtin_amdgcn_s_barrier();
  }
#undef STAGER
#undef COMPUTER
#undef SAr
#undef SBr

  __syncthreads();
  float* red = (float*)smem;
  if (grp) {
#pragma unroll
    for (int i = 0; i < 4; ++i)
#pragma unroll
      for (int j = 0; j < 4; ++j)
        *reinterpret_cast<f32x4*>(&red[t * 68 + (i * 4 + j) * 4]) = acc[i][j];
  }
  __syncthreads();
  if (!grp) {
    const int crow = (l >> 4) * 4;
    const int ccol = l & 15;
    float* Cf = (float*)Cv;
    unsigned short* Cb = (unsigned short*)Cv;
#pragma unroll
    for (int i = 0; i < 4; ++i) {
#pragma unroll
      for (int j = 0; j < 4; ++j) {
        const f32x4 o = *reinterpret_cast<const f32x4*>(&red[t * 68 + (i * 4 + j) * 4]);
        const int n = bn + wc + j * 16 + ccol;
        const float bv = bias ? bias[n] : 0.f;
#pragma unroll
        for (int r = 0; r < 4; ++r) {
          const int m = bm + wr + i * 16 + crow + r;
          float v = acc[i][j][r] + o[r] + bv;
          if (act == 1) v = (v > 20.f) ? v : __logf(1.f + __expf(v));
          else if (act == 2) v = (v >= 0.f) ? v : 0.01f * v;
          if (res) v += res[(size_t)m * ldc + n];
          if (outbf) Cb[(size_t)m * ldc + n] = f2bf(v);
          else       Cf[(size_t)m * ldc + n] = v;
        }
      }
    }
  }
}

// ---------------------------------------------------------------- x_proj split-K (N=96), 2-phase (proven; layout differs — left unswizzled)
__global__ __launch_bounds__(256) void xproj_kernel(
    const unsigned short* __restrict__ A, int lda,
    const unsigned short* __restrict__ B, int ldb,
    float* __restrict__ C)
{
  __shared__ unsigned short As[2][128 * 32];
  __shared__ unsigned short Bs[2][96 * 32];
  const int t = threadIdx.x;
  const int w = t >> 6, l = t & 63;
  const int bm = blockIdx.x * 128;
  const int kbase = blockIdx.y * 128;

  f32x4 acc[2][6] = {};

  const int srow = t >> 2;
  const int sk = (t & 3) * 8;
  const unsigned short* gA0 = A + (size_t)(bm + srow) * lda + kbase + sk;
  const unsigned short* gA1 = gA0 + (size_t)64 * lda;
  const unsigned short* gB0 = B + (size_t)srow * ldb + kbase + sk;
  const unsigned short* gB1 = gB0 + (size_t)64 * ldb;

  const int fr = l & 15;
  const int kb = (l >> 4) * 8;

#define STAGEX(buf, k0) do { \
    GLDS(gA0 + (k0), &As[buf][w * 512]); \
    GLDS(gA1 + (k0), &As[buf][2048 + w * 512]); \
    GLDS(gB0 + (k0), &Bs[buf][w * 512]); \
    if (w < 2) GLDS(gB1 + (k0), &Bs[buf][2048 + w * 512]); \
  } while (0)

#define COMPUTEX(buf) do { \
    bf16x8 af[2], bfr[6]; \
    _Pragma("unroll") \
    for (int i = 0; i < 2; ++i) \
      af[i] = *reinterpret_cast<const bf16x8*>(&As[buf][(w * 32 + i * 16 + fr) * 32 + kb]); \
    _Pragma("unroll") \
    for (int j = 0; j < 6; ++j) \
      bfr[j] = *reinterpret_cast<const bf16x8*>(&Bs[buf][(j * 16 + fr) * 32 + kb]); \
    _Pragma("unroll") \
    for (int i = 0; i < 2; ++i) \
      _Pragma("unroll") \
      for (int j = 0; j < 6; ++j) \
        acc[i][j] = __builtin_amdgcn_mfma_f32_16x16x32_bf16(af[i], bfr[j], acc[i][j], 0, 0, 0); \
  } while (0)

  STAGEX(0, 0);
  DRAIN_VM();
  __syncthreads();
  int cur = 0;
  for (int s = 1; s < 4; ++s) {
    __builtin_amdgcn_sched_barrier(0);
    STAGEX(cur ^ 1, s * 32);
    __builtin_amdgcn_sched_barrier(0);
    COMPUTEX(cur);
    DRAIN_VM();
    __syncthreads();
    cur ^= 1;
  }
  COMPUTEX(cur);
#undef STAGEX
#undef COMPUTEX

  const int crow = (l >> 4) * 4;
  const int ccol = l & 15;
#pragma unroll
  for (int i = 0; i < 2; ++i)
#pragma unroll
    for (int j = 0; j < 6; ++j)
#pragma unroll
      for (int r = 0; r < 4; ++r) {
        const int m = bm + w * 32 + i * 16 + crow + r;
        const int n = j * 16 + ccol;
        atomicAdd(&C[(size_t)m * 96 + n], acc[i][j][r]);
      }
}

// ---------------------------------------------------------------- conv(k=2)+SiLU (bf16, x8 vectorized)
__global__ __launch_bounds__(256) void conv_silu_kernel(
    const unsigned short* __restrict__ xz, const float* __restrict__ cw,
    const float* __restrict__ cb, unsigned short* __restrict__ xcb)
{
  const int i = blockIdx.x * 256 + threadIdx.x;   // 524288 threads, 8 elems each
  const int row = i >> 7;
  const int dv = (i & 127) * 8;
  const int l = row & (L_SEQ - 1);
  const u16x8 cur = *reinterpret_cast<const u16x8*>(&xz[(size_t)row * 2048 + dv]);
  u16x8 prev = {};
  if (l != 0) prev = *reinterpret_cast<const u16x8*>(&xz[(size_t)(row - 1) * 2048 + dv]);
  float cwv[16], cbv[8];
#pragma unroll
  for (int qq = 0; qq < 4; ++qq)
    *reinterpret_cast<float4*>(&cwv[qq * 4]) = reinterpret_cast<const float4*>(cw + 2 * dv)[qq];
#pragma unroll
  for (int qq = 0; qq < 2; ++qq)
    *reinterpret_cast<float4*>(&cbv[qq * 4]) = reinterpret_cast<const float4*>(cb + dv)[qq];
  u16x8 o;
#pragma unroll
  for (int e = 0; e < 8; ++e) {
    const float v = bf2f(prev[e]) * cwv[2 * e] + bf2f(cur[e]) * cwv[2 * e + 1] + cbv[e];
    o[e] = f2bf(v / (1.f + __expf(-v)));
  }
  *reinterpret_cast<u16x8*>(&xcb[(size_t)row * 1024 + dv]) = o;
}

// ---------------------------------------------------------------- scan pass 1 (bf16 in, bf16 state out)
__global__ __launch_bounds__(256) void scan_pass1(
    const unsigned short* __restrict__ delta, const unsigned short* __restrict__ xc,
    const float* __restrict__ xdbl, const float* __restrict__ A_log,
    unsigned short* __restrict__ hfin, unsigned short* __restrict__ pcum)
{
  const int tid = threadIdx.x;
  const int db = blockIdx.x & 3;
  const int c = (blockIdx.x >> 2) & (NCHUNK - 1);
  const int b = blockIdx.x >> 7;
  const int d = db * 256 + tid;
  __shared__ float Bsh[CH][16];
  {
    const int lr = tid >> 2, q = tid & 3;
    const float* p = xdbl + ((size_t)(b * L_SEQ + c * CH + lr) * 96) + 64 + q * 4;
    *reinterpret_cast<float4*>(&Bsh[lr][q * 4]) = *reinterpret_cast<const float4*>(p);
  }
  float a[NSTATE];
#pragma unroll
  for (int n = 0; n < NSTATE; ++n) a[n] = -__expf(A_log[d * 16 + n]);
  __syncthreads();
  float h[NSTATE], P[NSTATE];
#pragma unroll
  for (int n = 0; n < NSTATE; ++n) { h[n] = 0.f; P[n] = 1.f; }
  const size_t rowbase = (size_t)(b * L_SEQ + c * CH);
  for (int s = 0; s < CH; ++s) {
    const size_t row = rowbase + s;
    const float dl = bf2f(delta[row * 1024 + d]);
    const float xcv = bf2f(xc[row * 1024 + d]);
#pragma unroll
    for (int n = 0; n < NSTATE; ++n) {
      const float dA = __expf(dl * a[n]);
      h[n] = h[n] * dA + (dl * Bsh[s][n]) * xcv;
      P[n] *= dA;
    }
  }
  const size_t base = ((size_t)((b * NCHUNK + c) * 1024 + d)) * 16;
  u16x8 h0, h1, p0, p1;
#pragma unroll
  for (int n = 0; n < 8; ++n) {
    h0[n] = f2bf(h[n]);     h1[n] = f2bf(h[n + 8]);
    p0[n] = f2bf(P[n]);     p1[n] = f2bf(P[n + 8]);
  }
  *reinterpret_cast<u16x8*>(hfin + base) = h0;
  *reinterpret_cast<u16x8*>(hfin + base + 8) = h1;
  *reinterpret_cast<u16x8*>(pcum + base) = p0;
  *reinterpret_cast<u16x8*>(pcum + base + 8) = p1;
}

// ---------------------------------------------------------------- scan pass 2 (bf16 state)
__global__ __launch_bounds__(256) void scan_pass2(
    const unsigned short* __restrict__ hfin, const unsigned short* __restrict__ pcum,
    unsigned short* __restrict__ hstart)
{
  const int t = blockIdx.x * 256 + threadIdx.x;
  const int b = t >> 14;
  const int dn = t & 16383;
  const size_t base = (size_t)b * NCHUNK * 16384 + dn;
  float h = 0.f;
  for (int c = 0; c < NCHUNK; ++c) {
    const size_t idx = base + (size_t)c * 16384;
    hstart[idx] = f2bf(h);
    h = bf2f(pcum[idx]) * h + bf2f(hfin[idx]);
  }
}

// ---------------------------------------------------------------- scan pass 3 (bf16 in, bf16 y out)
__global__ __launch_bounds__(256) void scan_pass3(
    const unsigned short* __restrict__ delta, const unsigned short* __restrict__ xc,
    const float* __restrict__ xdbl, const float* __restrict__ A_log,
    const unsigned short* __restrict__ hstart, const float* __restrict__ Dp,
    const unsigned short* __restrict__ xz, unsigned short* __restrict__ yout)
{
  const int tid = threadIdx.x;
  const int db = blockIdx.x & 3;
  const int c = (blockIdx.x >> 2) & (NCHUNK - 1);
  const int b = blockIdx.x >> 7;
  const int d = db * 256 + tid;
  __shared__ float Bsh[CH][16];
  __shared__ float Csh[CH][16];
  {
    const int lr = tid >> 2, q = tid & 3;
    const float* p = xdbl + ((size_t)(b * L_SEQ + c * CH + lr) * 96);
    *reinterpret_cast<float4*>(&Bsh[lr][q * 4]) = *reinterpret_cast<const float4*>(p + 64 + q * 4);
    *reinterpret_cast<float4*>(&Csh[lr][q * 4]) = *reinterpret_cast<const float4*>(p + 80 + q * 4);
  }
  float a[NSTATE];
#pragma unroll
  for (int n = 0; n < NSTATE; ++n) a[n] = -__expf(A_log[d * 16 + n]);
  float h[NSTATE];
  {
    const size_t base = ((size_t)((b * NCHUNK + c) * 1024 + d)) * 16;
    const u16x8 v0 = *reinterpret_cast<const u16x8*>(hstart + base);
    const u16x8 v1 = *reinterpret_cast<const u16x8*>(hstart + base + 8);
#pragma unroll
    for (int n = 0; n < 8; ++n) { h[n] = bf2f(v0[n]); h[n + 8] = bf2f(v1[n]); }
  }
  const float dpv = Dp[d];
  __syncthreads();
  const size_t rowbase = (size_t)(b * L_SEQ + c * CH);
  for (int s = 0; s < CH; ++s) {
    const size_t row = rowbase + s;
    const float dl = bf2f(delta[row * 1024 + d]);
    const float xcv = bf2f(xc[row * 1024 + d]);
    float y = 0.f;
#pragma unroll
    for (int n = 0; n < NSTATE; ++n) {
      const float dA = __expf(dl * a[n]);
      h[n] = h[n] * dA + (dl * Bsh[s][n]) * xcv;
      y += h[n] * Csh[s][n];
    }
    const float z = bf2f(xz[row * 2048 + 1024 + d]);
    const float sil = z / (1.f + __expf(-z));
    yout[row * 1024 + d] = f2bf((y + xcv * dpv) * sil);
  }
}

// ---------------------------------------------------------------- launch
extern "C" void kernel_launch(void* const* d_in, const int* in_sizes, int n_in,
                              void* d_out, int out_size, void* d_ws, size_t ws_size,
                              hipStream_t stream)
{
  (void)in_sizes; (void)n_in; (void)out_size; (void)ws_size;
  const float* src        = (const float*)d_in[0];
  const float* in_proj_w  = (const float*)d_in[1];
  const float* conv_w     = (const float*)d_in[2];
  const float* conv_b     = (const float*)d_in[3];
  const float* x_proj_w   = (const float*)d_in[4];
  const float* dt_proj_w  = (const float*)d_in[5];
  const float* dt_proj_b  = (const float*)d_in[6];
  const float* A_log      = (const float*)d_in[7];
  const float* Dp         = (const float*)d_in[8];
  const float* out_proj_w = (const float*)d_in[9];
  const float* mnorm_g    = (const float*)d_in[10];
  const float* mnorm_b    = (const float*)d_in[11];
  const float* n1_g       = (const float*)d_in[12];
  const float* n1_b       = (const float*)d_in[13];
  const float* n2_g       = (const float*)d_in[14];
  const float* n2_b       = (const float*)d_in[15];
  const float* n3_g       = (const float*)d_in[16];
  const float* n3_b       = (const float*)d_in[17];
  const float* ffn_w1     = (const float*)d_in[18];
  const float* ffn_w2     = (const float*)d_in[19];
  const float* fe_w       = (const float*)d_in[20];
  const float* fe_b       = (const float*)d_in[21];
  float* out = (float*)d_out;
  float* ws  = (float*)d_ws;

  // ---- workspace layout (float offsets; ranges disjoint) ----
  unsigned short* xzb   = (unsigned short*)ws;              // u16 8388608 = f[0 .. 4194304)
  unsigned short* xdblb = (unsigned short*)(ws + 4194304);  // u16 393216  = f[.. 4390912)
  unsigned short* dtwb  = (unsigned short*)(ws + 4390912);  // u16 65536   = f[.. 4423680)
  unsigned short* deltab= (unsigned short*)(ws + 4423680);  // u16 4194304 = f[.. 6520832)
  float* xdbl  = ws + 12582912;       // f[12582912 .. 12976128)
  float* s5    = ws + 17301504;       // f[17301504 .. 21495808)
  float* src1  = ws + 21495808;       // f[21495808 .. 25690112)
  unsigned short* hfin = (unsigned short*)(ws + 25690112);  // u16 1048576
  unsigned short* pcum = (unsigned short*)(ws + 26738688);  // u16 1048576
  unsigned short* hst  = (unsigned short*)(ws + 27787264);  // u16 1048576
  unsigned short* s1b  = (unsigned short*)(ws + 28835840);  // u16 4194304
  unsigned short* xcb  = (unsigned short*)(ws + 30932992);  // u16 4194304
  unsigned short* yb   = (unsigned short*)(ws + 33030144);  // u16 4194304
  unsigned short* f1b  = (unsigned short*)(ws + 35127296);  // u16 16777216
  unsigned short* ipwb = (unsigned short*)(ws + 43515904);  // u16 2097152
  unsigned short* xpwb = (unsigned short*)(ws + 44564480);  // u16 98304
  unsigned short* opwb = (unsigned short*)(ws + 44613632);  // u16 1048576
  unsigned short* w1b  = (unsigned short*)(ws + 45137920);  // u16 4194304
  unsigned short* w2b  = (unsigned short*)(ws + 47235072);  // u16 4194304
  unsigned short* fewb = (unsigned short*)(ws + 49332224);  // u16 1048576

  const dim3 blk(256);
  const dim3 blk512(512);

  // 0+1. weights -> bf16, zero xdbl, step-1 LN (single launch; 12832 + 4096 blocks)
  cvt_all_kernel<<<16928, blk, 0, stream>>>(
      in_proj_w, x_proj_w, dt_proj_w, out_proj_w, ffn_w1, ffn_w2, fe_w, xdbl,
      ipwb, xpwb, dtwb, opwb, w1b, w2b, fewb,
      src, n1_g, n1_b, s1b);

  // 2. xz = x1 @ in_proj_w^T -> bf16  (ksplit2 BK=32 + T2 swizzle, 2 blocks/CU)
  gemm_ksplit_kernel<32><<<512, blk512, 0, stream>>>(s1b, 1024, ipwb, 1024, xzb, 2048,
                                                     nullptr, nullptr, 1024, 0, 1, 16);
  // 3. x_c = silu(conv(x_in)) -> bf16 (x8 vectorized)
  conv_silu_kernel<<<2048, blk, 0, stream>>>(xzb, conv_w, conv_b, xcb);
  // 4. x_dbl = x_c @ x_proj_w^T  (split-K=8, atomic f32; xdbl pre-zeroed in cvt_all)
  xproj_kernel<<<dim3(32, 8), blk, 0, stream>>>(xcb, 1024, xpwb, 1024, xdbl);
  // 4b. xdbl -> bf16 for dt_proj
  cvt_bf16_kernel<<<384, blk, 0, stream>>>(xdbl, xdblb, 98304);
  // 5. delta = softplus(dt @ dt_proj_w^T + b) -> bf16  (ksplit2 BK=32 + T2, K=64)
  gemm_ksplit_kernel<32><<<256, blk512, 0, stream>>>(xdblb, 96, dtwb, 64, deltab, 1024,
                                                     dt_proj_b, nullptr, 64, 1, 1, 8);
  // 6-8. selective scan (bf16 datapath + bf16 inter-chunk state)
  scan_pass1<<<256, blk, 0, stream>>>(deltab, xcb, xdbl, A_log, hfin, pcum);
  scan_pass2<<<128, blk, 0, stream>>>(hfin, pcum, hst);
  scan_pass3<<<256, blk, 0, stream>>>(deltab, xcb, xdbl, A_log, hst, Dp, xzb, yb);
  // 9. mamba_out = y @ out_proj_w^T  (ksplit2 BN=64 + T2, 512 blocks = 2/CU)
  gemm_ksplit_bn64_kernel<<<512, blk512, 0, stream>>>(yb, 1024, opwb, 1024, s5, 1024,
                                                      nullptr, nullptr, 1024, 0, 0, 16);
  // 10+11. src1 = src + LN(s5; mnorm); x2 = LN(src1; n2) -> bf16  (fused)
  ln2_kernel<<<NROWS, blk, 0, stream>>>(s5, mnorm_g, mnorm_b, src,
                                        n2_g, n2_b, src1, s1b);
  // 12. f1 = leaky(x2 @ ffn_w1^T) -> bf16  (256² ring-4 depth-3 + T2)
  gemm256_kernel<<<256, blk512, 0, stream>>>(s1b, 1024, w1b, 1024, f1b, 4096,
                                             nullptr, nullptr, 1024, 2, 1, 16);
  // 13. src2 = src1 + f1 @ ffn_w2^T  (ksplit2 ring-4 depth-3 + T2 + padded red)
  gemm_ksplit_ring_kernel<<<256, blk512, 0, stream>>>(f1b, 4096, w2b, 4096, s5, 1024,
                                                      nullptr, src1, 4096, 0, 0, 8);
  // 14. x3 = LN(src2; n3) -> bf16
  ln_kernel<<<NROWS, blk, 0, stream>>>(s5, n3_g, n3_b, nullptr, nullptr, s1b);
  // 15. out = src2 + x3 @ fe_w^T + fe_b  (ksplit2 BN=64 + T2, 512 blocks = 2/CU)
  gemm_ksplit_bn64_kernel<<<512, blk512, 0, stream>>>(s1b, 1024, fewb, 1024, out, 1024,
                                                      fe_b, s5, 1024, 0, 0, 16);
}

// Round 33
// 359.296 us; speedup vs baseline: 1.0544x; 1.0072x over previous
//
#include <hip/hip_runtime.h>
#include <hip/hip_bf16.h>
#include <cstddef>

#define L_SEQ   2048
#define NBATCH  2
#define NROWS   (NBATCH * L_SEQ)   /* 4096 */
#define NSTATE  16
#define CH      64
#define NCHUNK  (L_SEQ / CH)       /* 32 */

typedef __bf16 bf16x8 __attribute__((ext_vector_type(8)));
typedef float  f32x4  __attribute__((ext_vector_type(4)));
typedef unsigned short u16x4 __attribute__((ext_vector_type(4)));
typedef unsigned short u16x8 __attribute__((ext_vector_type(8)));

static __device__ __forceinline__ unsigned short f2bf(float f) {
  unsigned int x = __builtin_bit_cast(unsigned int, f);
  x += 0x7fffu + ((x >> 16) & 1u);          // RNE
  return (unsigned short)(x >> 16);
}
static __device__ __forceinline__ float bf2f(unsigned short u) {
  return __builtin_bit_cast(float, ((unsigned int)u) << 16);
}

// async global->LDS, 16B per lane; LDS dest = wave-uniform base + lane*16
#define GLDS(g, l) __builtin_amdgcn_global_load_lds( \
    (const __attribute__((address_space(1))) void*)(g), \
    (__attribute__((address_space(3))) void*)(l), 16, 0, 0)

#define DRAIN_VM() asm volatile("s_waitcnt vmcnt(0)" ::: "memory")

// T2 both-sides XOR swizzle (rounds 31/32 proven: ffn2 conflicts 6.1M->0,
// 67.7->62.6 us): global source k-chunk (t&3)^((t>>3)&3) staged into linear
// LDS chunk (t&3); read back with kb = ((l>>4)^((l>>1)&3))*8.
#define SWZ_SK(t)  ((((t) & 3) ^ (((t) >> 3) & 3)) * 8)
#define SWZ_KB(l)  (((((l) >> 4) ^ (((l) >> 1) & 3))) * 8)

// ---------------------------------------------------------------- f32 -> bf16 (generic, for xdbl)
__global__ __launch_bounds__(256) void cvt_bf16_kernel(
    const float* __restrict__ in, unsigned short* __restrict__ out, int n4)
{
  const int i = blockIdx.x * 256 + threadIdx.x;
  if (i < n4) {
    const float4 v = reinterpret_cast<const float4*>(in)[i];
    u16x4 o;
    o[0] = f2bf(v.x); o[1] = f2bf(v.y); o[2] = f2bf(v.z); o[3] = f2bf(v.w);
    reinterpret_cast<u16x4*>(out)[i] = o;
  }
}

// ---------------------------------------------------------------- all weights -> bf16 + zero xdbl + step-1 LN
__global__ __launch_bounds__(256) void cvt_all_kernel(
    const float* __restrict__ ipw, const float* __restrict__ xpw,
    const float* __restrict__ dtw, const float* __restrict__ opw,
    const float* __restrict__ w1,  const float* __restrict__ w2,
    const float* __restrict__ few, float* __restrict__ zx,
    unsigned short* __restrict__ o_ipw, unsigned short* __restrict__ o_xpw,
    unsigned short* __restrict__ o_dtw, unsigned short* __restrict__ o_opw,
    unsigned short* __restrict__ o_w1,  unsigned short* __restrict__ o_w2,
    unsigned short* __restrict__ o_few,
    const float* __restrict__ lsrc, const float* __restrict__ lg,
    const float* __restrict__ lb, unsigned short* __restrict__ louth)
{
  __shared__ float sm[8];
  if (blockIdx.x >= 12832) {             // fused step-1 LayerNorm
    const int row = blockIdx.x - 12832;
    const int tid = threadIdx.x;
    const float4 v = reinterpret_cast<const float4*>(lsrc + (size_t)row * 1024)[tid];
    float s = v.x + v.y + v.z + v.w;
#pragma unroll
    for (int o = 32; o > 0; o >>= 1) s += __shfl_down(s, o, 64);
    if ((tid & 63) == 0) sm[tid >> 6] = s;
    __syncthreads();
    const float mean = (sm[0] + sm[1] + sm[2] + sm[3]) * (1.f / 1024.f);
    const float dx = v.x - mean, dy = v.y - mean, dz = v.z - mean, dw = v.w - mean;
    float q = dx * dx + dy * dy + dz * dz + dw * dw;
#pragma unroll
    for (int o = 32; o > 0; o >>= 1) q += __shfl_down(q, o, 64);
    __syncthreads();
    if ((tid & 63) == 0) sm[tid >> 6] = q;
    __syncthreads();
    const float var = (sm[0] + sm[1] + sm[2] + sm[3]) * (1.f / 1024.f);
    const float rstd = rsqrtf(var + 1e-5f);
    const float4 gv = reinterpret_cast<const float4*>(lg)[tid];
    const float4 bv = reinterpret_cast<const float4*>(lb)[tid];
    u16x4 ob;
    ob[0] = f2bf(dx * rstd * gv.x + bv.x);
    ob[1] = f2bf(dy * rstd * gv.y + bv.y);
    ob[2] = f2bf(dz * rstd * gv.z + bv.z);
    ob[3] = f2bf(dw * rstd * gv.w + bv.w);
    reinterpret_cast<u16x4*>(louth + (size_t)row * 1024)[tid] = ob;
    return;
  }
  int i = blockIdx.x * 256 + threadIdx.x;
  if (i < 98304) {                       // zero xdbl (393216 floats)
    reinterpret_cast<float4*>(zx)[i] = make_float4(0.f, 0.f, 0.f, 0.f);
    return;
  }
  i -= 98304;
  const float* src; unsigned short* dst;
  if (i < 524288)                 { src = ipw; dst = o_ipw; }
  else if ((i -= 524288) < 24576) { src = xpw; dst = o_xpw; }
  else if ((i -= 24576) < 16384)  { src = dtw; dst = o_dtw; }
  else if ((i -= 16384) < 262144) { src = opw; dst = o_opw; }
  else if ((i -= 262144) < 1048576){ src = w1; dst = o_w1; }
  else if ((i -= 1048576) < 1048576){ src = w2; dst = o_w2; }
  else if ((i -= 1048576) < 262144){ src = few; dst = o_few; }
  else return;
  const float4 v = reinterpret_cast<const float4*>(src)[i];
  u16x4 o;
  o[0] = f2bf(v.x); o[1] = f2bf(v.y); o[2] = f2bf(v.z); o[3] = f2bf(v.w);
  reinterpret_cast<u16x4*>(dst)[i] = o;
}

// ---------------------------------------------------------------- LayerNorm (bf16 in, bf16 out; step 14 only)
__global__ __launch_bounds__(256) void ln_kernel(
    const unsigned short* __restrict__ in, const float* __restrict__ g,
    const float* __restrict__ bta, unsigned short* __restrict__ outb)
{
  const int row = blockIdx.x;
  const int tid = threadIdx.x;
  __shared__ float sm[8];
  const u16x4 iv = reinterpret_cast<const u16x4*>(in + (size_t)row * 1024)[tid];
  const float vx = bf2f(iv[0]), vy = bf2f(iv[1]), vz = bf2f(iv[2]), vw = bf2f(iv[3]);
  float s = vx + vy + vz + vw;
#pragma unroll
  for (int o = 32; o > 0; o >>= 1) s += __shfl_down(s, o, 64);
  if ((tid & 63) == 0) sm[tid >> 6] = s;
  __syncthreads();
  const float mean = (sm[0] + sm[1] + sm[2] + sm[3]) * (1.f / 1024.f);
  const float dx = vx - mean, dy = vy - mean, dz = vz - mean, dw = vw - mean;
  float q = dx * dx + dy * dy + dz * dz + dw * dw;
#pragma unroll
  for (int o = 32; o > 0; o >>= 1) q += __shfl_down(q, o, 64);
  __syncthreads();
  if ((tid & 63) == 0) sm[tid >> 6] = q;
  __syncthreads();
  const float var = (sm[0] + sm[1] + sm[2] + sm[3]) * (1.f / 1024.f);
  const float rstd = rsqrtf(var + 1e-5f);
  const float4 gv = reinterpret_cast<const float4*>(g)[tid];
  const float4 bv = reinterpret_cast<const float4*>(bta)[tid];
  u16x4 ob;
  ob[0] = f2bf(dx * rstd * gv.x + bv.x);
  ob[1] = f2bf(dy * rstd * gv.y + bv.y);
  ob[2] = f2bf(dz * rstd * gv.z + bv.z);
  ob[3] = f2bf(dw * rstd * gv.w + bv.w);
  reinterpret_cast<u16x4*>(outb + (size_t)row * 1024)[tid] = ob;
}

// ---------------------------------------------------------------- fused double-LayerNorm (steps 10+11; bf16 in)
__global__ __launch_bounds__(256) void ln2_kernel(
    const unsigned short* __restrict__ in, const float* __restrict__ g1,
    const float* __restrict__ b1, const float* __restrict__ res,
    const float* __restrict__ g2, const float* __restrict__ b2,
    float* __restrict__ out1, unsigned short* __restrict__ out2b)
{
  const int row = blockIdx.x;
  const int tid = threadIdx.x;
  __shared__ float sm[8];
  const u16x4 iv = reinterpret_cast<const u16x4*>(in + (size_t)row * 1024)[tid];
  const float vx = bf2f(iv[0]), vy = bf2f(iv[1]), vz = bf2f(iv[2]), vw = bf2f(iv[3]);
  float s = vx + vy + vz + vw;
#pragma unroll
  for (int o = 32; o > 0; o >>= 1) s += __shfl_down(s, o, 64);
  if ((tid & 63) == 0) sm[tid >> 6] = s;
  __syncthreads();
  const float mean = (sm[0] + sm[1] + sm[2] + sm[3]) * (1.f / 1024.f);
  const float dx = vx - mean, dy = vy - mean, dz = vz - mean, dw = vw - mean;
  float q = dx * dx + dy * dy + dz * dz + dw * dw;
#pragma unroll
  for (int o = 32; o > 0; o >>= 1) q += __shfl_down(q, o, 64);
  __syncthreads();
  if ((tid & 63) == 0) sm[tid >> 6] = q;
  __syncthreads();
  const float var = (sm[0] + sm[1] + sm[2] + sm[3]) * (1.f / 1024.f);
  const float rstd = rsqrtf(var + 1e-5f);
  const float4 g1v = reinterpret_cast<const float4*>(g1)[tid];
  const float4 b1v = reinterpret_cast<const float4*>(b1)[tid];
  const float4 rv = reinterpret_cast<const float4*>(res + (size_t)row * 1024)[tid];
  float4 o4;
  o4.x = dx * rstd * g1v.x + b1v.x + rv.x;
  o4.y = dy * rstd * g1v.y + b1v.y + rv.y;
  o4.z = dz * rstd * g1v.z + b1v.z + rv.z;
  o4.w = dw * rstd * g1v.w + b1v.w + rv.w;
  reinterpret_cast<float4*>(out1 + (size_t)row * 1024)[tid] = o4;
  __syncthreads();
  float s2 = o4.x + o4.y + o4.z + o4.w;
#pragma unroll
  for (int o = 32; o > 0; o >>= 1) s2 += __shfl_down(s2, o, 64);
  if ((tid & 63) == 0) sm[tid >> 6] = s2;
  __syncthreads();
  const float mean2 = (sm[0] + sm[1] + sm[2] + sm[3]) * (1.f / 1024.f);
  const float ex = o4.x - mean2, ey = o4.y - mean2, ez = o4.z - mean2, ew = o4.w - mean2;
  float q2 = ex * ex + ey * ey + ez * ez + ew * ew;
#pragma unroll
  for (int o = 32; o > 0; o >>= 1) q2 += __shfl_down(q2, o, 64);
  __syncthreads();
  if ((tid & 63) == 0) sm[tid >> 6] = q2;
  __syncthreads();
  const float var2 = (sm[0] + sm[1] + sm[2] + sm[3]) * (1.f / 1024.f);
  const float rstd2 = rsqrtf(var2 + 1e-5f);
  const float4 g2v = reinterpret_cast<const float4*>(g2)[tid];
  const float4 b2v = reinterpret_cast<const float4*>(b2)[tid];
  u16x4 ob;
  ob[0] = f2bf(ex * rstd2 * g2v.x + b2v.x);
  ob[1] = f2bf(ey * rstd2 * g2v.y + b2v.y);
  ob[2] = f2bf(ez * rstd2 * g2v.z + b2v.z);
  ob[3] = f2bf(ew * rstd2 * g2v.w + b2v.w);
  reinterpret_cast<u16x4*>(out2b + (size_t)row * 1024)[tid] = ob;
}

// ---------------------------------------------------------------- bf16 GEMM, 256x256 tile, BK=32, 4-slot ring, depth-3 vmcnt + T2 swizzle
__global__ __launch_bounds__(512) void gemm256_kernel(
    const unsigned short* __restrict__ A, int lda,
    const unsigned short* __restrict__ B, int ldb,
    void* __restrict__ Cv, int ldc,
    const float* __restrict__ bias, const float* __restrict__ res,
    int K, int act, int outbf, int gy)
{
  __shared__ __align__(16) unsigned char smem[131072];
  const int t = threadIdx.x;
  const int w = t >> 6, l = t & 63;

  const int q = gridDim.x >> 3;
  const int nid = (blockIdx.x & 7) * q + (blockIdx.x >> 3);
  const int bm = (nid / gy) * 256;
  const int bn = (nid % gy) * 256;

  const int wr = (w >> 2) * 128;
  const int wc = (w & 3) * 64;
  f32x4 acc[8][4] = {};

  const int srow = t >> 2;          // 0..127 (+128 second half: (row>>1)&3 invariant)
  const int sk = SWZ_SK(t);
  const unsigned short* gA = A + (size_t)(bm + srow) * lda + sk;
  const unsigned short* gB = B + (size_t)(bn + srow) * ldb + sk;

  const int fr = l & 15;
  const int kb = SWZ_KB(l);

#define SA7(s) (smem + (s) * 16384)
#define SB7(s) (smem + 65536 + (s) * 16384)

#define STAGE7(s, k0) do { \
    GLDS(gA + (k0), SA7(s) + w * 1024); \
    GLDS(gA + (k0) + (size_t)128 * lda, SA7(s) + 8192 + w * 1024); \
    GLDS(gB + (k0), SB7(s) + w * 1024); \
    GLDS(gB + (k0) + (size_t)128 * ldb, SB7(s) + 8192 + w * 1024); \
  } while (0)

#define COMPUTE7(s) do { \
    bf16x8 af[8], bfr[4]; \
    _Pragma("unroll") \
    for (int j = 0; j < 4; ++j) \
      bfr[j] = *reinterpret_cast<const bf16x8*>((const unsigned short*)SB7(s) + (wc + j * 16 + fr) * 32 + kb); \
    _Pragma("unroll") \
    for (int i = 0; i < 8; ++i) \
      af[i] = *reinterpret_cast<const bf16x8*>((const unsigned short*)SA7(s) + (wr + i * 16 + fr) * 32 + kb); \
    _Pragma("unroll") \
    for (int i = 0; i < 8; ++i) \
      _Pragma("unroll") \
      for (int j = 0; j < 4; ++j) \
        acc[i][j] = __builtin_amdgcn_mfma_f32_16x16x32_bf16(af[i], bfr[j], acc[i][j], 0, 0, 0); \
  } while (0)

  const int nt = K >> 5;
  STAGE7(0, 0);
  if (nt > 1) STAGE7(1, 32);
  if (nt > 2) STAGE7(2, 64);
  if (nt > 2)      asm volatile("s_waitcnt vmcnt(8)" ::: "memory");
  else if (nt > 1) asm volatile("s_waitcnt vmcnt(4)" ::: "memory");
  else             asm volatile("s_waitcnt vmcnt(0)" ::: "memory");
  __builtin_amdgcn_s_barrier();
  for (int kt = 0; kt < nt; ++kt) {
    const int s = kt & 3;
    __builtin_amdgcn_sched_barrier(0);
    if (kt + 3 < nt) STAGE7((kt + 3) & 3, (kt + 3) * 32);
    __builtin_amdgcn_sched_barrier(0);
    COMPUTE7(s);
    __builtin_amdgcn_sched_barrier(0);
    if (kt + 3 < nt)      asm volatile("s_waitcnt vmcnt(8)" ::: "memory");
    else if (kt + 2 < nt) asm volatile("s_waitcnt vmcnt(4)" ::: "memory");
    else if (kt + 1 < nt) asm volatile("s_waitcnt vmcnt(0)" ::: "memory");
    __builtin_amdgcn_s_barrier();
  }
#undef STAGE7
#undef COMPUTE7
#undef SA7
#undef SB7

  const int crow = (l >> 4) * 4;
  const int ccol = l & 15;
  float* Cf = (float*)Cv;
  unsigned short* Cb = (unsigned short*)Cv;
#pragma unroll
  for (int i = 0; i < 8; ++i) {
#pragma unroll
    for (int j = 0; j < 4; ++j) {
      const int n = bn + wc + j * 16 + ccol;
      const float bv = bias ? bias[n] : 0.f;
#pragma unroll
      for (int r = 0; r < 4; ++r) {
        const int m = bm + wr + i * 16 + crow + r;
        float v = acc[i][j][r] + bv;
        if (act == 1) v = (v > 20.f) ? v : __logf(1.f + __expf(v));
        else if (act == 2) v = (v >= 0.f) ? v : 0.01f * v;
        if (res) v += res[(size_t)m * ldc + n];
        if (outbf) Cb[(size_t)m * ldc + n] = f2bf(v);
        else       Cf[(size_t)m * ldc + n] = v;
      }
    }
  }
}

// ---------------------------------------------------------------- bf16 GEMM, intra-block K-split, 2 groups, 2-phase + T2 swizzle (BK=32)
template<int BK>
__global__ __launch_bounds__(512) void gemm_ksplit_kernel(
    const unsigned short* __restrict__ A, int lda,
    const unsigned short* __restrict__ B, int ldb,
    void* __restrict__ Cv, int ldc,
    const float* __restrict__ bias, const float* __restrict__ res,
    int K, int act, int outbf, int gy)
{
  constexpr int ABYTES = 128 * BK * 2;
  constexpr int NISS = (BK == 32) ? 2 : 4;
  constexpr int RPI  = (BK == 32) ? 64 : 32;
  constexpr int NS   = BK / 32;
  __shared__ __align__(16) unsigned char smem[8 * ABYTES];
  const int tid = threadIdx.x;
  const int grp = tid >> 8;
  const int t = tid & 255;
  const int w = t >> 6, l = t & 63;

  const int q = gridDim.x >> 3;
  const int nid = (blockIdx.x & 7) * q + (blockIdx.x >> 3);
  const int bm = (nid / gy) * 128;
  const int bn = (nid % gy) * 128;

  const int K2 = K >> 1;
  const int koff = grp * K2;
  const int wr = (w >> 1) * 64, wc = (w & 1) * 64;
  f32x4 acc[4][4] = {};

  const int srow = (BK == 32) ? (t >> 2) : (t >> 3);
  const int sk   = (BK == 32) ? SWZ_SK(t) : ((t & 7) * 8);
  const unsigned short* gA = A + (size_t)(bm + srow) * lda + koff + sk;
  const unsigned short* gB = B + (size_t)(bn + srow) * ldb + koff + sk;

  const int gbase = grp * 2 * ABYTES;
  const int fr = l & 15;
  const int kb = (BK == 32) ? SWZ_KB(l) : ((l >> 4) * 8);

#define SAb(buf) (smem + gbase + (buf) * ABYTES)
#define SBb(buf) (smem + 4 * ABYTES + gbase + (buf) * ABYTES)

#define STAGEK(buf, k0) do { \
    _Pragma("unroll") \
    for (int ii = 0; ii < NISS; ++ii) { \
      GLDS(gA + (k0) + (size_t)ii * RPI * lda, SAb(buf) + ii * 4096 + w * 1024); \
      GLDS(gB + (k0) + (size_t)ii * RPI * ldb, SBb(buf) + ii * 4096 + w * 1024); \
    } \
  } while (0)

#define COMPUTEK(buf) do { \
    _Pragma("unroll") \
    for (int s = 0; s < NS; ++s) { \
      bf16x8 af[4], bfr[4]; \
      _Pragma("unroll") \
      for (int i = 0; i < 4; ++i) \
        af[i] = *reinterpret_cast<const bf16x8*>((const unsigned short*)SAb(buf) + (wr + i * 16 + fr) * BK + s * 32 + kb); \
      _Pragma("unroll") \
      for (int j = 0; j < 4; ++j) \
        bfr[j] = *reinterpret_cast<const bf16x8*>((const unsigned short*)SBb(buf) + (wc + j * 16 + fr) * BK + s * 32 + kb); \
      _Pragma("unroll") \
      for (int i = 0; i < 4; ++i) \
        _Pragma("unroll") \
        for (int j = 0; j < 4; ++j) \
          acc[i][j] = __builtin_amdgcn_mfma_f32_16x16x32_bf16(af[i], bfr[j], acc[i][j], 0, 0, 0); \
    } \
  } while (0)

  STAGEK(0, 0);
  DRAIN_VM();
  __syncthreads();
  int cur = 0;
  for (int k0 = BK; k0 < K2; k0 += BK) {
    __builtin_amdgcn_sched_barrier(0);
    STAGEK(cur ^ 1, k0);
    __builtin_amdgcn_sched_barrier(0);
    COMPUTEK(cur);
    DRAIN_VM();
    __syncthreads();
    cur ^= 1;
  }
  COMPUTEK(cur);
#undef STAGEK
#undef COMPUTEK
#undef SAb
#undef SBb

  __syncthreads();
  float* red = (float*)smem;
  if (grp) {
#pragma unroll
    for (int i = 0; i < 4; ++i)
#pragma unroll
      for (int j = 0; j < 4; ++j)
        *reinterpret_cast<f32x4*>(&red[(t << 6) + (i * 4 + j) * 4]) = acc[i][j];
  }
  __syncthreads();
  if (!grp) {
    const int crow = (l >> 4) * 4;
    const int ccol = l & 15;
    float* Cf = (float*)Cv;
    unsigned short* Cb = (unsigned short*)Cv;
#pragma unroll
    for (int i = 0; i < 4; ++i) {
#pragma unroll
      for (int j = 0; j < 4; ++j) {
        const f32x4 o = *reinterpret_cast<const f32x4*>(&red[(t << 6) + (i * 4 + j) * 4]);
        const int n = bn + wc + j * 16 + ccol;
        const float bv = bias ? bias[n] : 0.f;
#pragma unroll
        for (int r = 0; r < 4; ++r) {
          const int m = bm + wr + i * 16 + crow + r;
          float v = acc[i][j][r] + o[r] + bv;
          if (act == 1) v = (v > 20.f) ? v : __logf(1.f + __expf(v));
          else if (act == 2) v = (v >= 0.f) ? v : 0.01f * v;
          if (res) v += res[(size_t)m * ldc + n];
          if (outbf) Cb[(size_t)m * ldc + n] = f2bf(v);
          else       Cf[(size_t)m * ldc + n] = v;
        }
      }
    }
  }
}

// ---------------------------------------------------------------- bf16 GEMM, 128x64 tile, intra-block K-split, 2 groups, 2-phase + T2 swizzle
// Short-K sites only (out_proj, fe). Padded reduction (stride 36 floats).
// resbf: residual pointer is bf16 (step 15 reads s5b).
__global__ __launch_bounds__(512) void gemm_ksplit_bn64_kernel(
    const unsigned short* __restrict__ A, int lda,
    const unsigned short* __restrict__ B, int ldb,
    void* __restrict__ Cv, int ldc,
    const float* __restrict__ bias, const void* __restrict__ res,
    int K, int act, int outbf, int gy, int resbf)
{
  __shared__ __align__(16) unsigned char smem[49152];
  const int tid = threadIdx.x;
  const int grp = tid >> 8;
  const int t = tid & 255;
  const int w = t >> 6, l = t & 63;

  const int q = gridDim.x >> 3;
  const int nid = (blockIdx.x & 7) * q + (blockIdx.x >> 3);
  const int bm = (nid / gy) * 128;
  const int bn = (nid % gy) * 64;

  const int K2 = K >> 1;
  const int koff = grp * K2;
  const int wr = (w >> 1) * 64, wc = (w & 1) * 32;
  f32x4 acc[4][2] = {};

  const int srow = t >> 2;          // 0..63
  const int sk = SWZ_SK(t);
  const unsigned short* gA = A + (size_t)(bm + srow) * lda + koff + sk;
  const unsigned short* gB = B + (size_t)(bn + srow) * ldb + koff + sk;

  const int fr = l & 15;
  const int kb = SWZ_KB(l);

#define SAn(buf) (smem + grp * 16384 + (buf) * 8192)
#define SBn(buf) (smem + 32768 + grp * 8192 + (buf) * 4096)

#define STAGEN(buf, k0) do { \
    GLDS(gA + (k0), SAn(buf) + w * 1024); \
    GLDS(gA + (k0) + (size_t)64 * lda, SAn(buf) + 4096 + w * 1024); \
    GLDS(gB + (k0), SBn(buf) + w * 1024); \
  } while (0)

#define COMPUTEN(buf) do { \
    bf16x8 af[4], bfr[2]; \
    _Pragma("unroll") \
    for (int i = 0; i < 4; ++i) \
      af[i] = *reinterpret_cast<const bf16x8*>((const unsigned short*)SAn(buf) + (wr + i * 16 + fr) * 32 + kb); \
    _Pragma("unroll") \
    for (int j = 0; j < 2; ++j) \
      bfr[j] = *reinterpret_cast<const bf16x8*>((const unsigned short*)SBn(buf) + (wc + j * 16 + fr) * 32 + kb); \
    _Pragma("unroll") \
    for (int i = 0; i < 4; ++i) \
      _Pragma("unroll") \
      for (int j = 0; j < 2; ++j) \
        acc[i][j] = __builtin_amdgcn_mfma_f32_16x16x32_bf16(af[i], bfr[j], acc[i][j], 0, 0, 0); \
  } while (0)

  STAGEN(0, 0);
  DRAIN_VM();
  __syncthreads();
  int cur = 0;
  for (int k0 = 32; k0 < K2; k0 += 32) {
    __builtin_amdgcn_sched_barrier(0);
    STAGEN(cur ^ 1, k0);
    __builtin_amdgcn_sched_barrier(0);
    COMPUTEN(cur);
    DRAIN_VM();
    __syncthreads();
    cur ^= 1;
  }
  COMPUTEN(cur);
#undef STAGEN
#undef COMPUTEN
#undef SAn
#undef SBn

  // reduction: grp1 dumps acc, grp0 adds + writes (stride 36 = bank-spread pad)
  __syncthreads();
  float* red = (float*)smem;
  if (grp) {
#pragma unroll
    for (int i = 0; i < 4; ++i)
#pragma unroll
      for (int j = 0; j < 2; ++j)
        *reinterpret_cast<f32x4*>(&red[t * 36 + (i * 2 + j) * 4]) = acc[i][j];
  }
  __syncthreads();
  if (!grp) {
    const int crow = (l >> 4) * 4;
    const int ccol = l & 15;
    float* Cf = (float*)Cv;
    unsigned short* Cb = (unsigned short*)Cv;
    const float* resf = (const float*)res;
    const unsigned short* resb = (const unsigned short*)res;
#pragma unroll
    for (int i = 0; i < 4; ++i) {
#pragma unroll
      for (int j = 0; j < 2; ++j) {
        const f32x4 o = *reinterpret_cast<const f32x4*>(&red[t * 36 + (i * 2 + j) * 4]);
        const int n = bn + wc + j * 16 + ccol;
        const float bv = bias ? bias[n] : 0.f;
#pragma unroll
        for (int r = 0; r < 4; ++r) {
          const int m = bm + wr + i * 16 + crow + r;
          float v = acc[i][j][r] + o[r] + bv;
          if (act == 1) v = (v > 20.f) ? v : __logf(1.f + __expf(v));
          else if (act == 2) v = (v >= 0.f) ? v : 0.01f * v;
          if (res) v += resbf ? bf2f(resb[(size_t)m * ldc + n]) : resf[(size_t)m * ldc + n];
          if (outbf) Cb[(size_t)m * ldc + n] = f2bf(v);
          else       Cf[(size_t)m * ldc + n] = v;
        }
      }
    }
  }
}

// ---------------------------------------------------------------- bf16 GEMM, intra-block K-split, 2 groups, 4-slot ring depth-3
// + T2 swizzle + padded reduction (rounds 31/32 proven: conflicts -> 0).
__global__ __launch_bounds__(512) void gemm_ksplit_ring_kernel(
    const unsigned short* __restrict__ A, int lda,
    const unsigned short* __restrict__ B, int ldb,
    void* __restrict__ Cv, int ldc,
    const float* __restrict__ bias, const float* __restrict__ res,
    int K, int act, int outbf, int gy)
{
  __shared__ __align__(16) unsigned char smem[131072];
  const int tid = threadIdx.x;
  const int grp = tid >> 8;
  const int t = tid & 255;
  const int w = t >> 6, l = t & 63;

  const int q = gridDim.x >> 3;
  const int nid = (blockIdx.x & 7) * q + (blockIdx.x >> 3);
  const int bm = (nid / gy) * 128;
  const int bn = (nid % gy) * 128;

  const int K2 = K >> 1;
  const int koff = grp * K2;
  const int wr = (w >> 1) * 64, wc = (w & 1) * 64;
  f32x4 acc[4][4] = {};

  const int srow = t >> 2;          // 0..63
  const int sk = SWZ_SK(t);
  const unsigned short* gA = A + (size_t)(bm + srow) * lda + koff + sk;
  const unsigned short* gB = B + (size_t)(bn + srow) * ldb + koff + sk;

  const int fr = l & 15;
  const int kb = SWZ_KB(l);

#define SAr(s) (smem + grp * 32768 + (s) * 8192)
#define SBr(s) (smem + 65536 + grp * 32768 + (s) * 8192)

#define STAGER(s, k0) do { \
    GLDS(gA + (k0), SAr(s) + w * 1024); \
    GLDS(gA + (k0) + (size_t)64 * lda, SAr(s) + 4096 + w * 1024); \
    GLDS(gB + (k0), SBr(s) + w * 1024); \
    GLDS(gB + (k0) + (size_t)64 * ldb, SBr(s) + 4096 + w * 1024); \
  } while (0)

#define COMPUTER(s) do { \
    bf16x8 af[4], bfr[4]; \
    _Pragma("unroll") \
    for (int i = 0; i < 4; ++i) \
      af[i] = *reinterpret_cast<const bf16x8*>((const unsigned short*)SAr(s) + (wr + i * 16 + fr) * 32 + kb); \
    _Pragma("unroll") \
    for (int j = 0; j < 4; ++j) \
      bfr[j] = *reinterpret_cast<const bf16x8*>((const unsigned short*)SBr(s) + (wc + j * 16 + fr) * 32 + kb); \
    _Pragma("unroll") \
    for (int i = 0; i < 4; ++i) \
      _Pragma("unroll") \
      for (int j = 0; j < 4; ++j) \
        acc[i][j] = __builtin_amdgcn_mfma_f32_16x16x32_bf16(af[i], bfr[j], acc[i][j], 0, 0, 0); \
  } while (0)

  const int nt = K2 >> 5;
  STAGER(0, 0);
  if (nt > 1) STAGER(1, 32);
  if (nt > 2) STAGER(2, 64);
  if (nt > 2)      asm volatile("s_waitcnt vmcnt(8)" ::: "memory");
  else if (nt > 1) asm volatile("s_waitcnt vmcnt(4)" ::: "memory");
  else             asm volatile("s_waitcnt vmcnt(0)" ::: "memory");
  __builtin_amdgcn_s_barrier();
  for (int kt = 0; kt < nt; ++kt) {
    const int s = kt & 3;
    __builtin_amdgcn_sched_barrier(0);
    if (kt + 3 < nt) STAGER((kt + 3) & 3, (kt + 3) * 32);
    __builtin_amdgcn_sched_barrier(0);
    COMPUTER(s);
    __builtin_amdgcn_sched_barrier(0);
    if (kt + 3 < nt)      asm volatile("s_waitcnt vmcnt(8)" ::: "memory");
    else if (kt + 2 < nt) asm volatile("s_waitcnt vmcnt(4)" ::: "memory");
    else if (kt + 1 < nt) asm volatile("s_waitcnt vmcnt(0)" ::: "memory");
    __builtin_amdgcn_s_barrier();
  }
#undef STAGER
#undef COMPUTER
#undef SAr
#undef SBr

  __syncthreads();
  float* red = (float*)smem;
  if (grp) {
#pragma unroll
    for (int i = 0; i < 4; ++i)
#pragma unroll
      for (int j = 0; j < 4; ++j)
        *reinterpret_cast<f32x4*>(&red[t * 68 + (i * 4 + j) * 4]) = acc[i][j];
  }
  __syncthreads();
  if (!grp) {
    const int crow = (l >> 4) * 4;
    const int ccol = l & 15;
    float* Cf = (float*)Cv;
    unsigned short* Cb = (unsigned short*)Cv;
#pragma unroll
    for (int i = 0; i < 4; ++i) {
#pragma unroll
      for (int j = 0; j < 4; ++j) {
        const f32x4 o = *reinterpret_cast<const f32x4*>(&red[t * 68 + (i * 4 + j) * 4]);
        const int n = bn + wc + j * 16 + ccol;
        const float bv = bias ? bias[n] : 0.f;
#pragma unroll
        for (int r = 0; r < 4; ++r) {
          const int m = bm + wr + i * 16 + crow + r;
          float v = acc[i][j][r] + o[r] + bv;
          if (act == 1) v = (v > 20.f) ? v : __logf(1.f + __expf(v));
          else if (act == 2) v = (v >= 0.f) ? v : 0.01f * v;
          if (res) v += res[(size_t)m * ldc + n];
          if (outbf) Cb[(size_t)m * ldc + n] = f2bf(v);
          else       Cf[(size_t)m * ldc + n] = v;
        }
      }
    }
  }
}

// ---------------------------------------------------------------- x_proj split-K (N=96), 2-phase (proven; layout differs — left unswizzled)
__global__ __launch_bounds__(256) void xproj_kernel(
    const unsigned short* __restrict__ A, int lda,
    const unsigned short* __restrict__ B, int ldb,
    float* __restrict__ C)
{
  __shared__ unsigned short As[2][128 * 32];
  __shared__ unsigned short Bs[2][96 * 32];
  const int t = threadIdx.x;
  const int w = t >> 6, l = t & 63;
  const int bm = blockIdx.x * 128;
  const int kbase = blockIdx.y * 128;

  f32x4 acc[2][6] = {};

  const int srow = t >> 2;
  const int sk = (t & 3) * 8;
  const unsigned short* gA0 = A + (size_t)(bm + srow) * lda + kbase + sk;
  const unsigned short* gA1 = gA0 + (size_t)64 * lda;
  const unsigned short* gB0 = B + (size_t)srow * ldb + kbase + sk;
  const unsigned short* gB1 = gB0 + (size_t)64 * ldb;

  const int fr = l & 15;
  const int kb = (l >> 4) * 8;

#define STAGEX(buf, k0) do { \
    GLDS(gA0 + (k0), &As[buf][w * 512]); \
    GLDS(gA1 + (k0), &As[buf][2048 + w * 512]); \
    GLDS(gB0 + (k0), &Bs[buf][w * 512]); \
    if (w < 2) GLDS(gB1 + (k0), &Bs[buf][2048 + w * 512]); \
  } while (0)

#define COMPUTEX(buf) do { \
    bf16x8 af[2], bfr[6]; \
    _Pragma("unroll") \
    for (int i = 0; i < 2; ++i) \
      af[i] = *reinterpret_cast<const bf16x8*>(&As[buf][(w * 32 + i * 16 + fr) * 32 + kb]); \
    _Pragma("unroll") \
    for (int j = 0; j < 6; ++j) \
      bfr[j] = *reinterpret_cast<const bf16x8*>(&Bs[buf][(j * 16 + fr) * 32 + kb]); \
    _Pragma("unroll") \
    for (int i = 0; i < 2; ++i) \
      _Pragma("unroll") \
      for (int j = 0; j < 6; ++j) \
        acc[i][j] = __builtin_amdgcn_mfma_f32_16x16x32_bf16(af[i], bfr[j], acc[i][j], 0, 0, 0); \
  } while (0)

  STAGEX(0, 0);
  DRAIN_VM();
  __syncthreads();
  int cur = 0;
  for (int s = 1; s < 4; ++s) {
    __builtin_amdgcn_sched_barrier(0);
    STAGEX(cur ^ 1, s * 32);
    __builtin_amdgcn_sched_barrier(0);
    COMPUTEX(cur);
    DRAIN_VM();
    __syncthreads();
    cur ^= 1;
  }
  COMPUTEX(cur);
#undef STAGEX
#undef COMPUTEX

  const int crow = (l >> 4) * 4;
  const int ccol = l & 15;
#pragma unroll
  for (int i = 0; i < 2; ++i)
#pragma unroll
    for (int j = 0; j < 6; ++j)
#pragma unroll
      for (int r = 0; r < 4; ++r) {
        const int m = bm + w * 32 + i * 16 + crow + r;
        const int n = j * 16 + ccol;
        atomicAdd(&C[(size_t)m * 96 + n], acc[i][j][r]);
      }
}

// ---------------------------------------------------------------- conv(k=2)+SiLU (bf16, x8 vectorized)
__global__ __launch_bounds__(256) void conv_silu_kernel(
    const unsigned short* __restrict__ xz, const float* __restrict__ cw,
    const float* __restrict__ cb, unsigned short* __restrict__ xcb)
{
  const int i = blockIdx.x * 256 + threadIdx.x;   // 524288 threads, 8 elems each
  const int row = i >> 7;
  const int dv = (i & 127) * 8;
  const int l = row & (L_SEQ - 1);
  const u16x8 cur = *reinterpret_cast<const u16x8*>(&xz[(size_t)row * 2048 + dv]);
  u16x8 prev = {};
  if (l != 0) prev = *reinterpret_cast<const u16x8*>(&xz[(size_t)(row - 1) * 2048 + dv]);
  float cwv[16], cbv[8];
#pragma unroll
  for (int qq = 0; qq < 4; ++qq)
    *reinterpret_cast<float4*>(&cwv[qq * 4]) = reinterpret_cast<const float4*>(cw + 2 * dv)[qq];
#pragma unroll
  for (int qq = 0; qq < 2; ++qq)
    *reinterpret_cast<float4*>(&cbv[qq * 4]) = reinterpret_cast<const float4*>(cb + dv)[qq];
  u16x8 o;
#pragma unroll
  for (int e = 0; e < 8; ++e) {
    const float v = bf2f(prev[e]) * cwv[2 * e] + bf2f(cur[e]) * cwv[2 * e + 1] + cbv[e];
    o[e] = f2bf(v / (1.f + __expf(-v)));
  }
  *reinterpret_cast<u16x8*>(&xcb[(size_t)row * 1024 + dv]) = o;
}

// ---------------------------------------------------------------- scan pass 1 (bf16 in, bf16 state out)
__global__ __launch_bounds__(256) void scan_pass1(
    const unsigned short* __restrict__ delta, const unsigned short* __restrict__ xc,
    const float* __restrict__ xdbl, const float* __restrict__ A_log,
    unsigned short* __restrict__ hfin, unsigned short* __restrict__ pcum)
{
  const int tid = threadIdx.x;
  const int db = blockIdx.x & 3;
  const int c = (blockIdx.x >> 2) & (NCHUNK - 1);
  const int b = blockIdx.x >> 7;
  const int d = db * 256 + tid;
  __shared__ float Bsh[CH][16];
  {
    const int lr = tid >> 2, q = tid & 3;
    const float* p = xdbl + ((size_t)(b * L_SEQ + c * CH + lr) * 96) + 64 + q * 4;
    *reinterpret_cast<float4*>(&Bsh[lr][q * 4]) = *reinterpret_cast<const float4*>(p);
  }
  float a[NSTATE];
#pragma unroll
  for (int n = 0; n < NSTATE; ++n) a[n] = -__expf(A_log[d * 16 + n]);
  __syncthreads();
  float h[NSTATE], P[NSTATE];
#pragma unroll
  for (int n = 0; n < NSTATE; ++n) { h[n] = 0.f; P[n] = 1.f; }
  const size_t rowbase = (size_t)(b * L_SEQ + c * CH);
  for (int s = 0; s < CH; ++s) {
    const size_t row = rowbase + s;
    const float dl = bf2f(delta[row * 1024 + d]);
    const float xcv = bf2f(xc[row * 1024 + d]);
#pragma unroll
    for (int n = 0; n < NSTATE; ++n) {
      const float dA = __expf(dl * a[n]);
      h[n] = h[n] * dA + (dl * Bsh[s][n]) * xcv;
      P[n] *= dA;
    }
  }
  const size_t base = ((size_t)((b * NCHUNK + c) * 1024 + d)) * 16;
  u16x8 h0, h1, p0, p1;
#pragma unroll
  for (int n = 0; n < 8; ++n) {
    h0[n] = f2bf(h[n]);     h1[n] = f2bf(h[n + 8]);
    p0[n] = f2bf(P[n]);     p1[n] = f2bf(P[n + 8]);
  }
  *reinterpret_cast<u16x8*>(hfin + base) = h0;
  *reinterpret_cast<u16x8*>(hfin + base + 8) = h1;
  *reinterpret_cast<u16x8*>(pcum + base) = p0;
  *reinterpret_cast<u16x8*>(pcum + base + 8) = p1;
}

// ---------------------------------------------------------------- scan pass 2 (bf16 state)
__global__ __launch_bounds__(256) void scan_pass2(
    const unsigned short* __restrict__ hfin, const unsigned short* __restrict__ pcum,
    unsigned short* __restrict__ hstart)
{
  const int t = blockIdx.x * 256 + threadIdx.x;
  const int b = t >> 14;
  const int dn = t & 16383;
  const size_t base = (size_t)b * NCHUNK * 16384 + dn;
  float h = 0.f;
  for (int c = 0; c < NCHUNK; ++c) {
    const size_t idx = base + (size_t)c * 16384;
    hstart[idx] = f2bf(h);
    h = bf2f(pcum[idx]) * h + bf2f(hfin[idx]);
  }
}

// ---------------------------------------------------------------- scan pass 3 (bf16 in, bf16 y out)
__global__ __launch_bounds__(256) void scan_pass3(
    const unsigned short* __restrict__ delta, const unsigned short* __restrict__ xc,
    const float* __restrict__ xdbl, const float* __restrict__ A_log,
    const unsigned short* __restrict__ hstart, const float* __restrict__ Dp,
    const unsigned short* __restrict__ xz, unsigned short* __restrict__ yout)
{
  const int tid = threadIdx.x;
  const int db = blockIdx.x & 3;
  const int c = (blockIdx.x >> 2) & (NCHUNK - 1);
  const int b = blockIdx.x >> 7;
  const int d = db * 256 + tid;
  __shared__ float Bsh[CH][16];
  __shared__ float Csh[CH][16];
  {
    const int lr = tid >> 2, q = tid & 3;
    const float* p = xdbl + ((size_t)(b * L_SEQ + c * CH + lr) * 96);
    *reinterpret_cast<float4*>(&Bsh[lr][q * 4]) = *reinterpret_cast<const float4*>(p + 64 + q * 4);
    *reinterpret_cast<float4*>(&Csh[lr][q * 4]) = *reinterpret_cast<const float4*>(p + 80 + q * 4);
  }
  float a[NSTATE];
#pragma unroll
  for (int n = 0; n < NSTATE; ++n) a[n] = -__expf(A_log[d * 16 + n]);
  float h[NSTATE];
  {
    const size_t base = ((size_t)((b * NCHUNK + c) * 1024 + d)) * 16;
    const u16x8 v0 = *reinterpret_cast<const u16x8*>(hstart + base);
    const u16x8 v1 = *reinterpret_cast<const u16x8*>(hstart + base + 8);
#pragma unroll
    for (int n = 0; n < 8; ++n) { h[n] = bf2f(v0[n]); h[n + 8] = bf2f(v1[n]); }
  }
  const float dpv = Dp[d];
  __syncthreads();
  const size_t rowbase = (size_t)(b * L_SEQ + c * CH);
  for (int s = 0; s < CH; ++s) {
    const size_t row = rowbase + s;
    const float dl = bf2f(delta[row * 1024 + d]);
    const float xcv = bf2f(xc[row * 1024 + d]);
    float y = 0.f;
#pragma unroll
    for (int n = 0; n < NSTATE; ++n) {
      const float dA = __expf(dl * a[n]);
      h[n] = h[n] * dA + (dl * Bsh[s][n]) * xcv;
      y += h[n] * Csh[s][n];
    }
    const float z = bf2f(xz[row * 2048 + 1024 + d]);
    const float sil = z / (1.f + __expf(-z));
    yout[row * 1024 + d] = f2bf((y + xcv * dpv) * sil);
  }
}

// ---------------------------------------------------------------- launch
extern "C" void kernel_launch(void* const* d_in, const int* in_sizes, int n_in,
                              void* d_out, int out_size, void* d_ws, size_t ws_size,
                              hipStream_t stream)
{
  (void)in_sizes; (void)n_in; (void)out_size; (void)ws_size;
  const float* src        = (const float*)d_in[0];
  const float* in_proj_w  = (const float*)d_in[1];
  const float* conv_w     = (const float*)d_in[2];
  const float* conv_b     = (const float*)d_in[3];
  const float* x_proj_w   = (const float*)d_in[4];
  const float* dt_proj_w  = (const float*)d_in[5];
  const float* dt_proj_b  = (const float*)d_in[6];
  const float* A_log      = (const float*)d_in[7];
  const float* Dp         = (const float*)d_in[8];
  const float* out_proj_w = (const float*)d_in[9];
  const float* mnorm_g    = (const float*)d_in[10];
  const float* mnorm_b    = (const float*)d_in[11];
  const float* n1_g       = (const float*)d_in[12];
  const float* n1_b       = (const float*)d_in[13];
  const float* n2_g       = (const float*)d_in[14];
  const float* n2_b       = (const float*)d_in[15];
  const float* n3_g       = (const float*)d_in[16];
  const float* n3_b       = (const float*)d_in[17];
  const float* ffn_w1     = (const float*)d_in[18];
  const float* ffn_w2     = (const float*)d_in[19];
  const float* fe_w       = (const float*)d_in[20];
  const float* fe_b       = (const float*)d_in[21];
  float* out = (float*)d_out;
  float* ws  = (float*)d_ws;

  // ---- workspace layout (float offsets; ranges disjoint) ----
  unsigned short* xzb   = (unsigned short*)ws;              // u16 8388608 = f[0 .. 4194304)
  unsigned short* xdblb = (unsigned short*)(ws + 4194304);  // u16 393216  = f[.. 4390912)
  unsigned short* dtwb  = (unsigned short*)(ws + 4390912);  // u16 65536   = f[.. 4423680)
  unsigned short* deltab= (unsigned short*)(ws + 4423680);  // u16 4194304 = f[.. 6520832)
  float* xdbl  = ws + 12582912;       // f[12582912 .. 12976128)
  unsigned short* s5b  = (unsigned short*)(ws + 17301504);  // u16 4194304 (bf16 staging, was f32 s5)
  float* src1  = ws + 21495808;       // f[21495808 .. 25690112)
  unsigned short* hfin = (unsigned short*)(ws + 25690112);  // u16 1048576
  unsigned short* pcum = (unsigned short*)(ws + 26738688);  // u16 1048576
  unsigned short* hst  = (unsigned short*)(ws + 27787264);  // u16 1048576
  unsigned short* s1b  = (unsigned short*)(ws + 28835840);  // u16 4194304
  unsigned short* xcb  = (unsigned short*)(ws + 30932992);  // u16 4194304
  unsigned short* yb   = (unsigned short*)(ws + 33030144);  // u16 4194304
  unsigned short* f1b  = (unsigned short*)(ws + 35127296);  // u16 16777216
  unsigned short* ipwb = (unsigned short*)(ws + 43515904);  // u16 2097152
  unsigned short* xpwb = (unsigned short*)(ws + 44564480);  // u16 98304
  unsigned short* opwb = (unsigned short*)(ws + 44613632);  // u16 1048576
  unsigned short* w1b  = (unsigned short*)(ws + 45137920);  // u16 4194304
  unsigned short* w2b  = (unsigned short*)(ws + 47235072);  // u16 4194304
  unsigned short* fewb = (unsigned short*)(ws + 49332224);  // u16 1048576

  const dim3 blk(256);
  const dim3 blk512(512);

  // 0+1. weights -> bf16, zero xdbl, step-1 LN (single launch; 12832 + 4096 blocks)
  cvt_all_kernel<<<16928, blk, 0, stream>>>(
      in_proj_w, x_proj_w, dt_proj_w, out_proj_w, ffn_w1, ffn_w2, fe_w, xdbl,
      ipwb, xpwb, dtwb, opwb, w1b, w2b, fewb,
      src, n1_g, n1_b, s1b);

  // 2. xz = x1 @ in_proj_w^T -> bf16  (ksplit2 BK=32 + T2 swizzle, 2 blocks/CU)
  gemm_ksplit_kernel<32><<<512, blk512, 0, stream>>>(s1b, 1024, ipwb, 1024, xzb, 2048,
                                                     nullptr, nullptr, 1024, 0, 1, 16);
  // 3. x_c = silu(conv(x_in)) -> bf16 (x8 vectorized)
  conv_silu_kernel<<<2048, blk, 0, stream>>>(xzb, conv_w, conv_b, xcb);
  // 4. x_dbl = x_c @ x_proj_w^T  (split-K=8, atomic f32; xdbl pre-zeroed in cvt_all)
  xproj_kernel<<<dim3(32, 8), blk, 0, stream>>>(xcb, 1024, xpwb, 1024, xdbl);
  // 4b. xdbl -> bf16 for dt_proj
  cvt_bf16_kernel<<<384, blk, 0, stream>>>(xdbl, xdblb, 98304);
  // 5. delta = softplus(dt @ dt_proj_w^T + b) -> bf16  (ksplit2 BK=32 + T2, K=64)
  gemm_ksplit_kernel<32><<<256, blk512, 0, stream>>>(xdblb, 96, dtwb, 64, deltab, 1024,
                                                     dt_proj_b, nullptr, 64, 1, 1, 8);
  // 6-8. selective scan (bf16 datapath + bf16 inter-chunk state)
  scan_pass1<<<256, blk, 0, stream>>>(deltab, xcb, xdbl, A_log, hfin, pcum);
  scan_pass2<<<128, blk, 0, stream>>>(hfin, pcum, hst);
  scan_pass3<<<256, blk, 0, stream>>>(deltab, xcb, xdbl, A_log, hst, Dp, xzb, yb);
  // 9. mamba_out = y @ out_proj_w^T -> bf16 s5b  (ksplit2 BN=64 + T2)
  gemm_ksplit_bn64_kernel<<<512, blk512, 0, stream>>>(yb, 1024, opwb, 1024, s5b, 1024,
                                                      nullptr, nullptr, 1024, 0, 1, 16, 0);
  // 10+11. src1 = src + LN(s5b; mnorm); x2 = LN(src1; n2) -> bf16  (fused, bf16 in)
  ln2_kernel<<<NROWS, blk, 0, stream>>>(s5b, mnorm_g, mnorm_b, src,
                                        n2_g, n2_b, src1, s1b);
  // 12. f1 = leaky(x2 @ ffn_w1^T) -> bf16  (256² ring-4 depth-3 + T2)
  gemm256_kernel<<<256, blk512, 0, stream>>>(s1b, 1024, w1b, 1024, f1b, 4096,
                                             nullptr, nullptr, 1024, 2, 1, 16);
  // 13. src2 = src1 + f1 @ ffn_w2^T -> bf16 s5b  (ring-4 depth-3 + T2)
  gemm_ksplit_ring_kernel<<<256, blk512, 0, stream>>>(f1b, 4096, w2b, 4096, s5b, 1024,
                                                      nullptr, src1, 4096, 0, 1, 8);
  // 14. x3 = LN(s5b; n3) -> bf16  (bf16 in/out)
  ln_kernel<<<NROWS, blk, 0, stream>>>(s5b, n3_g, n3_b, s1b);
  // 15. out = src2 + x3 @ fe_w^T + fe_b  (ksplit2 BN=64 + T2, bf16 residual s5b)
  gemm_ksplit_bn64_kernel<<<512, blk512, 0, stream>>>(s1b, 1024, fewb, 1024, out, 1024,
                                                      fe_b, s5b, 1024, 0, 0, 16, 1);
}